// Round 1
// baseline (3664.503 us; speedup 1.0000x reference)
//
#include <hip/hip_runtime.h>

// ---------------------------------------------------------------------------
// Model_81990925681018: 3x conv-encoder branches + label attention + GCN + head
// Round 1: fp32 VALU implementation (no fp32 MFMA exists on CDNA4).
// ---------------------------------------------------------------------------

#define CDIV(a,b) (((a)+(b)-1)/(b))

#define B_    16
#define L_    4096
#define D_    256
#define LP_   4112      // L + 2*POFF
#define POFF  8         // column pad (supports taps up to 17)
#define F_    100
#define FP_   104       // F padded to mult of 8 (K-chunk)
#define A_    256
#define C_    50
#define NN_   512
#define EE_   8192
#define ADJ_  8704      // EE_ + NN_ (self loops)
#define ZLD_  2056      // Z chunk ld: 2048 + 8 margin
#define ZCH_  2048
#define OC_   560       // out_cat padded cols (556 -> 560)

// ---------------- utility fills ----------------
__global__ void fill_f_k(float* p, int n, float v){
    int i = blockIdx.x*256 + threadIdx.x; if (i < n) p[i] = v;
}
__global__ void fill_i_k(int* p, int n, int v){
    int i = blockIdx.x*256 + threadIdx.x; if (i < n) p[i] = v;
}
// zero the 8 left + 8 right pad columns of a [rows][LP_] buffer
__global__ void zero_pads_k(float* buf, int rows){
    int idx = blockIdx.x*256 + threadIdx.x;
    if (idx >= rows*16) return;
    int r = idx >> 4, p = idx & 15;
    int col = (p < 8) ? p : (4096 + p);
    buf[(size_t)r*LP_ + col] = 0.f;
}

// ---------------- embedding gather + transpose ----------------
// h_pad[b][d][POFF+l] = word_emb[x[b][l]][d]
__global__ __launch_bounds__(256) void embed_k(const int* __restrict__ x,
                                               const float* __restrict__ emb,
                                               float* __restrict__ h){
    int b = blockIdx.y, l0 = blockIdx.x*64, tid = threadIdx.x;
    __shared__ float tile[64][65];
    __shared__ int   toks[64];
    if (tid < 64) toks[tid] = x[b*L_ + l0 + tid];
    __syncthreads();
    for (int dc = 0; dc < 4; ++dc){
        #pragma unroll 4
        for (int it = 0; it < 16; ++it){
            int tok = it*4 + (tid >> 6), d = tid & 63;
            tile[tok][d] = emb[(size_t)toks[tok]*D_ + dc*64 + d];
        }
        __syncthreads();
        #pragma unroll 4
        for (int it = 0; it < 16; ++it){
            int d = it*4 + (tid >> 6), l = tid & 63;
            h[((size_t)b*D_ + dc*64 + d)*LP_ + POFF + l0 + l] = tile[l][d];
        }
        __syncthreads();
    }
}

// ---------------- weight transpose: W[M][K][kt] -> Wt[Kp][kt][Mp] (zero pad) --
__global__ void transpose_w_k(const float* __restrict__ src, float* __restrict__ dst,
                              int M, int K, int kt, int Mp, int Kp){
    int idx = blockIdx.x*256 + threadIdx.x;
    int tot = Kp*kt*Mp;
    if (idx >= tot) return;
    int m = idx % Mp, rest = idx / Mp;
    int j = rest % kt, kc = rest / kt;
    float v = 0.f;
    if (m < M && kc < K) v = src[((size_t)m*K + kc)*kt + j];
    dst[idx] = v;
}
// fin1_w[128][556] -> w1t[560][128] zero-padded
__global__ void transpose_fin1_k(const float* __restrict__ src, float* __restrict__ dst){
    int idx = blockIdx.x*256 + threadIdx.x;
    if (idx >= OC_*128) return;
    int h = idx & 127, j = idx >> 7;
    dst[idx] = (j < 556) ? src[h*556 + j] : 0.f;
}

// ---------------- the workhorse: shifted-GEMM conv with fused epilogue -------
// out[b][m][n] = sum_{kc<Kp} sum_{j<KT} Wt[kc][j][m0+m] * in[b][kc][off+cb+n+j-KT/2]
// mode 0: tanh(acc+bias)*s+beta   (conv1)
// mode 1: tanh(acc*s+beta+resid)  (residual block)
// mode 2: tanh(acc)               (Z)
// mode 3: acc                     (logits)
template<int KT>
__global__ __launch_bounds__(256) void conv_gemm_k(
    const float* __restrict__ in, int in_bs, int in_ld, int in_off, int in_cb,
    const float* __restrict__ wt,
    const float* __restrict__ bias, const float* __restrict__ gamma, const float* __restrict__ beta,
    float* __restrict__ out, int out_bs, int out_ld, int out_off, int out_cb,
    int Kp, int Mp, int Mreal, int Mstore, int mode)
{
    __shared__ float aW[8*KT*128];
    __shared__ float bIn[8*72];
    int tid = threadIdx.x;
    int tx = tid & 15, ty = tid >> 4;
    int tm = ty*8, tn = tx*4;
    int n0 = blockIdx.x*64;
    int b  = blockIdx.y;
    int m0 = blockIdx.z*128;
    const float* inb = in + (size_t)b*in_bs;
    float acc[8][4];
    #pragma unroll
    for (int r = 0; r < 8; ++r)
        #pragma unroll
        for (int i = 0; i < 4; ++i) acc[r][i] = 0.f;
    const int cshift = 4 - (KT >> 1);
    int nch = Kp >> 3;
    for (int ch = 0; ch < nch; ++ch){
        int kc0 = ch << 3;
        const float* wsrc = wt + (size_t)kc0*KT*Mp + m0;
        for (int idx = tid; idx < 8*KT*128; idx += 256){
            int m = idx & 127, rest = idx >> 7;
            aW[idx] = wsrc[(size_t)rest*Mp + m];
        }
        const float* isrc = inb + (size_t)kc0*in_ld + (in_off + in_cb + n0 - 4);
        for (int idx = tid; idx < 576; idx += 256){
            int col = idx % 72, kc = idx / 72;
            bIn[idx] = isrc[(size_t)kc*in_ld + col];
        }
        __syncthreads();
        #pragma unroll 4
        for (int kc = 0; kc < 8; ++kc){
            #pragma unroll
            for (int j = 0; j < KT; ++j){
                const float* ap = &aW[(kc*KT + j) << 7];
                float4 a0 = *(const float4*)(ap + tm);
                float4 a1 = *(const float4*)(ap + tm + 4);
                const float* bp = &bIn[kc*72 + tn + j + cshift];
                float av[8] = {a0.x,a0.y,a0.z,a0.w,a1.x,a1.y,a1.z,a1.w};
                float bv[4] = {bp[0],bp[1],bp[2],bp[3]};
                #pragma unroll
                for (int r = 0; r < 8; ++r)
                    #pragma unroll
                    for (int i = 0; i < 4; ++i)
                        acc[r][i] = fmaf(av[r], bv[i], acc[r][i]);
            }
        }
        __syncthreads();
    }
    const float BNS = 0.9999950000374997f; // 1/sqrt(1+1e-5)
    #pragma unroll
    for (int r = 0; r < 8; ++r){
        int m = m0 + tm + r;
        if (m >= Mstore) continue;
        float s = 0.f, be = 0.f, bi = 0.f;
        if (mode <= 1 && m < Mreal){ s = gamma[m]*BNS; be = beta[m]; }
        if (mode == 0 && m < Mreal) bi = bias[m];
        float* op = out + (size_t)b*out_bs + (size_t)m*out_ld + (out_off + out_cb + n0 + tn);
        const float* resp = nullptr;
        if (mode == 1) resp = inb + (size_t)m*in_ld + (in_off + in_cb + n0 + tn);
        #pragma unroll
        for (int i = 0; i < 4; ++i){
            float v = acc[r][i];
            if      (mode == 0) v = tanhf(v + bi)*s + be;
            else if (mode == 1) v = tanhf(fmaf(v, s, be) + resp[i]);
            else if (mode == 2) v = tanhf(v);
            op[i] = v;
        }
    }
}

// ---------------- softmax over L per (b,c) row, in place ----------------
__global__ __launch_bounds__(256) void softmax_k(float* __restrict__ S){
    int row = blockIdx.x, t = threadIdx.x;
    float* p = S + (size_t)row*L_;
    __shared__ float sh[256];
    float mx = -1e30f;
    for (int j = t; j < L_; j += 256) mx = fmaxf(mx, p[j]);
    sh[t] = mx; __syncthreads();
    for (int o = 128; o > 0; o >>= 1){ if (t < o) sh[t] = fmaxf(sh[t], sh[t+o]); __syncthreads(); }
    float m = sh[0]; __syncthreads();
    float sum = 0.f;
    for (int j = t; j < L_; j += 256){ float e = expf(p[j] - m); p[j] = e; sum += e; }
    sh[t] = sum; __syncthreads();
    for (int o = 128; o > 0; o >>= 1){ if (t < o) sh[t] += sh[t+o]; __syncthreads(); }
    float inv = 1.0f / sh[0];
    for (int j = t; j < L_; j += 256) p[j] *= inv;
}

// ---------------- V[b][c][f] = sum_l t[f][l] * A[c][l] ----------------
// grid (8 L-chunks, B). atomicAdd into zeroed V.
__global__ __launch_bounds__(256) void v_accum_k(const float* __restrict__ t0,
                                                 const float* __restrict__ S,
                                                 float* __restrict__ V){
    __shared__ float As[C_*65];
    __shared__ float Ts[F_*65];
    int cx = blockIdx.x, b = blockIdx.y, tid = threadIdx.x;
    int c = tid/5, q = tid%5, f0 = q*20;
    float acc[20];
    #pragma unroll
    for (int i = 0; i < 20; ++i) acc[i] = 0.f;
    for (int sub = 0; sub < 8; ++sub){
        int l0 = cx*512 + sub*64;
        for (int idx = tid; idx < C_*64; idx += 256){
            int cc = idx >> 6, col = idx & 63;
            As[cc*65 + col] = S[((size_t)b*C_ + cc)*L_ + l0 + col];
        }
        for (int idx = tid; idx < F_*64; idx += 256){
            int ff = idx >> 6, col = idx & 63;
            Ts[ff*65 + col] = t0[((size_t)b*FP_ + ff)*LP_ + POFF + l0 + col];
        }
        __syncthreads();
        if (tid < 250){
            for (int col = 0; col < 64; ++col){
                float a = As[c*65 + col];
                #pragma unroll
                for (int ff = 0; ff < 20; ++ff)
                    acc[ff] = fmaf(a, Ts[(f0+ff)*65 + col], acc[ff]);
            }
        }
        __syncthreads();
    }
    if (tid < 250){
        float* vp = V + ((size_t)b*C_ + c)*F_ + f0;
        #pragma unroll
        for (int ff = 0; ff < 20; ++ff) atomicAdd(vp + ff, acc[ff]);
    }
}

// ---------------- GCN ----------------
__global__ void gather_nodes_k(const int* __restrict__ nodes, const float* __restrict__ emb,
                               float* __restrict__ ne){
    int idx = blockIdx.x*256 + threadIdx.x;
    if (idx >= B_*NN_*D_) return;
    int d = idx & 255, n = (idx >> 8) & 511, b = idx >> 17;
    ne[idx] = emb[(size_t)nodes[b*NN_ + n]*D_ + d];
}
__global__ void deg_count_k(const int* __restrict__ edges, int* __restrict__ deg){
    int idx = blockIdx.x*256 + threadIdx.x;
    if (idx >= B_*EE_) return;
    int b = idx >> 13, e = idx & (EE_-1);
    int dst = edges[b*2*EE_ + EE_ + e];
    atomicAdd(&deg[b*NN_ + dst], 1);
}
__global__ void dinv_k(const int* __restrict__ deg, float* __restrict__ dinv){
    int i = blockIdx.x*256 + threadIdx.x;
    if (i < B_*NN_) dinv[i] = 1.0f / sqrtf((float)deg[i]);
}
__global__ void scan_csr_k(const int* __restrict__ deg, int* __restrict__ rp, int* __restrict__ cur){
    int b = blockIdx.x, t = threadIdx.x;    // 512 threads
    __shared__ int sh[NN_];
    int v = deg[b*NN_ + t];
    sh[t] = v; __syncthreads();
    for (int off = 1; off < NN_; off <<= 1){
        int x = (t >= off) ? sh[t-off] : 0;
        __syncthreads();
        sh[t] += x;
        __syncthreads();
    }
    int incl = sh[t], excl = incl - v;
    rp[b*513 + t] = excl;
    cur[b*NN_ + t] = excl;
    if (t == NN_-1) rp[b*513 + NN_] = incl;
}
__global__ void fill_csr_k(const int* __restrict__ edges, int* __restrict__ cur, int* __restrict__ adj){
    int e = blockIdx.x*256 + threadIdx.x, b = blockIdx.y;
    if (e >= ADJ_) return;
    int s, d;
    if (e < EE_){ s = edges[b*2*EE_ + e]; d = edges[b*2*EE_ + EE_ + e]; }
    else        { s = d = e - EE_; }
    int pos = atomicAdd(&cur[b*NN_ + d], 1);
    adj[b*ADJ_ + pos] = s;
}
// out[b][n][i] = sum_j A[b][n][j] * W[i][j]   (NT GEMM, M=512,N=256,K=256)
__global__ __launch_bounds__(256) void gemm_nt_k(const float* __restrict__ A,
                                                 const float* __restrict__ W,
                                                 float* __restrict__ out){
    int b = blockIdx.z, n0 = blockIdx.x*64, i0 = blockIdx.y*64;
    __shared__ float aL[64][17], wL[64][17];
    int tid = threadIdx.x, tx = tid & 15, ty = tid >> 4;
    const float* Ab = A + (size_t)b*NN_*D_;
    float acc[4][4];
    #pragma unroll
    for (int r = 0; r < 4; ++r)
        #pragma unroll
        for (int i = 0; i < 4; ++i) acc[r][i] = 0.f;
    for (int j0 = 0; j0 < D_; j0 += 16){
        for (int idx = tid; idx < 1024; idx += 256){
            int r = idx >> 4, cc = idx & 15;
            aL[r][cc] = Ab[(size_t)(n0+r)*D_ + j0 + cc];
            wL[r][cc] = W[(size_t)(i0+r)*D_ + j0 + cc];
        }
        __syncthreads();
        #pragma unroll
        for (int kk = 0; kk < 16; ++kk){
            float av[4], wv[4];
            #pragma unroll
            for (int r = 0; r < 4; ++r) av[r] = aL[ty*4+r][kk];
            #pragma unroll
            for (int i = 0; i < 4; ++i) wv[i] = wL[tx*4+i][kk];
            #pragma unroll
            for (int r = 0; r < 4; ++r)
                #pragma unroll
                for (int i = 0; i < 4; ++i) acc[r][i] = fmaf(av[r], wv[i], acc[r][i]);
        }
        __syncthreads();
    }
    float* ob = out + (size_t)b*NN_*D_;
    #pragma unroll
    for (int r = 0; r < 4; ++r)
        #pragma unroll
        for (int i = 0; i < 4; ++i)
            ob[(size_t)(n0+ty*4+r)*D_ + i0+tx*4+i] = acc[r][i];
}
// per-node aggregation: out[n][i] = (sum_{e in CSR[n]} xw[src_e][i]*dinv[src_e])*dinv[n]+bias
__global__ __launch_bounds__(256) void scatter_k(const float* __restrict__ xw,
                                                 const int* __restrict__ adj,
                                                 const int* __restrict__ rp,
                                                 const float* __restrict__ dinv,
                                                 const float* __restrict__ bias,
                                                 float* __restrict__ out,
                                                 int out_bs, int out_ld, int relu){
    int n = blockIdx.x, b = blockIdx.y, t = threadIdx.x;
    const int* rpb = rp + b*513;
    const int* adjb = adj + b*ADJ_;
    const float* xwb = xw + (size_t)b*NN_*D_;
    const float* dvb = dinv + b*NN_;
    int e0 = rpb[n], e1 = rpb[n+1];
    float acc = 0.f;
    for (int e = e0; e < e1; ++e){
        int s = adjb[e];
        acc = fmaf(xwb[(size_t)s*D_ + t], dvb[s], acc);
    }
    float v = fmaf(acc, dvb[n], bias[t]);
    if (relu) v = fmaxf(v, 0.f);
    out[(size_t)b*out_bs + (size_t)n*out_ld + t] = v;
}

// ---------------- concat V parts into out_cat cols [256,560) ----------------
__global__ void concat_v_k(const float* __restrict__ V, float* __restrict__ oc){
    int idx = blockIdx.x*256 + threadIdx.x;
    if (idx >= B_*C_*304) return;
    int p = idx % 304, c = (idx/304) % C_, b = idx/(304*C_);
    float v = 0.f;
    if      (p < 100) v = V[((size_t)(0*B_ + b)*C_ + c)*F_ + p];
    else if (p < 200) v = V[((size_t)(1*B_ + b)*C_ + c)*F_ + (p-100)];
    else if (p < 300) v = V[((size_t)(2*B_ + b)*C_ + c)*F_ + (p-200)];
    oc[((size_t)b*C_ + c)*OC_ + 256 + p] = v;
}

// ---------------- fused head: relu(oc @ fin1^T + b1) -> dot fin2 row --------
__global__ __launch_bounds__(128) void final_k(const float* __restrict__ oc,
                                               const float* __restrict__ w1t,
                                               const float* __restrict__ b1,
                                               const float* __restrict__ w2,
                                               const float* __restrict__ b2,
                                               float* __restrict__ y){
    int c = blockIdx.x, b = blockIdx.y, h = threadIdx.x;
    __shared__ float row[OC_];
    __shared__ float red[128];
    const float* src = oc + ((size_t)b*C_ + c)*OC_;
    for (int j = h; j < OC_; j += 128) row[j] = src[j];
    __syncthreads();
    float acc = b1[h];
    #pragma unroll 8
    for (int j = 0; j < OC_; ++j) acc = fmaf(row[j], w1t[j*128 + h], acc);
    float hid = fmaxf(acc, 0.f);
    red[h] = hid * w2[c*128 + h];
    __syncthreads();
    for (int o = 64; o > 0; o >>= 1){ if (h < o) red[h] += red[h+o]; __syncthreads(); }
    if (h == 0) y[b*C_ + c] = red[0] + b2[c];
}

// ===========================================================================
extern "C" void kernel_launch(void* const* d_in, const int* in_sizes, int n_in,
                              void* d_out, int out_size, void* d_ws, size_t ws_size,
                              hipStream_t stream){
    (void)in_sizes; (void)n_in; (void)out_size; (void)ws_size;
    const int*   x          = (const int*)d_in[0];
    const int*   nodes      = (const int*)d_in[2];
    const int*   edges      = (const int*)d_in[3];
    const float* word_emb   = (const float*)d_in[4];
    const float* entity_emb = (const float*)d_in[5];
    const float* convw[3]   = {(const float*)d_in[6], (const float*)d_in[9],  (const float*)d_in[12]};
    const float* convb[3]   = {(const float*)d_in[7], (const float*)d_in[10], (const float*)d_in[13]};
    const float* resw[3]    = {(const float*)d_in[8], (const float*)d_in[11], (const float*)d_in[14]};
    const float* bn_gamma   = (const float*)d_in[15];  // [3][3][100]
    const float* bn_beta    = (const float*)d_in[16];
    const float* attn_w     = (const float*)d_in[17];  // [3][256][100]
    const float* attn_u     = (const float*)d_in[18];  // [3][50][256]
    const float* gc1_w      = (const float*)d_in[19];
    const float* gc1_b      = (const float*)d_in[20];
    const float* gc2_w      = (const float*)d_in[21];
    const float* gc2_b      = (const float*)d_in[22];
    const float* fin1_w     = (const float*)d_in[23];
    const float* fin1_b     = (const float*)d_in[24];
    const float* fin2_w     = (const float*)d_in[25];
    const float* fin2_b     = (const float*)d_in[26];
    float* y = (float*)d_out;

    // ---- workspace layout ----
    char* base = (char*)d_ws;
    size_t off = 0;
    auto alloc = [&](size_t elems, size_t esz) -> char* {
        char* p = base + off;
        off += ((elems*esz + 255) / 256) * 256;
        return p;
    };
    float* h_pad = (float*)alloc((size_t)B_*D_*LP_, 4);
    float* t0    = (float*)alloc((size_t)B_*FP_*LP_, 4);
    float* t1    = (float*)alloc((size_t)B_*FP_*LP_, 4);
    float* Zb    = (float*)alloc((size_t)B_*A_*ZLD_, 4);
    float* S     = (float*)alloc((size_t)B_*C_*L_, 4);
    float* V     = (float*)alloc((size_t)3*B_*C_*F_, 4);
    float* ne    = (float*)alloc((size_t)B_*NN_*D_, 4);
    float* xw    = (float*)alloc((size_t)B_*NN_*D_, 4);
    float* g1    = (float*)alloc((size_t)B_*NN_*D_, 4);
    float* ocat  = (float*)alloc((size_t)B_*C_*OC_, 4);
    float* wt_c1 = (float*)alloc((size_t)256*9*128, 4);
    float* wt_r1 = (float*)alloc((size_t)FP_*9*128, 4);
    float* wt_r2 = (float*)alloc((size_t)FP_*9*128, 4);
    float* wt_aw = (float*)alloc((size_t)FP_*A_, 4);
    float* wt_au = (float*)alloc((size_t)A_*128, 4);
    float* w1t   = (float*)alloc((size_t)OC_*128, 4);
    float* dinvp = (float*)alloc((size_t)B_*NN_, 4);
    int* deg  = (int*)alloc((size_t)B_*NN_, 4);
    int* rpB  = (int*)alloc((size_t)B_*513, 4);
    int* cur  = (int*)alloc((size_t)B_*NN_, 4);
    int* adj  = (int*)alloc((size_t)B_*ADJ_, 4);

    auto launch_cg = [&](int k, dim3 g,
                         const float* in, int in_bs, int in_ld, int in_off, int in_cb,
                         const float* wt, const float* bias, const float* gam, const float* bet,
                         float* out, int out_bs, int out_ld, int out_off, int out_cb,
                         int Kp, int Mp, int Mreal, int Mstore, int mode){
        switch (k){
        case 1: conv_gemm_k<1><<<g,256,0,stream>>>(in,in_bs,in_ld,in_off,in_cb,wt,bias,gam,bet,
                    out,out_bs,out_ld,out_off,out_cb,Kp,Mp,Mreal,Mstore,mode); break;
        case 3: conv_gemm_k<3><<<g,256,0,stream>>>(in,in_bs,in_ld,in_off,in_cb,wt,bias,gam,bet,
                    out,out_bs,out_ld,out_off,out_cb,Kp,Mp,Mreal,Mstore,mode); break;
        case 5: conv_gemm_k<5><<<g,256,0,stream>>>(in,in_bs,in_ld,in_off,in_cb,wt,bias,gam,bet,
                    out,out_bs,out_ld,out_off,out_cb,Kp,Mp,Mreal,Mstore,mode); break;
        case 9: conv_gemm_k<9><<<g,256,0,stream>>>(in,in_bs,in_ld,in_off,in_cb,wt,bias,gam,bet,
                    out,out_bs,out_ld,out_off,out_cb,Kp,Mp,Mreal,Mstore,mode); break;
        }
    };

    // ---- init ----
    fill_f_k<<<CDIV(3*B_*C_*F_,256),256,0,stream>>>(V, 3*B_*C_*F_, 0.f);
    fill_i_k<<<CDIV(B_*NN_,256),256,0,stream>>>(deg, B_*NN_, 1);   // self-loop
    zero_pads_k<<<CDIV(B_*D_*16,256),256,0,stream>>>(h_pad, B_*D_);
    zero_pads_k<<<CDIV(B_*FP_*16,256),256,0,stream>>>(t0, B_*FP_);
    zero_pads_k<<<CDIV(B_*FP_*16,256),256,0,stream>>>(t1, B_*FP_);

    // ---- embedding ----
    embed_k<<<dim3(L_/64, B_),256,0,stream>>>(x, word_emb, h_pad);

    // ---- GCN ----
    gather_nodes_k<<<CDIV(B_*NN_*D_,256),256,0,stream>>>(nodes, entity_emb, ne);
    deg_count_k<<<CDIV(B_*EE_,256),256,0,stream>>>(edges, deg);
    dinv_k<<<CDIV(B_*NN_,256),256,0,stream>>>(deg, dinvp);
    scan_csr_k<<<B_,NN_,0,stream>>>(deg, rpB, cur);
    fill_csr_k<<<dim3(CDIV(ADJ_,256),B_),256,0,stream>>>(edges, cur, adj);
    gemm_nt_k<<<dim3(NN_/64, D_/64, B_),256,0,stream>>>(ne, gc1_w, xw);
    scatter_k<<<dim3(NN_,B_),256,0,stream>>>(xw, adj, rpB, dinvp, gc1_b, g1, NN_*D_, D_, 1);
    gemm_nt_k<<<dim3(NN_/64, D_/64, B_),256,0,stream>>>(g1, gc2_w, xw);
    scatter_k<<<dim3(C_,B_),256,0,stream>>>(xw, adj, rpB, dinvp, gc2_b, ocat, C_*OC_, OC_, 0);

    // ---- encoder branches ----
    const int ks[3] = {3, 5, 9};
    for (int br = 0; br < 3; ++br){
        int k = ks[br];
        transpose_w_k<<<CDIV(256*k*128,256),256,0,stream>>>(convw[br], wt_c1, F_, 256, k, 128, 256);
        transpose_w_k<<<CDIV(FP_*k*128,256),256,0,stream>>>(resw[br], wt_r1, F_, F_, k, 128, FP_);
        transpose_w_k<<<CDIV(FP_*k*128,256),256,0,stream>>>(resw[br] + F_*F_*k, wt_r2, F_, F_, k, 128, FP_);
        transpose_w_k<<<CDIV(FP_*A_,256),256,0,stream>>>(attn_w + br*A_*F_, wt_aw, A_, F_, 1, A_, FP_);
        transpose_w_k<<<CDIV(A_*128,256),256,0,stream>>>(attn_u + br*C_*A_, wt_au, C_, A_, 1, 128, A_);
        const float* gam = bn_gamma + br*300;
        const float* bet = bn_beta + br*300;
        // conv1: h_pad -> t0
        launch_cg(k, dim3(L_/64, B_, 1), h_pad, D_*LP_, LP_, POFF, 0, wt_c1, convb[br], gam, bet,
                  t0, FP_*LP_, LP_, POFF, 0, 256, 128, F_, FP_, 0);
        // res1: t0 -> t1
        launch_cg(k, dim3(L_/64, B_, 1), t0, FP_*LP_, LP_, POFF, 0, wt_r1, nullptr, gam+100, bet+100,
                  t1, FP_*LP_, LP_, POFF, 0, FP_, 128, F_, FP_, 1);
        // res2: t1 -> t0
        launch_cg(k, dim3(L_/64, B_, 1), t1, FP_*LP_, LP_, POFF, 0, wt_r2, nullptr, gam+200, bet+200,
                  t0, FP_*LP_, LP_, POFF, 0, FP_, 128, F_, FP_, 1);
        // attention: Z in 2 L-chunks to cap Z memory; logits into S
        for (int cz = 0; cz < 2; ++cz){
            launch_cg(1, dim3(ZCH_/64, B_, 2), t0, FP_*LP_, LP_, POFF, cz*ZCH_, wt_aw,
                      nullptr, nullptr, nullptr,
                      Zb, A_*ZLD_, ZLD_, 4, 0, FP_, A_, A_, A_, 2);
            launch_cg(1, dim3(ZCH_/64, B_, 1), Zb, A_*ZLD_, ZLD_, 4, 0, wt_au,
                      nullptr, nullptr, nullptr,
                      S, C_*L_, L_, 0, cz*ZCH_, A_, 128, C_, C_, 3);
        }
        softmax_k<<<B_*C_,256,0,stream>>>(S);
        v_accum_k<<<dim3(8, B_),256,0,stream>>>(t0, S, V + (size_t)br*B_*C_*F_);
    }

    // ---- head ----
    transpose_fin1_k<<<CDIV(OC_*128,256),256,0,stream>>>(fin1_w, w1t);
    concat_v_k<<<CDIV(B_*C_*304,256),256,0,stream>>>(V, ocat);
    final_k<<<dim3(C_,B_),128,0,stream>>>(ocat, w1t, fin1_b, fin2_w, fin2_b, y);
}

// Round 2
// 2464.128 us; speedup vs baseline: 1.4871x; 1.4871x over previous
//
#include <hip/hip_runtime.h>

// ---------------------------------------------------------------------------
// Model_81990925681018  — Round 2: bf16-split MFMA conv encoders.
// All conv/GEMM-shaped work runs as hi/lo bf16 split (3 MFMA products,
// error ~2^-18) on v_mfma_f32_16x16x32_bf16. Activations live as bf16 hi/lo
// planes in [b][col][ch] layout (transpose-free LDS staging); weights are
// pre-packed in exact A-fragment order and read from global (L2-resident).
// ---------------------------------------------------------------------------

#define CDIV(a,b) (((a)+(b)-1)/(b))

#define B_    16
#define L_    4096
#define D_    256
#define LP_   4112      // L + 2*POFF
#define POFF  8
#define F_    100
#define A_    256
#define C_    50
#define NN_   512
#define EE_   8192
#define ADJ_  8704
#define OC_   560

typedef unsigned short u16;
using short8  = __attribute__((ext_vector_type(8))) short;
using short4v = __attribute__((ext_vector_type(4))) short;
using f32x4   = __attribute__((ext_vector_type(4))) float;

__device__ __forceinline__ u16 f2b(float f){
    unsigned u = __float_as_uint(f);
    u += 0x7FFF + ((u >> 16) & 1);
    return (u16)(u >> 16);
}
__device__ __forceinline__ float b2f(u16 h){ return __uint_as_float(((unsigned)h) << 16); }

// ---------------- utility fills ----------------
__global__ void fill_f_k(float* p, int n, float v){
    int i = blockIdx.x*256 + threadIdx.x; if (i < n) p[i] = v;
}
__global__ void fill_i_k(int* p, int n, int v){
    int i = blockIdx.x*256 + threadIdx.x; if (i < n) p[i] = v;
}
// zero the 8 left + 8 right pad cols of a hi/lo plane pair [b][LP_][CHp]
__global__ void zero_pads2_k(u16* pH, u16* pL, int CHp){
    int idx = blockIdx.x*256 + threadIdx.x;
    int tot = B_*16*CHp;
    if (idx >= tot) return;
    int ch = idx % CHp; int rest = idx / CHp;
    int pc = rest & 15; int b = rest >> 4;
    int col = (pc < 8) ? pc : (4096 + pc);
    size_t o = ((size_t)b*LP_ + col)*CHp + ch;
    pH[o] = 0; pL[o] = 0;
}

// ---------------- embedding gather -> hi/lo planes [b][col][256] ----------
__global__ __launch_bounds__(256) void embed2_k(const int* __restrict__ x,
                                                const float* __restrict__ emb,
                                                u16* __restrict__ hH, u16* __restrict__ hL){
    int b = blockIdx.y;
    int col = blockIdx.x*16 + (threadIdx.x >> 4);
    int cg = (threadIdx.x & 15) * 16;
    size_t o = ((size_t)b*LP_ + col)*D_ + cg;
    int l = col - POFF;
    short8 h0, h1, l0, l1;
    if (l < 0 || l >= L_){
        #pragma unroll
        for (int i = 0; i < 8; ++i){ h0[i]=0; h1[i]=0; l0[i]=0; l1[i]=0; }
    } else {
        int tok = x[b*L_ + l];
        const float* s = emb + (size_t)tok*D_ + cg;
        #pragma unroll
        for (int i = 0; i < 8; ++i){
            float v = s[i];
            u16 hv = f2b(v); u16 lv = f2b(v - b2f(hv));
            h0[i] = (short)hv; l0[i] = (short)lv;
        }
        #pragma unroll
        for (int i = 0; i < 8; ++i){
            float v = s[8+i];
            u16 hv = f2b(v); u16 lv = f2b(v - b2f(hv));
            h1[i] = (short)hv; l1[i] = (short)lv;
        }
    }
    *(short8*)(hH + o)     = h0;
    *(short8*)(hH + o + 8) = h1;
    *(short8*)(hL + o)     = l0;
    *(short8*)(hL + o + 8) = l1;
}

// ---------------- weight -> MFMA A-fragment packer -------------------------
// src: W[M][K][kt] fp32.  dst: [j][cc][mt]{hi 512 | lo 512} u16, lane-major.
// frag element: m = mt*16 + (lane&15), ch = cc*32 + (lane>>4)*8 + i.
__global__ void frag_w_k(const float* __restrict__ src, u16* __restrict__ dst,
                         int M, int K, int kt, int nch, int MTtot){
    int idx = blockIdx.x*256 + threadIdx.x;
    int tot = kt*nch*MTtot*512;
    if (idx >= tot) return;
    int i = idx & 7, lane = (idx >> 3) & 63;
    int rest = idx >> 9;
    int mt = rest % MTtot; int rest2 = rest / MTtot;
    int cc = rest2 % nch;  int j = rest2 / nch;
    int m  = mt*16 + (lane & 15);
    int ch = cc*32 + (lane >> 4)*8 + i;
    float v = (m < M && ch < K) ? src[((size_t)m*K + ch)*kt + j] : 0.f;
    u16 hi = f2b(v);
    u16 lo = f2b(v - b2f(hi));
    size_t base = (size_t)rest*1024 + lane*8 + i;
    dst[base]       = hi;
    dst[base + 512] = lo;
}

// fin1_w[128][556] -> w1t[560][128] zero-padded
__global__ void transpose_fin1_k(const float* __restrict__ src, float* __restrict__ dst){
    int idx = blockIdx.x*256 + threadIdx.x;
    if (idx >= OC_*128) return;
    int h = idx & 127, j = idx >> 7;
    dst[idx] = (j < 556) ? src[h*556 + j] : 0.f;
}

// ---------------- MFMA shifted-GEMM conv -----------------------------------
// Block: 256 thr (4 waves, 2x2), out tile BM x 128 cols, BM = MT*32.
// K = nch chunks of 32 channels x KT taps.  3-product hi/lo split.
// mode 0: tanh(acc+bias)*s+beta   -> hi/lo planes
// mode 1: tanh(acc*s+beta+resid)  -> hi/lo planes (resid = input planes)
// mode 2: tanh(acc)               -> hi/lo planes
// mode 3: acc (fp32)              -> Sout[b][m][L]
template<int KT, int MT>
__global__ __launch_bounds__(256) void conv_mfma_k(
    const u16* __restrict__ inH, const u16* __restrict__ inL, int CHp_in, int nch,
    const u16* __restrict__ wf, int MTtot,
    const float* __restrict__ bias, const float* __restrict__ gamma,
    const float* __restrict__ beta, int Mreal,
    u16* __restrict__ outH, u16* __restrict__ outL, int CHp_out,
    float* __restrict__ Sout, int mode)
{
    constexpr int BM = MT*32;
    __shared__ short sm[11520];   // slab: hi[144][40] | lo[144][40]; reused as epi [32][136] x2
    const int tid  = threadIdx.x;
    const int lane = tid & 63;
    const int w  = tid >> 6, wm = w >> 1, wn = w & 1;
    const int q  = lane >> 4, lr = lane & 15;
    const int n0 = blockIdx.x * 128;
    const int b  = blockIdx.y;
    const int mblk = blockIdx.z;

    f32x4 acc[MT][4];
    #pragma unroll
    for (int t = 0; t < MT; ++t)
        #pragma unroll
        for (int n = 0; n < 4; ++n) acc[t][n] = (f32x4){0.f,0.f,0.f,0.f};

    for (int cc = 0; cc < nch; ++cc){
        // stage input slab: block cols [n0-8, n0+136) x 32 ch, hi+lo
        for (int idx = tid; idx < 1152; idx += 256){
            int pl = (idx >= 576);
            int e  = pl ? idx - 576 : idx;
            int col = e >> 2, qq = e & 3;
            const u16* src = (pl ? inL : inH)
                + ((size_t)b*LP_ + n0 + col)*CHp_in + cc*32 + qq*8;   // POFF-8+n0+col = n0+col
            *(short8*)(sm + (pl ? 5760 : 0) + col*40 + qq*8) = *(const short8*)src;
        }
        __syncthreads();
        for (int j = 0; j < KT; ++j){
            short8 Ah[MT], Al[MT];
            const u16* fp = wf + (size_t)((j*nch + cc)*MTtot + mblk*(2*MT) + wm*MT)*1024 + lane*8;
            #pragma unroll
            for (int t = 0; t < MT; ++t){
                Ah[t] = *(const short8*)(fp + t*1024);
                Al[t] = *(const short8*)(fp + t*1024 + 512);
            }
            short8 Bh[4], Bl[4];
            int sc0 = 8 - (KT >> 1) + j + wn*64 + lr;
            #pragma unroll
            for (int n = 0; n < 4; ++n){
                int ad = (sc0 + n*16)*40 + q*8;
                Bh[n] = *(const short8*)(sm + ad);
                Bl[n] = *(const short8*)(sm + 5760 + ad);
            }
            #pragma unroll
            for (int t = 0; t < MT; ++t)
                #pragma unroll
                for (int n = 0; n < 4; ++n){
                    acc[t][n] = __builtin_amdgcn_mfma_f32_16x16x32_bf16(Ah[t], Bh[n], acc[t][n], 0,0,0);
                    acc[t][n] = __builtin_amdgcn_mfma_f32_16x16x32_bf16(Ah[t], Bl[n], acc[t][n], 0,0,0);
                    acc[t][n] = __builtin_amdgcn_mfma_f32_16x16x32_bf16(Al[t], Bh[n], acc[t][n], 0,0,0);
                }
        }
        __syncthreads();
    }

    // ---- epilogue ----
    if (mode == 3){
        #pragma unroll
        for (int t = 0; t < MT; ++t){
            int mrow = mblk*BM + wm*(MT*16) + t*16 + q*4;
            #pragma unroll
            for (int n = 0; n < 4; ++n){
                int colg = n0 + wn*64 + n*16 + lr;
                #pragma unroll
                for (int r = 0; r < 4; ++r){
                    int mm = mrow + r;
                    if (mm < Mreal) Sout[((size_t)b*C_ + mm)*L_ + colg] = acc[t][n][r];
                }
            }
        }
        return;
    }
    const float BNS = 0.9999950000374997f; // 1/sqrt(1+1e-5)
    for (int p = 0; p < 4; ++p){           // 32-col transpose passes
        if (wn == (p >> 1)){
            int ntp = p & 1;
            for (int t = 0; t < MT; ++t){
                #pragma unroll
                for (int u = 0; u < 2; ++u){
                    int nn = 2*ntp + u;
                    int mbase = wm*(MT*16) + t*16 + q*4;
                    int colg  = n0 + wn*64 + nn*16 + lr;
                    int cl    = nn*16 + lr - ntp*32;
                    float rsum[4] = {0.f,0.f,0.f,0.f};
                    if (mode == 1){
                        size_t ro = ((size_t)b*LP_ + POFF + colg)*CHp_in + mbase;
                        short4v rh = *(const short4v*)(inH + ro);
                        short4v rl = *(const short4v*)(inL + ro);
                        #pragma unroll
                        for (int r = 0; r < 4; ++r)
                            rsum[r] = b2f((u16)rh[r]) + b2f((u16)rl[r]);
                    }
                    u16 hv[4], lv[4];
                    #pragma unroll
                    for (int r = 0; r < 4; ++r){
                        int mm = mbase + r;
                        float a = acc[t][nn][r];
                        float v;
                        if (mode == 0){
                            float bi=0.f, s=0.f, be=0.f;
                            if (mm < Mreal){ bi = bias[mm]; s = gamma[mm]*BNS; be = beta[mm]; }
                            v = tanhf(a + bi)*s + be;
                        } else if (mode == 1){
                            float s=0.f, be=0.f;
                            if (mm < Mreal){ s = gamma[mm]*BNS; be = beta[mm]; }
                            v = tanhf(fmaf(a, s, be) + rsum[r]);
                        } else {
                            v = tanhf(a);
                        }
                        hv[r] = f2b(v);
                        lv[r] = f2b(v - b2f(hv[r]));
                    }
                    int eo = cl*136 + mbase;
                    *(short4v*)(sm + eo)        = (short4v){(short)hv[0],(short)hv[1],(short)hv[2],(short)hv[3]};
                    *(short4v*)(sm + 4352 + eo) = (short4v){(short)lv[0],(short)lv[1],(short)lv[2],(short)lv[3]};
                }
            }
        }
        __syncthreads();
        if (MT == 4){
            for (int idx = tid; idx < 1024; idx += 256){
                int pl = idx >> 9, e = idx & 511;
                int col = e >> 4, q8 = e & 15;
                short8 vv = *(const short8*)(sm + (pl ? 4352 : 0) + col*136 + q8*8);
                u16* dst = (pl ? outL : outH)
                    + ((size_t)b*LP_ + POFF + n0 + p*32 + col)*CHp_out + mblk*BM + q8*8;
                *(short8*)dst = vv;
            }
        }
        __syncthreads();
    }
}

// ---------------- softmax over L per (b,c) row, in place ----------------
__global__ __launch_bounds__(256) void softmax_k(float* __restrict__ S){
    int row = blockIdx.x, t = threadIdx.x;
    float* p = S + (size_t)row*L_;
    __shared__ float sh[256];
    float mx = -1e30f;
    for (int j = t; j < L_; j += 256) mx = fmaxf(mx, p[j]);
    sh[t] = mx; __syncthreads();
    for (int o = 128; o > 0; o >>= 1){ if (t < o) sh[t] = fmaxf(sh[t], sh[t+o]); __syncthreads(); }
    float m = sh[0]; __syncthreads();
    float sum = 0.f;
    for (int j = t; j < L_; j += 256){ float e = expf(p[j] - m); p[j] = e; sum += e; }
    sh[t] = sum; __syncthreads();
    for (int o = 128; o > 0; o >>= 1){ if (t < o) sh[t] += sh[t+o]; __syncthreads(); }
    float inv = 1.0f / sh[0];
    for (int j = t; j < L_; j += 256) p[j] *= inv;
}

// ---------------- V[b][c][f] = sum_l t[l][f] * A[c][l] ----------------
// t from hi/lo planes [b][col][128]; grid (32 L-chunks of 128, B).
__global__ __launch_bounds__(256) void v_accum2_k(const u16* __restrict__ tH,
                                                  const u16* __restrict__ tL,
                                                  const float* __restrict__ S,
                                                  float* __restrict__ V){
    __shared__ float As[C_*65];
    __shared__ float Ts[64*104];
    int cx = blockIdx.x, b = blockIdx.y, tid = threadIdx.x;
    int c = tid/5, qq = tid%5, f0 = qq*20;
    float acc[20];
    #pragma unroll
    for (int i = 0; i < 20; ++i) acc[i] = 0.f;
    for (int sub = 0; sub < 2; ++sub){
        int l0 = cx*128 + sub*64;
        for (int idx = tid; idx < C_*64; idx += 256){
            int cc = idx >> 6, col = idx & 63;
            As[cc*65 + col] = S[((size_t)b*C_ + cc)*L_ + l0 + col];
        }
        for (int idx = tid; idx < 64*13; idx += 256){
            int col = idx/13, g = idx%13;
            size_t o = ((size_t)b*LP_ + POFF + l0 + col)*128 + g*8;
            short8 hh = *(const short8*)(tH + o);
            short8 ll = *(const short8*)(tL + o);
            #pragma unroll
            for (int i = 0; i < 8; ++i)
                Ts[col*104 + g*8 + i] = b2f((u16)hh[i]) + b2f((u16)ll[i]);
        }
        __syncthreads();
        if (c < C_){
            for (int col = 0; col < 64; ++col){
                float a = As[c*65 + col];
                #pragma unroll
                for (int ff = 0; ff < 20; ++ff)
                    acc[ff] = fmaf(a, Ts[col*104 + f0 + ff], acc[ff]);
            }
        }
        __syncthreads();
    }
    if (c < C_){
        float* vp = V + ((size_t)b*C_ + c)*F_ + f0;
        #pragma unroll
        for (int ff = 0; ff < 20; ++ff) atomicAdd(vp + ff, acc[ff]);
    }
}

// ---------------- GCN ----------------
__global__ void gather_nodes_k(const int* __restrict__ nodes, const float* __restrict__ emb,
                               float* __restrict__ ne){
    int idx = blockIdx.x*256 + threadIdx.x;
    if (idx >= B_*NN_*D_) return;
    int d = idx & 255, n = (idx >> 8) & 511, b = idx >> 17;
    ne[idx] = emb[(size_t)nodes[b*NN_ + n]*D_ + d];
}
__global__ void deg_count_k(const int* __restrict__ edges, int* __restrict__ deg){
    int idx = blockIdx.x*256 + threadIdx.x;
    if (idx >= B_*EE_) return;
    int b = idx >> 13, e = idx & (EE_-1);
    int dst = edges[b*2*EE_ + EE_ + e];
    atomicAdd(&deg[b*NN_ + dst], 1);
}
__global__ void dinv_k(const int* __restrict__ deg, float* __restrict__ dinv){
    int i = blockIdx.x*256 + threadIdx.x;
    if (i < B_*NN_) dinv[i] = 1.0f / sqrtf((float)deg[i]);
}
__global__ void scan_csr_k(const int* __restrict__ deg, int* __restrict__ rp, int* __restrict__ cur){
    int b = blockIdx.x, t = threadIdx.x;    // 512 threads
    __shared__ int sh[NN_];
    int v = deg[b*NN_ + t];
    sh[t] = v; __syncthreads();
    for (int off = 1; off < NN_; off <<= 1){
        int x = (t >= off) ? sh[t-off] : 0;
        __syncthreads();
        sh[t] += x;
        __syncthreads();
    }
    int incl = sh[t], excl = incl - v;
    rp[b*513 + t] = excl;
    cur[b*NN_ + t] = excl;
    if (t == NN_-1) rp[b*513 + NN_] = incl;
}
__global__ void fill_csr_k(const int* __restrict__ edges, int* __restrict__ cur, int* __restrict__ adj){
    int e = blockIdx.x*256 + threadIdx.x, b = blockIdx.y;
    if (e >= ADJ_) return;
    int s, d;
    if (e < EE_){ s = edges[b*2*EE_ + e]; d = edges[b*2*EE_ + EE_ + e]; }
    else        { s = d = e - EE_; }
    int pos = atomicAdd(&cur[b*NN_ + d], 1);
    adj[b*ADJ_ + pos] = s;
}
__global__ __launch_bounds__(256) void gemm_nt_k(const float* __restrict__ A,
                                                 const float* __restrict__ W,
                                                 float* __restrict__ out){
    int b = blockIdx.z, n0 = blockIdx.x*64, i0 = blockIdx.y*64;
    __shared__ float aL[64][17], wL[64][17];
    int tid = threadIdx.x, tx = tid & 15, ty = tid >> 4;
    const float* Ab = A + (size_t)b*NN_*D_;
    float acc[4][4];
    #pragma unroll
    for (int r = 0; r < 4; ++r)
        #pragma unroll
        for (int i = 0; i < 4; ++i) acc[r][i] = 0.f;
    for (int j0 = 0; j0 < D_; j0 += 16){
        for (int idx = tid; idx < 1024; idx += 256){
            int r = idx >> 4, cc = idx & 15;
            aL[r][cc] = Ab[(size_t)(n0+r)*D_ + j0 + cc];
            wL[r][cc] = W[(size_t)(i0+r)*D_ + j0 + cc];
        }
        __syncthreads();
        #pragma unroll
        for (int kk = 0; kk < 16; ++kk){
            float av[4], wv[4];
            #pragma unroll
            for (int r = 0; r < 4; ++r) av[r] = aL[ty*4+r][kk];
            #pragma unroll
            for (int i = 0; i < 4; ++i) wv[i] = wL[tx*4+i][kk];
            #pragma unroll
            for (int r = 0; r < 4; ++r)
                #pragma unroll
                for (int i = 0; i < 4; ++i) acc[r][i] = fmaf(av[r], wv[i], acc[r][i]);
        }
        __syncthreads();
    }
    float* ob = out + (size_t)b*NN_*D_;
    #pragma unroll
    for (int r = 0; r < 4; ++r)
        #pragma unroll
        for (int i = 0; i < 4; ++i)
            ob[(size_t)(n0+ty*4+r)*D_ + i0+tx*4+i] = acc[r][i];
}
__global__ __launch_bounds__(256) void scatter_k(const float* __restrict__ xw,
                                                 const int* __restrict__ adj,
                                                 const int* __restrict__ rp,
                                                 const float* __restrict__ dinv,
                                                 const float* __restrict__ bias,
                                                 float* __restrict__ out,
                                                 int out_bs, int out_ld, int relu){
    int n = blockIdx.x, b = blockIdx.y, t = threadIdx.x;
    const int* rpb = rp + b*513;
    const int* adjb = adj + b*ADJ_;
    const float* xwb = xw + (size_t)b*NN_*D_;
    const float* dvb = dinv + b*NN_;
    int e0 = rpb[n], e1 = rpb[n+1];
    float acc = 0.f;
    for (int e = e0; e < e1; ++e){
        int s = adjb[e];
        acc = fmaf(xwb[(size_t)s*D_ + t], dvb[s], acc);
    }
    float v = fmaf(acc, dvb[n], bias[t]);
    if (relu) v = fmaxf(v, 0.f);
    out[(size_t)b*out_bs + (size_t)n*out_ld + t] = v;
}

// ---------------- concat V parts into out_cat cols [256,560) ----------------
__global__ void concat_v_k(const float* __restrict__ V, float* __restrict__ oc){
    int idx = blockIdx.x*256 + threadIdx.x;
    if (idx >= B_*C_*304) return;
    int p = idx % 304, c = (idx/304) % C_, b = idx/(304*C_);
    float v = 0.f;
    if      (p < 100) v = V[((size_t)(0*B_ + b)*C_ + c)*F_ + p];
    else if (p < 200) v = V[((size_t)(1*B_ + b)*C_ + c)*F_ + (p-100)];
    else if (p < 300) v = V[((size_t)(2*B_ + b)*C_ + c)*F_ + (p-200)];
    oc[((size_t)b*C_ + c)*OC_ + 256 + p] = v;
}

// ---------------- fused head ----------------
__global__ __launch_bounds__(128) void final_k(const float* __restrict__ oc,
                                               const float* __restrict__ w1t,
                                               const float* __restrict__ b1,
                                               const float* __restrict__ w2,
                                               const float* __restrict__ b2,
                                               float* __restrict__ y){
    int c = blockIdx.x, b = blockIdx.y, h = threadIdx.x;
    __shared__ float row[OC_];
    __shared__ float red[128];
    const float* src = oc + ((size_t)b*C_ + c)*OC_;
    for (int j = h; j < OC_; j += 128) row[j] = src[j];
    __syncthreads();
    float acc = b1[h];
    #pragma unroll 8
    for (int j = 0; j < OC_; ++j) acc = fmaf(row[j], w1t[j*128 + h], acc);
    float hid = fmaxf(acc, 0.f);
    red[h] = hid * w2[c*128 + h];
    __syncthreads();
    for (int o = 64; o > 0; o >>= 1){ if (h < o) red[h] += red[h+o]; __syncthreads(); }
    if (h == 0) y[b*C_ + c] = red[0] + b2[c];
}

// ===========================================================================
extern "C" void kernel_launch(void* const* d_in, const int* in_sizes, int n_in,
                              void* d_out, int out_size, void* d_ws, size_t ws_size,
                              hipStream_t stream){
    (void)in_sizes; (void)n_in; (void)out_size; (void)ws_size;
    const int*   x          = (const int*)d_in[0];
    const int*   nodes      = (const int*)d_in[2];
    const int*   edges      = (const int*)d_in[3];
    const float* word_emb   = (const float*)d_in[4];
    const float* entity_emb = (const float*)d_in[5];
    const float* convw[3]   = {(const float*)d_in[6], (const float*)d_in[9],  (const float*)d_in[12]};
    const float* convb[3]   = {(const float*)d_in[7], (const float*)d_in[10], (const float*)d_in[13]};
    const float* resw[3]    = {(const float*)d_in[8], (const float*)d_in[11], (const float*)d_in[14]};
    const float* bn_gamma   = (const float*)d_in[15];
    const float* bn_beta    = (const float*)d_in[16];
    const float* attn_w     = (const float*)d_in[17];
    const float* attn_u     = (const float*)d_in[18];
    const float* gc1_w      = (const float*)d_in[19];
    const float* gc1_b      = (const float*)d_in[20];
    const float* gc2_w      = (const float*)d_in[21];
    const float* gc2_b      = (const float*)d_in[22];
    const float* fin1_w     = (const float*)d_in[23];
    const float* fin1_b     = (const float*)d_in[24];
    const float* fin2_w     = (const float*)d_in[25];
    const float* fin2_b     = (const float*)d_in[26];
    float* y = (float*)d_out;

    char* base = (char*)d_ws;
    size_t off = 0;
    auto alloc = [&](size_t elems, size_t esz) -> char* {
        char* p = base + off;
        off += ((elems*esz + 255) / 256) * 256;
        return p;
    };
    u16* hH  = (u16*)alloc((size_t)B_*LP_*D_, 2);
    u16* hL  = (u16*)alloc((size_t)B_*LP_*D_, 2);
    u16* t0H = (u16*)alloc((size_t)B_*LP_*128, 2);
    u16* t0L = (u16*)alloc((size_t)B_*LP_*128, 2);
    u16* t1H = (u16*)alloc((size_t)B_*LP_*128, 2);
    u16* t1L = (u16*)alloc((size_t)B_*LP_*128, 2);
    u16* ZH  = (u16*)alloc((size_t)B_*LP_*256, 2);
    u16* ZL  = (u16*)alloc((size_t)B_*LP_*256, 2);
    float* S    = (float*)alloc((size_t)B_*C_*L_, 4);
    float* V    = (float*)alloc((size_t)3*B_*C_*F_, 4);
    float* ne   = (float*)alloc((size_t)B_*NN_*D_, 4);
    float* xw   = (float*)alloc((size_t)B_*NN_*D_, 4);
    float* g1   = (float*)alloc((size_t)B_*NN_*D_, 4);
    float* ocat = (float*)alloc((size_t)B_*C_*OC_, 4);
    u16* wf_c1 = (u16*)alloc((size_t)9*8*8*1024, 2);
    u16* wf_r1 = (u16*)alloc((size_t)9*4*8*1024, 2);
    u16* wf_r2 = (u16*)alloc((size_t)9*4*8*1024, 2);
    u16* wf_aw = (u16*)alloc((size_t)1*4*16*1024, 2);
    u16* wf_au = (u16*)alloc((size_t)1*8*4*1024, 2);
    float* w1t   = (float*)alloc((size_t)OC_*128, 4);
    float* dinvp = (float*)alloc((size_t)B_*NN_, 4);
    int* deg = (int*)alloc((size_t)B_*NN_, 4);
    int* rpB = (int*)alloc((size_t)B_*513, 4);
    int* cur = (int*)alloc((size_t)B_*NN_, 4);
    int* adj = (int*)alloc((size_t)B_*ADJ_, 4);

    // ---- init ----
    fill_f_k<<<CDIV(3*B_*C_*F_,256),256,0,stream>>>(V, 3*B_*C_*F_, 0.f);
    fill_i_k<<<CDIV(B_*NN_,256),256,0,stream>>>(deg, B_*NN_, 1);
    zero_pads2_k<<<CDIV(B_*16*128,256),256,0,stream>>>(t0H, t0L, 128);
    zero_pads2_k<<<CDIV(B_*16*128,256),256,0,stream>>>(t1H, t1L, 128);
    zero_pads2_k<<<CDIV(B_*16*256,256),256,0,stream>>>(ZH, ZL, 256);

    // ---- embedding ----
    embed2_k<<<dim3(LP_/16, B_),256,0,stream>>>(x, word_emb, hH, hL);

    // ---- GCN ----
    gather_nodes_k<<<CDIV(B_*NN_*D_,256),256,0,stream>>>(nodes, entity_emb, ne);
    deg_count_k<<<CDIV(B_*EE_,256),256,0,stream>>>(edges, deg);
    dinv_k<<<CDIV(B_*NN_,256),256,0,stream>>>(deg, dinvp);
    scan_csr_k<<<B_,NN_,0,stream>>>(deg, rpB, cur);
    fill_csr_k<<<dim3(CDIV(ADJ_,256),B_),256,0,stream>>>(edges, cur, adj);
    gemm_nt_k<<<dim3(NN_/64, D_/64, B_),256,0,stream>>>(ne, gc1_w, xw);
    scatter_k<<<dim3(NN_,B_),256,0,stream>>>(xw, adj, rpB, dinvp, gc1_b, g1, NN_*D_, D_, 1);
    gemm_nt_k<<<dim3(NN_/64, D_/64, B_),256,0,stream>>>(g1, gc2_w, xw);
    scatter_k<<<dim3(C_,B_),256,0,stream>>>(xw, adj, rpB, dinvp, gc2_b, ocat, C_*OC_, OC_, 0);

    // ---- encoder branches ----
    const int ks[3] = {3, 5, 9};
    for (int br = 0; br < 3; ++br){
        int k = ks[br];
        frag_w_k<<<CDIV(k*8*8*512,256),256,0,stream>>>(convw[br], wf_c1, F_, 256, k, 8, 8);
        frag_w_k<<<CDIV(k*4*8*512,256),256,0,stream>>>(resw[br], wf_r1, F_, F_, k, 4, 8);
        frag_w_k<<<CDIV(k*4*8*512,256),256,0,stream>>>(resw[br] + (size_t)F_*F_*k, wf_r2, F_, F_, k, 4, 8);
        frag_w_k<<<CDIV(4*16*512,256),256,0,stream>>>(attn_w + (size_t)br*A_*F_, wf_aw, A_, F_, 1, 4, 16);
        frag_w_k<<<CDIV(8*4*512,256),256,0,stream>>>(attn_u + (size_t)br*C_*A_, wf_au, C_, A_, 1, 8, 4);
        const float* gam = bn_gamma + br*300;
        const float* bet = bn_beta + br*300;
        dim3 g1d(32, B_, 1), g2d(32, B_, 2);
        // conv1: h -> t0 (mode 0)
        if (k == 3)      conv_mfma_k<3,4><<<g1d,256,0,stream>>>(hH,hL,256,8, wf_c1,8, convb[br],gam,bet,F_, t0H,t0L,128, nullptr,0);
        else if (k == 5) conv_mfma_k<5,4><<<g1d,256,0,stream>>>(hH,hL,256,8, wf_c1,8, convb[br],gam,bet,F_, t0H,t0L,128, nullptr,0);
        else             conv_mfma_k<9,4><<<g1d,256,0,stream>>>(hH,hL,256,8, wf_c1,8, convb[br],gam,bet,F_, t0H,t0L,128, nullptr,0);
        // res1: t0 -> t1 (mode 1)
        if (k == 3)      conv_mfma_k<3,4><<<g1d,256,0,stream>>>(t0H,t0L,128,4, wf_r1,8, nullptr,gam+100,bet+100,F_, t1H,t1L,128, nullptr,1);
        else if (k == 5) conv_mfma_k<5,4><<<g1d,256,0,stream>>>(t0H,t0L,128,4, wf_r1,8, nullptr,gam+100,bet+100,F_, t1H,t1L,128, nullptr,1);
        else             conv_mfma_k<9,4><<<g1d,256,0,stream>>>(t0H,t0L,128,4, wf_r1,8, nullptr,gam+100,bet+100,F_, t1H,t1L,128, nullptr,1);
        // res2: t1 -> t0 (mode 1)
        if (k == 3)      conv_mfma_k<3,4><<<g1d,256,0,stream>>>(t1H,t1L,128,4, wf_r2,8, nullptr,gam+200,bet+200,F_, t0H,t0L,128, nullptr,1);
        else if (k == 5) conv_mfma_k<5,4><<<g1d,256,0,stream>>>(t1H,t1L,128,4, wf_r2,8, nullptr,gam+200,bet+200,F_, t0H,t0L,128, nullptr,1);
        else             conv_mfma_k<9,4><<<g1d,256,0,stream>>>(t1H,t1L,128,4, wf_r2,8, nullptr,gam+200,bet+200,F_, t0H,t0L,128, nullptr,1);
        // Z = tanh(aw . t): t0 -> Z (mode 2), M=256 via grid z=2
        conv_mfma_k<1,4><<<g2d,256,0,stream>>>(t0H,t0L,128,4, wf_aw,16, nullptr,nullptr,nullptr,256, ZH,ZL,256, nullptr,2);
        // logits = au . Z: Z -> S (mode 3), M=50 (block M=64)
        conv_mfma_k<1,2><<<g1d,256,0,stream>>>(ZH,ZL,256,8, wf_au,4, nullptr,nullptr,nullptr,C_, nullptr,nullptr,0, S,3);
        softmax_k<<<B_*C_,256,0,stream>>>(S);
        v_accum2_k<<<dim3(32, B_),256,0,stream>>>(t0H, t0L, S, V + (size_t)br*B_*C_*F_);
    }

    // ---- head ----
    transpose_fin1_k<<<CDIV(OC_*128,256),256,0,stream>>>(fin1_w, w1t);
    concat_v_k<<<CDIV(B_*C_*304,256),256,0,stream>>>(V, ocat);
    final_k<<<dim3(C_,B_),128,0,stream>>>(ocat, w1t, fin1_b, fin2_w, fin2_b, y);
}

// Round 4
// 1279.038 us; speedup vs baseline: 2.8650x; 1.9265x over previous
//
#include <hip/hip_runtime.h>

// ---------------------------------------------------------------------------
// Model_81990925681018 — Round 4: R3 structure with the attn_k staging fix
// (full 128-channel t-slab; R3 staged only half -> uninit-LDS NaNs ->
// fmaxf(NaN,0)=0 -> all-zero output). Single-bf16 MFMA convs, 64-col tiles,
// fused attention (Z stays in LDS).
// ---------------------------------------------------------------------------

#define CDIV(a,b) (((a)+(b)-1)/(b))

#define B_    16
#define L_    4096
#define D_    256
#define LP_   4112      // L + 2*POFF
#define POFF  8
#define F_    100
#define A_    256
#define C_    50
#define NN_   512
#define EE_   8192
#define ADJ_  8704
#define OC_   560

#define WFC1_STRIDE ((size_t)9*8*8*512)   // per-branch conv1 frag stride (shorts)
#define WFRES_STRIDE ((size_t)9*4*8*512)  // per (branch,block) res frag stride
#define WFAW_STRIDE ((size_t)4*16*512)
#define WFAU_STRIDE ((size_t)8*4*512)

typedef unsigned short u16;
using short8  = __attribute__((ext_vector_type(8))) short;
using short4v = __attribute__((ext_vector_type(4))) short;
using f32x4   = __attribute__((ext_vector_type(4))) float;

__device__ __forceinline__ u16 f2b(float f){
    unsigned u = __float_as_uint(f);
    u += 0x7FFF + ((u >> 16) & 1);
    return (u16)(u >> 16);
}
__device__ __forceinline__ float b2f(u16 h){ return __uint_as_float(((unsigned)h) << 16); }

// ---------------- utility fills ----------------
__global__ void fill_f_k(float* p, int n, float v){
    int i = blockIdx.x*256 + threadIdx.x; if (i < n) p[i] = v;
}
__global__ void fill_i_k(int* p, int n, int v){
    int i = blockIdx.x*256 + threadIdx.x; if (i < n) p[i] = v;
}
// zero the 8 left + 8 right pad cols of a plane [b][LP_][128]
__global__ void zero_pads1_k(u16* p){
    int idx = blockIdx.x*256 + threadIdx.x;
    if (idx >= B_*16*128) return;
    int ch = idx & 127; int rest = idx >> 7;
    int pc = rest & 15; int b = rest >> 4;
    int col = (pc < 8) ? pc : (4096 + pc);
    p[((size_t)b*LP_ + col)*128 + ch] = 0;
}

// ---------------- embedding gather -> bf16 plane [b][col][256] -------------
__global__ __launch_bounds__(256) void embed1_k(const int* __restrict__ x,
                                                const float* __restrict__ emb,
                                                u16* __restrict__ hH){
    int b = blockIdx.y;
    int col = blockIdx.x*8 + (threadIdx.x >> 5);
    int cg  = (threadIdx.x & 31) * 8;
    size_t o = ((size_t)b*LP_ + col)*D_ + cg;
    int l = col - POFF;
    short8 h0;
    if (l < 0 || l >= L_){
        #pragma unroll
        for (int i = 0; i < 8; ++i) h0[i] = 0;
    } else {
        int tok = x[b*L_ + l];
        const float* s = emb + (size_t)tok*D_ + cg;
        #pragma unroll
        for (int i = 0; i < 8; ++i) h0[i] = (short)f2b(s[i]);
    }
    *(short8*)(hH + o) = h0;
}

// ---------------- weight -> MFMA A-fragment packer (single plane) ----------
// dst layout: rest = (j*nch + cc)*MTtot + mt; dst[rest*512 + lane*8 + i]
// element: m = mt*16 + (lane&15), ch = cc*32 + (lane>>4)*8 + i
__device__ __forceinline__ void pack_frag(const float* src, u16* dst,
                                          int M, int K, int kt, int nch, int MTtot, int idx){
    int i = idx & 7, lane = (idx >> 3) & 63, rest = idx >> 9;
    int mt = rest % MTtot, r2 = rest / MTtot;
    int cc = r2 % nch,  j = r2 / nch;
    int m  = mt*16 + (lane & 15);
    int ch = cc*32 + (lane >> 4)*8 + i;
    float v = (m < M && ch < K) ? src[((size_t)m*K + ch)*kt + j] : 0.f;
    dst[(size_t)rest*512 + lane*8 + i] = f2b(v);
}
__global__ void pack_conv1_k(const float* w3, const float* w5, const float* w9, u16* dst){
    int br = blockIdx.y;
    int k = (br == 0) ? 3 : (br == 1) ? 5 : 9;
    const float* s = (br == 0) ? w3 : (br == 1) ? w5 : w9;
    int idx = blockIdx.x*256 + threadIdx.x;
    if (idx < k*8*8*512) pack_frag(s, dst + (size_t)br*WFC1_STRIDE, F_, 256, k, 8, 8, idx);
}
__global__ void pack_res_k(const float* w3, const float* w5, const float* w9, u16* dst){
    int br = blockIdx.y, blk = blockIdx.z;
    int k = (br == 0) ? 3 : (br == 1) ? 5 : 9;
    const float* s = ((br == 0) ? w3 : (br == 1) ? w5 : w9) + (size_t)blk*F_*F_*k;
    int idx = blockIdx.x*256 + threadIdx.x;
    if (idx < k*4*8*512) pack_frag(s, dst + (size_t)(br*2 + blk)*WFRES_STRIDE, F_, F_, k, 4, 8, idx);
}
__global__ void pack_aw_k(const float* aw, u16* dst){
    int br = blockIdx.y;
    int idx = blockIdx.x*256 + threadIdx.x;
    if (idx < 4*16*512) pack_frag(aw + (size_t)br*A_*F_, dst + (size_t)br*WFAW_STRIDE, A_, F_, 1, 4, 16, idx);
}
__global__ void pack_au_k(const float* au, u16* dst){
    int br = blockIdx.y;
    int idx = blockIdx.x*256 + threadIdx.x;
    if (idx < 8*4*512) pack_frag(au + (size_t)br*C_*A_, dst + (size_t)br*WFAU_STRIDE, C_, A_, 1, 8, 4, idx);
}
// fin1_w[128][556] -> w1t[560][128] zero-padded
__global__ void transpose_fin1_k(const float* __restrict__ src, float* __restrict__ dst){
    int idx = blockIdx.x*256 + threadIdx.x;
    if (idx >= OC_*128) return;
    int h = idx & 127, j = idx >> 7;
    dst[idx] = (j < 556) ? src[h*556 + j] : 0.f;
}

// ---------------- MFMA shifted-GEMM conv, 64-col tile ----------------------
// Block 256 thr, waves 2x2 (wm: M-half of 128, wn: 32-col half).
// MODE 0: tanh(acc+bias)*s+beta ; MODE 1: tanh(acc*s+beta+resid)
template<int KT, int MODE>
__global__ __launch_bounds__(256) void conv_mfma_k(
    const u16* __restrict__ in, int CHp_in, int nch,
    const u16* __restrict__ wf,
    const float* __restrict__ bias, const float* __restrict__ gamma,
    const float* __restrict__ beta,
    u16* __restrict__ out)
{
    __shared__ short sm[4352];   // staging 80*40=3200 ; epilogue pass 32*136=4352
    const int tid = threadIdx.x, lane = tid & 63;
    const int w = tid >> 6, wm = w >> 1, wn = w & 1;
    const int q = lane >> 4, lr = lane & 15;
    const int n0 = blockIdx.x * 64;
    const int b  = blockIdx.y;
    const u16* inb = in + (size_t)b*LP_*CHp_in;

    f32x4 acc[4][2];
    #pragma unroll
    for (int t = 0; t < 4; ++t)
        #pragma unroll
        for (int n = 0; n < 2; ++n) acc[t][n] = (f32x4){0.f,0.f,0.f,0.f};

    for (int cc = 0; cc < nch; ++cc){
        // stage 80 cols x 32 ch (padded col n0..n0+80 == real n0-8..n0+72)
        for (int idx = tid; idx < 320; idx += 256){
            int col = idx >> 2, qq = idx & 3;
            *(short8*)(sm + col*40 + qq*8) =
                *(const short8*)(inb + (size_t)(n0 + col)*CHp_in + cc*32 + qq*8);
        }
        __syncthreads();
        const u16* fpb = wf + (size_t)(cc*8 + wm*4)*512 + lane*8;
        short8 Ac[4];
        #pragma unroll
        for (int t = 0; t < 4; ++t) Ac[t] = *(const short8*)(fpb + (size_t)t*512);
        #pragma unroll
        for (int j = 0; j < KT; ++j){
            short8 An[4];
            if (j + 1 < KT){
                const u16* fn = fpb + (size_t)(j+1)*nch*8*512;
                #pragma unroll
                for (int t = 0; t < 4; ++t) An[t] = *(const short8*)(fn + (size_t)t*512);
            }
            int sc0 = 8 - (KT >> 1) + j + wn*32 + lr;
            short8 Bv[2];
            #pragma unroll
            for (int n = 0; n < 2; ++n)
                Bv[n] = *(const short8*)(sm + (sc0 + n*16)*40 + q*8);
            #pragma unroll
            for (int t = 0; t < 4; ++t)
                #pragma unroll
                for (int n = 0; n < 2; ++n)
                    acc[t][n] = __builtin_amdgcn_mfma_f32_16x16x32_bf16(Ac[t], Bv[n], acc[t][n], 0,0,0);
            if (j + 1 < KT){
                #pragma unroll
                for (int t = 0; t < 4; ++t) Ac[t] = An[t];
            }
        }
        __syncthreads();
    }

    // ---- epilogue: transpose to [col][128] plane via LDS, 2 passes of 32 cols
    const float BNS = 0.9999950000374997f; // 1/sqrt(1+1e-5)
    for (int p = 0; p < 2; ++p){
        if (wn == p){
            #pragma unroll
            for (int t = 0; t < 4; ++t){
                #pragma unroll
                for (int n = 0; n < 2; ++n){
                    int mbase = wm*64 + t*16 + q*4;
                    int cl = n*16 + lr;
                    int colg = n0 + p*32 + cl;
                    float rsum[4] = {0.f,0.f,0.f,0.f};
                    if (MODE == 1){
                        size_t ro = ((size_t)b*LP_ + POFF + colg)*CHp_in + mbase;
                        short4v rh = *(const short4v*)(in + ro);
                        #pragma unroll
                        for (int r = 0; r < 4; ++r) rsum[r] = b2f((u16)rh[r]);
                    }
                    short4v hv;
                    #pragma unroll
                    for (int r = 0; r < 4; ++r){
                        int mm = mbase + r;
                        float a = acc[t][n][r];
                        float v;
                        if (MODE == 0){
                            float bi=0.f, s=0.f, be=0.f;
                            if (mm < F_){ bi = bias[mm]; s = gamma[mm]*BNS; be = beta[mm]; }
                            v = tanhf(a + bi)*s + be;
                        } else {
                            float s=0.f, be=0.f;
                            if (mm < F_){ s = gamma[mm]*BNS; be = beta[mm]; }
                            v = tanhf(fmaf(a, s, be) + rsum[r]);
                        }
                        hv[r] = (short)f2b(v);
                    }
                    *(short4v*)(sm + cl*136 + mbase) = hv;
                }
            }
        }
        __syncthreads();
        for (int idx = tid; idx < 512; idx += 256){
            int col = idx >> 4, q8 = idx & 15;
            short8 vv = *(const short8*)(sm + col*136 + q8*8);
            *(short8*)(out + ((size_t)b*LP_ + POFF + n0 + p*32 + col)*128 + q8*8) = vv;
        }
        __syncthreads();
    }
}

// ---------------- fused attention: S = au . tanh(aw . t), Z in LDS ---------
// Block: 128-col tile. Phase1: Z(256 x 128cols) in acc regs (2x2 waves).
// Two col-half passes: Z half -> LDS (bf16) -> phase2 (all waves) -> S.
__global__ __launch_bounds__(256) void attn_k(const u16* __restrict__ tpl,
                                              const u16* __restrict__ awf,
                                              const u16* __restrict__ auf,
                                              float* __restrict__ S){
    __shared__ short sm[17408];   // t-slab 128*136 ; reused as Z 64*264
    const int tid = threadIdx.x, lane = tid & 63;
    const int w = tid >> 6, wm = w >> 1, wn = w & 1;
    const int q = lane >> 4, lr = lane & 15;
    const int n0 = blockIdx.x * 128;
    const int b  = blockIdx.y;

    // stage t: 128 cols x 128 ch  (FIX: full 2048 short8 groups, was 1024)
    for (int idx = tid; idx < 2048; idx += 256){
        int col = idx >> 4, g = idx & 15;
        *(short8*)(sm + col*136 + g*8) =
            *(const short8*)(tpl + ((size_t)b*LP_ + POFF + n0 + col)*128 + g*8);
    }
    __syncthreads();

    // phase 1: wave (wm,wn): a in [wm*128, wm*128+128), cols [wn*64, wn*64+64)
    f32x4 acc1[8][4];
    #pragma unroll
    for (int t = 0; t < 8; ++t)
        #pragma unroll
        for (int n = 0; n < 4; ++n) acc1[t][n] = (f32x4){0.f,0.f,0.f,0.f};
    for (int cc = 0; cc < 4; ++cc){
        short8 Af[8];
        const u16* fp = awf + (size_t)(cc*16 + wm*8)*512 + lane*8;
        #pragma unroll
        for (int t = 0; t < 8; ++t) Af[t] = *(const short8*)(fp + (size_t)t*512);
        short8 Bf[4];
        #pragma unroll
        for (int n = 0; n < 4; ++n)
            Bf[n] = *(const short8*)(sm + (wn*64 + n*16 + lr)*136 + cc*32 + q*8);
        #pragma unroll
        for (int t = 0; t < 8; ++t)
            #pragma unroll
            for (int n = 0; n < 4; ++n)
                acc1[t][n] = __builtin_amdgcn_mfma_f32_16x16x32_bf16(Af[t], Bf[n], acc1[t][n], 0,0,0);
    }
    __syncthreads();   // t-slab dead

    for (int p = 0; p < 2; ++p){
        if (wn == p){
            #pragma unroll
            for (int t = 0; t < 8; ++t){
                #pragma unroll
                for (int n = 0; n < 4; ++n){
                    int abase = wm*128 + t*16 + q*4;
                    int cl = n*16 + lr;
                    short4v zv;
                    #pragma unroll
                    for (int r = 0; r < 4; ++r) zv[r] = (short)f2b(tanhf(acc1[t][n][r]));
                    *(short4v*)(sm + cl*264 + abase) = zv;
                }
            }
        }
        __syncthreads();
        // phase 2: all waves; wave w covers 16 cols
        f32x4 acc2[4];
        #pragma unroll
        for (int t = 0; t < 4; ++t) acc2[t] = (f32x4){0.f,0.f,0.f,0.f};
        for (int cc = 0; cc < 8; ++cc){
            short8 Af2[4];
            const u16* fp2 = auf + (size_t)(cc*4)*512 + lane*8;
            #pragma unroll
            for (int t = 0; t < 4; ++t) Af2[t] = *(const short8*)(fp2 + (size_t)t*512);
            short8 Bf2 = *(const short8*)(sm + (w*16 + lr)*264 + cc*32 + q*8);
            #pragma unroll
            for (int t = 0; t < 4; ++t)
                acc2[t] = __builtin_amdgcn_mfma_f32_16x16x32_bf16(Af2[t], Bf2, acc2[t], 0,0,0);
        }
        #pragma unroll
        for (int t = 0; t < 4; ++t)
            #pragma unroll
            for (int r = 0; r < 4; ++r){
                int c = t*16 + q*4 + r;
                if (c < C_) S[((size_t)b*C_ + c)*L_ + n0 + p*64 + w*16 + lr] = acc2[t][r];
            }
        __syncthreads();
    }
}

// ---------------- softmax over L per (b,c) row, in place ----------------
__global__ __launch_bounds__(256) void softmax_k(float* __restrict__ S){
    int row = blockIdx.x, t = threadIdx.x;
    float* p = S + (size_t)row*L_;
    __shared__ float sh[256];
    float mx = -1e30f;
    for (int j = t; j < L_; j += 256) mx = fmaxf(mx, p[j]);
    sh[t] = mx; __syncthreads();
    for (int o = 128; o > 0; o >>= 1){ if (t < o) sh[t] = fmaxf(sh[t], sh[t+o]); __syncthreads(); }
    float m = sh[0]; __syncthreads();
    float sum = 0.f;
    for (int j = t; j < L_; j += 256){ float e = expf(p[j] - m); p[j] = e; sum += e; }
    sh[t] = sum; __syncthreads();
    for (int o = 128; o > 0; o >>= 1){ if (t < o) sh[t] += sh[t+o]; __syncthreads(); }
    float inv = 1.0f / sh[0];
    for (int j = t; j < L_; j += 256) p[j] *= inv;
}

// ---------------- V[b][c][f] = sum_l t[l][f] * A[c][l] ----------------
__global__ __launch_bounds__(256) void v_accum2_k(const u16* __restrict__ tH,
                                                  const float* __restrict__ S,
                                                  float* __restrict__ V){
    __shared__ float As[C_*65];
    __shared__ float Ts[64*104];
    int cx = blockIdx.x, b = blockIdx.y, tid = threadIdx.x;
    int c = tid/5, qq = tid%5, f0 = qq*20;
    float acc[20];
    #pragma unroll
    for (int i = 0; i < 20; ++i) acc[i] = 0.f;
    for (int sub = 0; sub < 2; ++sub){
        int l0 = cx*128 + sub*64;
        for (int idx = tid; idx < C_*64; idx += 256){
            int cc = idx >> 6, col = idx & 63;
            As[cc*65 + col] = S[((size_t)b*C_ + cc)*L_ + l0 + col];
        }
        for (int idx = tid; idx < 64*13; idx += 256){
            int col = idx/13, g = idx%13;
            size_t o = ((size_t)b*LP_ + POFF + l0 + col)*128 + g*8;
            short8 hh = *(const short8*)(tH + o);
            #pragma unroll
            for (int i = 0; i < 8; ++i)
                Ts[col*104 + g*8 + i] = b2f((u16)hh[i]);
        }
        __syncthreads();
        if (c < C_){
            for (int col = 0; col < 64; ++col){
                float a = As[c*65 + col];
                #pragma unroll
                for (int ff = 0; ff < 20; ++ff)
                    acc[ff] = fmaf(a, Ts[col*104 + f0 + ff], acc[ff]);
            }
        }
        __syncthreads();
    }
    if (c < C_){
        float* vp = V + ((size_t)b*C_ + c)*F_ + f0;
        #pragma unroll
        for (int ff = 0; ff < 20; ++ff) atomicAdd(vp + ff, acc[ff]);
    }
}

// ---------------- GCN ----------------
__global__ void gather_nodes_k(const int* __restrict__ nodes, const float* __restrict__ emb,
                               float* __restrict__ ne){
    int idx = blockIdx.x*256 + threadIdx.x;
    if (idx >= B_*NN_*D_) return;
    int d = idx & 255, n = (idx >> 8) & 511, b = idx >> 17;
    ne[idx] = emb[(size_t)nodes[b*NN_ + n]*D_ + d];
}
__global__ void deg_count_k(const int* __restrict__ edges, int* __restrict__ deg){
    int idx = blockIdx.x*256 + threadIdx.x;
    if (idx >= B_*EE_) return;
    int b = idx >> 13, e = idx & (EE_-1);
    int dst = edges[b*2*EE_ + EE_ + e];
    atomicAdd(&deg[b*NN_ + dst], 1);
}
__global__ void dinv_k(const int* __restrict__ deg, float* __restrict__ dinv){
    int i = blockIdx.x*256 + threadIdx.x;
    if (i < B_*NN_) dinv[i] = 1.0f / sqrtf((float)deg[i]);
}
__global__ void scan_csr_k(const int* __restrict__ deg, int* __restrict__ rp, int* __restrict__ cur){
    int b = blockIdx.x, t = threadIdx.x;    // 512 threads
    __shared__ int sh[NN_];
    int v = deg[b*NN_ + t];
    sh[t] = v; __syncthreads();
    for (int off = 1; off < NN_; off <<= 1){
        int x = (t >= off) ? sh[t-off] : 0;
        __syncthreads();
        sh[t] += x;
        __syncthreads();
    }
    int incl = sh[t], excl = incl - v;
    rp[b*513 + t] = excl;
    cur[b*NN_ + t] = excl;
    if (t == NN_-1) rp[b*513 + NN_] = incl;
}
__global__ void fill_csr_k(const int* __restrict__ edges, int* __restrict__ cur, int* __restrict__ adj){
    int e = blockIdx.x*256 + threadIdx.x, b = blockIdx.y;
    if (e >= ADJ_) return;
    int s, d;
    if (e < EE_){ s = edges[b*2*EE_ + e]; d = edges[b*2*EE_ + EE_ + e]; }
    else        { s = d = e - EE_; }
    int pos = atomicAdd(&cur[b*NN_ + d], 1);
    adj[b*ADJ_ + pos] = s;
}
__global__ __launch_bounds__(256) void gemm_nt_k(const float* __restrict__ A,
                                                 const float* __restrict__ W,
                                                 float* __restrict__ out){
    int b = blockIdx.z, n0 = blockIdx.x*64, i0 = blockIdx.y*64;
    __shared__ float aL[64][17], wL[64][17];
    int tid = threadIdx.x, tx = tid & 15, ty = tid >> 4;
    const float* Ab = A + (size_t)b*NN_*D_;
    float acc[4][4];
    #pragma unroll
    for (int r = 0; r < 4; ++r)
        #pragma unroll
        for (int i = 0; i < 4; ++i) acc[r][i] = 0.f;
    for (int j0 = 0; j0 < D_; j0 += 16){
        for (int idx = tid; idx < 1024; idx += 256){
            int r = idx >> 4, cc = idx & 15;
            aL[r][cc] = Ab[(size_t)(n0+r)*D_ + j0 + cc];
            wL[r][cc] = W[(size_t)(i0+r)*D_ + j0 + cc];
        }
        __syncthreads();
        #pragma unroll
        for (int kk = 0; kk < 16; ++kk){
            float av[4], wv[4];
            #pragma unroll
            for (int r = 0; r < 4; ++r) av[r] = aL[ty*4+r][kk];
            #pragma unroll
            for (int i = 0; i < 4; ++i) wv[i] = wL[tx*4+i][kk];
            #pragma unroll
            for (int r = 0; r < 4; ++r)
                #pragma unroll
                for (int i = 0; i < 4; ++i) acc[r][i] = fmaf(av[r], wv[i], acc[r][i]);
        }
        __syncthreads();
    }
    float* ob = out + (size_t)b*NN_*D_;
    #pragma unroll
    for (int r = 0; r < 4; ++r)
        #pragma unroll
        for (int i = 0; i < 4; ++i)
            ob[(size_t)(n0+ty*4+r)*D_ + i0+tx*4+i] = acc[r][i];
}
__global__ __launch_bounds__(256) void scatter_k(const float* __restrict__ xw,
                                                 const int* __restrict__ adj,
                                                 const int* __restrict__ rp,
                                                 const float* __restrict__ dinv,
                                                 const float* __restrict__ bias,
                                                 float* __restrict__ out,
                                                 int out_bs, int out_ld, int relu){
    int n = blockIdx.x, b = blockIdx.y, t = threadIdx.x;
    const int* rpb = rp + b*513;
    const int* adjb = adj + b*ADJ_;
    const float* xwb = xw + (size_t)b*NN_*D_;
    const float* dvb = dinv + b*NN_;
    int e0 = rpb[n], e1 = rpb[n+1];
    float acc = 0.f;
    for (int e = e0; e < e1; ++e){
        int s = adjb[e];
        acc = fmaf(xwb[(size_t)s*D_ + t], dvb[s], acc);
    }
    float v = fmaf(acc, dvb[n], bias[t]);
    if (relu) v = fmaxf(v, 0.f);
    out[(size_t)b*out_bs + (size_t)n*out_ld + t] = v;
}

// ---------------- concat V parts into out_cat cols [256,560) ----------------
__global__ void concat_v_k(const float* __restrict__ V, float* __restrict__ oc){
    int idx = blockIdx.x*256 + threadIdx.x;
    if (idx >= B_*C_*304) return;
    int p = idx % 304, c = (idx/304) % C_, b = idx/(304*C_);
    float v = 0.f;
    if      (p < 100) v = V[((size_t)(0*B_ + b)*C_ + c)*F_ + p];
    else if (p < 200) v = V[((size_t)(1*B_ + b)*C_ + c)*F_ + (p-100)];
    else if (p < 300) v = V[((size_t)(2*B_ + b)*C_ + c)*F_ + (p-200)];
    oc[((size_t)b*C_ + c)*OC_ + 256 + p] = v;
}

// ---------------- fused head ----------------
__global__ __launch_bounds__(128) void final_k(const float* __restrict__ oc,
                                               const float* __restrict__ w1t,
                                               const float* __restrict__ b1,
                                               const float* __restrict__ w2,
                                               const float* __restrict__ b2,
                                               float* __restrict__ y){
    int c = blockIdx.x, b = blockIdx.y, h = threadIdx.x;
    __shared__ float row[OC_];
    __shared__ float red[128];
    const float* src = oc + ((size_t)b*C_ + c)*OC_;
    for (int j = h; j < OC_; j += 128) row[j] = src[j];
    __syncthreads();
    float acc = b1[h];
    #pragma unroll 8
    for (int j = 0; j < OC_; ++j) acc = fmaf(row[j], w1t[j*128 + h], acc);
    float hid = fmaxf(acc, 0.f);
    red[h] = hid * w2[c*128 + h];
    __syncthreads();
    for (int o = 64; o > 0; o >>= 1){ if (h < o) red[h] += red[h+o]; __syncthreads(); }
    if (h == 0) y[b*C_ + c] = red[0] + b2[c];
}

// ===========================================================================
extern "C" void kernel_launch(void* const* d_in, const int* in_sizes, int n_in,
                              void* d_out, int out_size, void* d_ws, size_t ws_size,
                              hipStream_t stream){
    (void)in_sizes; (void)n_in; (void)out_size; (void)ws_size;
    const int*   x          = (const int*)d_in[0];
    const int*   nodes      = (const int*)d_in[2];
    const int*   edges      = (const int*)d_in[3];
    const float* word_emb   = (const float*)d_in[4];
    const float* entity_emb = (const float*)d_in[5];
    const float* convb[3]   = {(const float*)d_in[7], (const float*)d_in[10], (const float*)d_in[13]};
    const float* bn_gamma   = (const float*)d_in[15];
    const float* bn_beta    = (const float*)d_in[16];
    const float* gc1_w      = (const float*)d_in[19];
    const float* gc1_b      = (const float*)d_in[20];
    const float* gc2_w      = (const float*)d_in[21];
    const float* gc2_b      = (const float*)d_in[22];
    const float* fin1_w     = (const float*)d_in[23];
    const float* fin1_b     = (const float*)d_in[24];
    const float* fin2_w     = (const float*)d_in[25];
    const float* fin2_b     = (const float*)d_in[26];
    float* y = (float*)d_out;

    char* base = (char*)d_ws;
    size_t off = 0;
    auto alloc = [&](size_t elems, size_t esz) -> char* {
        char* p = base + off;
        off += ((elems*esz + 255) / 256) * 256;
        return p;
    };
    u16* hH  = (u16*)alloc((size_t)B_*LP_*D_, 2);
    u16* t0  = (u16*)alloc((size_t)B_*LP_*128, 2);
    u16* t1  = (u16*)alloc((size_t)B_*LP_*128, 2);
    float* S    = (float*)alloc((size_t)B_*C_*L_, 4);
    float* V    = (float*)alloc((size_t)3*B_*C_*F_, 4);
    float* ne   = (float*)alloc((size_t)B_*NN_*D_, 4);
    float* xw   = (float*)alloc((size_t)B_*NN_*D_, 4);
    float* g1   = (float*)alloc((size_t)B_*NN_*D_, 4);
    float* ocat = (float*)alloc((size_t)B_*C_*OC_, 4);
    u16* wfc1  = (u16*)alloc(3*WFC1_STRIDE, 2);
    u16* wfres = (u16*)alloc(6*WFRES_STRIDE, 2);
    u16* wfaw  = (u16*)alloc(3*WFAW_STRIDE, 2);
    u16* wfau  = (u16*)alloc(3*WFAU_STRIDE, 2);
    float* w1t   = (float*)alloc((size_t)OC_*128, 4);
    float* dinvp = (float*)alloc((size_t)B_*NN_, 4);
    int* deg = (int*)alloc((size_t)B_*NN_, 4);
    int* rpB = (int*)alloc((size_t)B_*513, 4);
    int* cur = (int*)alloc((size_t)B_*NN_, 4);
    int* adj = (int*)alloc((size_t)B_*ADJ_, 4);

    // ---- init & weight packing ----
    fill_f_k<<<CDIV(3*B_*C_*F_,256),256,0,stream>>>(V, 3*B_*C_*F_, 0.f);
    fill_i_k<<<CDIV(B_*NN_,256),256,0,stream>>>(deg, B_*NN_, 1);
    zero_pads1_k<<<CDIV(B_*16*128,256),256,0,stream>>>(t0);
    zero_pads1_k<<<CDIV(B_*16*128,256),256,0,stream>>>(t1);
    pack_conv1_k<<<dim3(CDIV(9*8*8*512,256),3),256,0,stream>>>(
        (const float*)d_in[6], (const float*)d_in[9], (const float*)d_in[12], wfc1);
    pack_res_k<<<dim3(CDIV(9*4*8*512,256),3,2),256,0,stream>>>(
        (const float*)d_in[8], (const float*)d_in[11], (const float*)d_in[14], wfres);
    pack_aw_k<<<dim3(CDIV(4*16*512,256),3),256,0,stream>>>((const float*)d_in[17], wfaw);
    pack_au_k<<<dim3(CDIV(8*4*512,256),3),256,0,stream>>>((const float*)d_in[18], wfau);

    // ---- embedding ----
    embed1_k<<<dim3(LP_/8, B_),256,0,stream>>>(x, word_emb, hH);

    // ---- GCN ----
    gather_nodes_k<<<CDIV(B_*NN_*D_,256),256,0,stream>>>(nodes, entity_emb, ne);
    deg_count_k<<<CDIV(B_*EE_,256),256,0,stream>>>(edges, deg);
    dinv_k<<<CDIV(B_*NN_,256),256,0,stream>>>(deg, dinvp);
    scan_csr_k<<<B_,NN_,0,stream>>>(deg, rpB, cur);
    fill_csr_k<<<dim3(CDIV(ADJ_,256),B_),256,0,stream>>>(edges, cur, adj);
    gemm_nt_k<<<dim3(NN_/64, D_/64, B_),256,0,stream>>>(ne, gc1_w, xw);
    scatter_k<<<dim3(NN_,B_),256,0,stream>>>(xw, adj, rpB, dinvp, gc1_b, g1, NN_*D_, D_, 1);
    gemm_nt_k<<<dim3(NN_/64, D_/64, B_),256,0,stream>>>(g1, gc2_w, xw);
    scatter_k<<<dim3(C_,B_),256,0,stream>>>(xw, adj, rpB, dinvp, gc2_b, ocat, C_*OC_, OC_, 0);

    // ---- encoder branches ----
    dim3 gc(64, B_), ga(32, B_);
    for (int br = 0; br < 3; ++br){
        const float* gam = bn_gamma + br*300;
        const float* bet = bn_beta + br*300;
        const u16* wc = wfc1 + (size_t)br*WFC1_STRIDE;
        const u16* wr1 = wfres + (size_t)(br*2+0)*WFRES_STRIDE;
        const u16* wr2 = wfres + (size_t)(br*2+1)*WFRES_STRIDE;
        if (br == 0){
            conv_mfma_k<3,0><<<gc,256,0,stream>>>(hH,256,8, wc, convb[br],gam,bet, t0);
            conv_mfma_k<3,1><<<gc,256,0,stream>>>(t0,128,4, wr1, nullptr,gam+100,bet+100, t1);
            conv_mfma_k<3,1><<<gc,256,0,stream>>>(t1,128,4, wr2, nullptr,gam+200,bet+200, t0);
        } else if (br == 1){
            conv_mfma_k<5,0><<<gc,256,0,stream>>>(hH,256,8, wc, convb[br],gam,bet, t0);
            conv_mfma_k<5,1><<<gc,256,0,stream>>>(t0,128,4, wr1, nullptr,gam+100,bet+100, t1);
            conv_mfma_k<5,1><<<gc,256,0,stream>>>(t1,128,4, wr2, nullptr,gam+200,bet+200, t0);
        } else {
            conv_mfma_k<9,0><<<gc,256,0,stream>>>(hH,256,8, wc, convb[br],gam,bet, t0);
            conv_mfma_k<9,1><<<gc,256,0,stream>>>(t0,128,4, wr1, nullptr,gam+100,bet+100, t1);
            conv_mfma_k<9,1><<<gc,256,0,stream>>>(t1,128,4, wr2, nullptr,gam+200,bet+200, t0);
        }
        attn_k<<<ga,256,0,stream>>>(t0, wfaw + (size_t)br*WFAW_STRIDE,
                                    wfau + (size_t)br*WFAU_STRIDE, S);
        softmax_k<<<B_*C_,256,0,stream>>>(S);
        v_accum2_k<<<dim3(32, B_),256,0,stream>>>(t0, S, V + (size_t)br*B_*C_*F_);
    }

    // ---- head ----
    transpose_fin1_k<<<CDIV(OC_*128,256),256,0,stream>>>(fin1_w, w1t);
    concat_v_k<<<CDIV(B_*C_*304,256),256,0,stream>>>(V, ocat);
    final_k<<<dim3(C_,B_),128,0,stream>>>(ocat, w1t, fin1_b, fin2_w, fin2_b, y);
}

// Round 5
// 1048.730 us; speedup vs baseline: 3.4942x; 1.2196x over previous
//
#include <hip/hip_runtime.h>

// ---------------------------------------------------------------------------
// Model_81990925681018 — Round 5: replace scalar-LDS v_accum (3x170us, 3% VALU)
// with a zero-LDS MFMA GEMM fed by a transposed t-plane written in the res2
// conv epilogue. S padded to 64 rows/b so B-frags need no row guard.
// ---------------------------------------------------------------------------

#define CDIV(a,b) (((a)+(b)-1)/(b))

#define B_    16
#define L_    4096
#define D_    256
#define LP_   4112      // L + 2*POFF
#define POFF  8
#define F_    100
#define A_    256
#define C_    50
#define NN_   512
#define EE_   8192
#define ADJ_  8704
#define OC_   560

#define WFC1_STRIDE ((size_t)9*8*8*512)   // per-branch conv1 frag stride (shorts)
#define WFRES_STRIDE ((size_t)9*4*8*512)  // per (branch,block) res frag stride
#define WFAW_STRIDE ((size_t)4*16*512)
#define WFAU_STRIDE ((size_t)8*4*512)

typedef unsigned short u16;
using short8  = __attribute__((ext_vector_type(8))) short;
using short4v = __attribute__((ext_vector_type(4))) short;
using f32x4   = __attribute__((ext_vector_type(4))) float;

__device__ __forceinline__ u16 f2b(float f){
    unsigned u = __float_as_uint(f);
    u += 0x7FFF + ((u >> 16) & 1);
    return (u16)(u >> 16);
}
__device__ __forceinline__ float b2f(u16 h){ return __uint_as_float(((unsigned)h) << 16); }

// ---------------- utility fills ----------------
__global__ void fill_f_k(float* p, int n, float v){
    int i = blockIdx.x*256 + threadIdx.x; if (i < n) p[i] = v;
}
__global__ void fill_i_k(int* p, int n, int v){
    int i = blockIdx.x*256 + threadIdx.x; if (i < n) p[i] = v;
}
// zero the 8 left + 8 right pad cols of a plane [b][LP_][128]
__global__ void zero_pads1_k(u16* p){
    int idx = blockIdx.x*256 + threadIdx.x;
    if (idx >= B_*16*128) return;
    int ch = idx & 127; int rest = idx >> 7;
    int pc = rest & 15; int b = rest >> 4;
    int col = (pc < 8) ? pc : (4096 + pc);
    p[((size_t)b*LP_ + col)*128 + ch] = 0;
}

// ---------------- embedding gather -> bf16 plane [b][col][256] -------------
__global__ __launch_bounds__(256) void embed1_k(const int* __restrict__ x,
                                                const float* __restrict__ emb,
                                                u16* __restrict__ hH){
    int b = blockIdx.y;
    int col = blockIdx.x*8 + (threadIdx.x >> 5);
    int cg  = (threadIdx.x & 31) * 8;
    size_t o = ((size_t)b*LP_ + col)*D_ + cg;
    int l = col - POFF;
    short8 h0;
    if (l < 0 || l >= L_){
        #pragma unroll
        for (int i = 0; i < 8; ++i) h0[i] = 0;
    } else {
        int tok = x[b*L_ + l];
        const float* s = emb + (size_t)tok*D_ + cg;
        #pragma unroll
        for (int i = 0; i < 8; ++i) h0[i] = (short)f2b(s[i]);
    }
    *(short8*)(hH + o) = h0;
}

// ---------------- weight -> MFMA A-fragment packer (single plane) ----------
__device__ __forceinline__ void pack_frag(const float* src, u16* dst,
                                          int M, int K, int kt, int nch, int MTtot, int idx){
    int i = idx & 7, lane = (idx >> 3) & 63, rest = idx >> 9;
    int mt = rest % MTtot, r2 = rest / MTtot;
    int cc = r2 % nch,  j = r2 / nch;
    int m  = mt*16 + (lane & 15);
    int ch = cc*32 + (lane >> 4)*8 + i;
    float v = (m < M && ch < K) ? src[((size_t)m*K + ch)*kt + j] : 0.f;
    dst[(size_t)rest*512 + lane*8 + i] = f2b(v);
}
__global__ void pack_conv1_k(const float* w3, const float* w5, const float* w9, u16* dst){
    int br = blockIdx.y;
    int k = (br == 0) ? 3 : (br == 1) ? 5 : 9;
    const float* s = (br == 0) ? w3 : (br == 1) ? w5 : w9;
    int idx = blockIdx.x*256 + threadIdx.x;
    if (idx < k*8*8*512) pack_frag(s, dst + (size_t)br*WFC1_STRIDE, F_, 256, k, 8, 8, idx);
}
__global__ void pack_res_k(const float* w3, const float* w5, const float* w9, u16* dst){
    int br = blockIdx.y, blk = blockIdx.z;
    int k = (br == 0) ? 3 : (br == 1) ? 5 : 9;
    const float* s = ((br == 0) ? w3 : (br == 1) ? w5 : w9) + (size_t)blk*F_*F_*k;
    int idx = blockIdx.x*256 + threadIdx.x;
    if (idx < k*4*8*512) pack_frag(s, dst + (size_t)(br*2 + blk)*WFRES_STRIDE, F_, F_, k, 4, 8, idx);
}
__global__ void pack_aw_k(const float* aw, u16* dst){
    int br = blockIdx.y;
    int idx = blockIdx.x*256 + threadIdx.x;
    if (idx < 4*16*512) pack_frag(aw + (size_t)br*A_*F_, dst + (size_t)br*WFAW_STRIDE, A_, F_, 1, 4, 16, idx);
}
__global__ void pack_au_k(const float* au, u16* dst){
    int br = blockIdx.y;
    int idx = blockIdx.x*256 + threadIdx.x;
    if (idx < 8*4*512) pack_frag(au + (size_t)br*C_*A_, dst + (size_t)br*WFAU_STRIDE, C_, A_, 1, 8, 4, idx);
}
// fin1_w[128][556] -> w1t[560][128] zero-padded
__global__ void transpose_fin1_k(const float* __restrict__ src, float* __restrict__ dst){
    int idx = blockIdx.x*256 + threadIdx.x;
    if (idx >= OC_*128) return;
    int h = idx & 127, j = idx >> 7;
    dst[idx] = (j < 556) ? src[h*556 + j] : 0.f;
}

// ---------------- MFMA shifted-GEMM conv, 64-col tile ----------------------
// Block 256 thr, waves 2x2 (wm: M-half of 128, wn: 32-col half).
// MODE 0: tanh(acc+bias)*s+beta ; MODE 1: tanh(acc*s+beta+resid)
// outT (optional): transposed plane [b][f][L_] for the V-GEMM's A-operand.
template<int KT, int MODE>
__global__ __launch_bounds__(256) void conv_mfma_k(
    const u16* __restrict__ in, int CHp_in, int nch,
    const u16* __restrict__ wf,
    const float* __restrict__ bias, const float* __restrict__ gamma,
    const float* __restrict__ beta,
    u16* __restrict__ out, u16* __restrict__ outT)
{
    __shared__ short sm[4352];   // staging 80*40=3200 ; epilogue pass 32*136=4352
    const int tid = threadIdx.x, lane = tid & 63;
    const int w = tid >> 6, wm = w >> 1, wn = w & 1;
    const int q = lane >> 4, lr = lane & 15;
    const int n0 = blockIdx.x * 64;
    const int b  = blockIdx.y;
    const u16* inb = in + (size_t)b*LP_*CHp_in;

    f32x4 acc[4][2];
    #pragma unroll
    for (int t = 0; t < 4; ++t)
        #pragma unroll
        for (int n = 0; n < 2; ++n) acc[t][n] = (f32x4){0.f,0.f,0.f,0.f};

    for (int cc = 0; cc < nch; ++cc){
        for (int idx = tid; idx < 320; idx += 256){
            int col = idx >> 2, qq = idx & 3;
            *(short8*)(sm + col*40 + qq*8) =
                *(const short8*)(inb + (size_t)(n0 + col)*CHp_in + cc*32 + qq*8);
        }
        __syncthreads();
        const u16* fpb = wf + (size_t)(cc*8 + wm*4)*512 + lane*8;
        short8 Ac[4];
        #pragma unroll
        for (int t = 0; t < 4; ++t) Ac[t] = *(const short8*)(fpb + (size_t)t*512);
        #pragma unroll
        for (int j = 0; j < KT; ++j){
            short8 An[4];
            if (j + 1 < KT){
                const u16* fn = fpb + (size_t)(j+1)*nch*8*512;
                #pragma unroll
                for (int t = 0; t < 4; ++t) An[t] = *(const short8*)(fn + (size_t)t*512);
            }
            int sc0 = 8 - (KT >> 1) + j + wn*32 + lr;
            short8 Bv[2];
            #pragma unroll
            for (int n = 0; n < 2; ++n)
                Bv[n] = *(const short8*)(sm + (sc0 + n*16)*40 + q*8);
            #pragma unroll
            for (int t = 0; t < 4; ++t)
                #pragma unroll
                for (int n = 0; n < 2; ++n)
                    acc[t][n] = __builtin_amdgcn_mfma_f32_16x16x32_bf16(Ac[t], Bv[n], acc[t][n], 0,0,0);
            if (j + 1 < KT){
                #pragma unroll
                for (int t = 0; t < 4; ++t) Ac[t] = An[t];
            }
        }
        __syncthreads();
    }

    // ---- epilogue: transpose to [col][128] plane via LDS, 2 passes of 32 cols
    const float BNS = 0.9999950000374997f; // 1/sqrt(1+1e-5)
    for (int p = 0; p < 2; ++p){
        if (wn == p){
            #pragma unroll
            for (int t = 0; t < 4; ++t){
                #pragma unroll
                for (int n = 0; n < 2; ++n){
                    int mbase = wm*64 + t*16 + q*4;
                    int cl = n*16 + lr;
                    int colg = n0 + p*32 + cl;
                    float rsum[4] = {0.f,0.f,0.f,0.f};
                    if (MODE == 1){
                        size_t ro = ((size_t)b*LP_ + POFF + colg)*CHp_in + mbase;
                        short4v rh = *(const short4v*)(in + ro);
                        #pragma unroll
                        for (int r = 0; r < 4; ++r) rsum[r] = b2f((u16)rh[r]);
                    }
                    short4v hv;
                    #pragma unroll
                    for (int r = 0; r < 4; ++r){
                        int mm = mbase + r;
                        float a = acc[t][n][r];
                        float v;
                        if (MODE == 0){
                            float bi=0.f, s=0.f, be=0.f;
                            if (mm < F_){ bi = bias[mm]; s = gamma[mm]*BNS; be = beta[mm]; }
                            v = tanhf(a + bi)*s + be;
                        } else {
                            float s=0.f, be=0.f;
                            if (mm < F_){ s = gamma[mm]*BNS; be = beta[mm]; }
                            v = tanhf(fmaf(a, s, be) + rsum[r]);
                        }
                        hv[r] = (short)f2b(v);
                    }
                    *(short4v*)(sm + cl*136 + mbase) = hv;
                }
            }
        }
        __syncthreads();
        for (int idx = tid; idx < 512; idx += 256){
            int col = idx >> 4, q8 = idx & 15;
            short8 vv = *(const short8*)(sm + col*136 + q8*8);
            *(short8*)(out + ((size_t)b*LP_ + POFF + n0 + p*32 + col)*128 + q8*8) = vv;
        }
        if (outT){
            // also emit transposed plane: [b][f][l], 128 f x 32 l per pass
            int f = tid & 127, half = tid >> 7;
            u16 vals[16];
            #pragma unroll
            for (int i = 0; i < 16; ++i) vals[i] = (u16)sm[(half*16 + i)*136 + f];
            short8 v0, v1;
            #pragma unroll
            for (int i = 0; i < 8; ++i){ v0[i] = (short)vals[i]; v1[i] = (short)vals[8+i]; }
            u16* dst = outT + ((size_t)b*128 + f)*L_ + n0 + p*32 + half*16;
            *(short8*)dst = v0;
            *(short8*)(dst + 8) = v1;
        }
        __syncthreads();
    }
}

// ---------------- fused attention: S = au . tanh(aw . t), Z in LDS ---------
// S padded to 64 rows per b; rows 50..63 are exact zeros (au pad).
__global__ __launch_bounds__(256) void attn_k(const u16* __restrict__ tpl,
                                              const u16* __restrict__ awf,
                                              const u16* __restrict__ auf,
                                              float* __restrict__ S){
    __shared__ short sm[17408];   // t-slab 128*136 ; reused as Z 64*264
    const int tid = threadIdx.x, lane = tid & 63;
    const int w = tid >> 6, wm = w >> 1, wn = w & 1;
    const int q = lane >> 4, lr = lane & 15;
    const int n0 = blockIdx.x * 128;
    const int b  = blockIdx.y;

    for (int idx = tid; idx < 2048; idx += 256){
        int col = idx >> 4, g = idx & 15;
        *(short8*)(sm + col*136 + g*8) =
            *(const short8*)(tpl + ((size_t)b*LP_ + POFF + n0 + col)*128 + g*8);
    }
    __syncthreads();

    f32x4 acc1[8][4];
    #pragma unroll
    for (int t = 0; t < 8; ++t)
        #pragma unroll
        for (int n = 0; n < 4; ++n) acc1[t][n] = (f32x4){0.f,0.f,0.f,0.f};
    for (int cc = 0; cc < 4; ++cc){
        short8 Af[8];
        const u16* fp = awf + (size_t)(cc*16 + wm*8)*512 + lane*8;
        #pragma unroll
        for (int t = 0; t < 8; ++t) Af[t] = *(const short8*)(fp + (size_t)t*512);
        short8 Bf[4];
        #pragma unroll
        for (int n = 0; n < 4; ++n)
            Bf[n] = *(const short8*)(sm + (wn*64 + n*16 + lr)*136 + cc*32 + q*8);
        #pragma unroll
        for (int t = 0; t < 8; ++t)
            #pragma unroll
            for (int n = 0; n < 4; ++n)
                acc1[t][n] = __builtin_amdgcn_mfma_f32_16x16x32_bf16(Af[t], Bf[n], acc1[t][n], 0,0,0);
    }
    __syncthreads();

    for (int p = 0; p < 2; ++p){
        if (wn == p){
            #pragma unroll
            for (int t = 0; t < 8; ++t){
                #pragma unroll
                for (int n = 0; n < 4; ++n){
                    int abase = wm*128 + t*16 + q*4;
                    int cl = n*16 + lr;
                    short4v zv;
                    #pragma unroll
                    for (int r = 0; r < 4; ++r) zv[r] = (short)f2b(tanhf(acc1[t][n][r]));
                    *(short4v*)(sm + cl*264 + abase) = zv;
                }
            }
        }
        __syncthreads();
        f32x4 acc2[4];
        #pragma unroll
        for (int t = 0; t < 4; ++t) acc2[t] = (f32x4){0.f,0.f,0.f,0.f};
        for (int cc = 0; cc < 8; ++cc){
            short8 Af2[4];
            const u16* fp2 = auf + (size_t)(cc*4)*512 + lane*8;
            #pragma unroll
            for (int t = 0; t < 4; ++t) Af2[t] = *(const short8*)(fp2 + (size_t)t*512);
            short8 Bf2 = *(const short8*)(sm + (w*16 + lr)*264 + cc*32 + q*8);
            #pragma unroll
            for (int t = 0; t < 4; ++t)
                acc2[t] = __builtin_amdgcn_mfma_f32_16x16x32_bf16(Af2[t], Bf2, acc2[t], 0,0,0);
        }
        #pragma unroll
        for (int t = 0; t < 4; ++t)
            #pragma unroll
            for (int r = 0; r < 4; ++r){
                int c = t*16 + q*4 + r;   // 0..63, padded S
                S[((size_t)b*64 + c)*L_ + n0 + p*64 + w*16 + lr] = acc2[t][r];
            }
        __syncthreads();
    }
}

// ---------------- softmax over L per (b,c) row, in place (padded S) --------
__global__ __launch_bounds__(256) void softmax_k(float* __restrict__ S){
    int c = blockIdx.x, b = blockIdx.y, t = threadIdx.x;
    float* p = S + ((size_t)b*64 + c)*L_;
    __shared__ float sh[256];
    float mx = -1e30f;
    for (int j = t; j < L_; j += 256) mx = fmaxf(mx, p[j]);
    sh[t] = mx; __syncthreads();
    for (int o = 128; o > 0; o >>= 1){ if (t < o) sh[t] = fmaxf(sh[t], sh[t+o]); __syncthreads(); }
    float m = sh[0]; __syncthreads();
    float sum = 0.f;
    for (int j = t; j < L_; j += 256){ float e = expf(p[j] - m); p[j] = e; sum += e; }
    sh[t] = sum; __syncthreads();
    for (int o = 128; o > 0; o >>= 1){ if (t < o) sh[t] += sh[t+o]; __syncthreads(); }
    float inv = 1.0f / sh[0];
    for (int j = t; j < L_; j += 256) p[j] *= inv;
}

// ---------------- V-GEMM: V[b][c][f] += sum_l tT[b][f][l] * A[c][l] --------
// MFMA, zero LDS: A-frag (m=f) from tT contiguous; B-frag (n=c) from S rows.
// grid (32 L-chunks of 128, B). 4 waves = 4 c-tiles; 7 f-tiles; atomicAdd out.
__global__ __launch_bounds__(256) void v_mfma_k(const u16* __restrict__ tT,
                                                const float* __restrict__ S,
                                                float* __restrict__ V){
    int cx = blockIdx.x, b = blockIdx.y;
    int w = threadIdx.x >> 6, lane = threadIdx.x & 63;
    int q = lane >> 4, lr = lane & 15;
    int l0 = cx*128;
    f32x4 acc[7];
    #pragma unroll
    for (int mt = 0; mt < 7; ++mt) acc[mt] = (f32x4){0.f,0.f,0.f,0.f};
    const u16* tb = tT + (size_t)b*128*L_;
    const float* Sb = S + ((size_t)b*64 + w*16 + lr)*L_;
    #pragma unroll
    for (int kk = 0; kk < 4; ++kk){
        int l = l0 + kk*32 + q*8;
        float4 s0 = *(const float4*)(Sb + l);
        float4 s1 = *(const float4*)(Sb + l + 4);
        short8 Bf;
        Bf[0] = (short)f2b(s0.x); Bf[1] = (short)f2b(s0.y);
        Bf[2] = (short)f2b(s0.z); Bf[3] = (short)f2b(s0.w);
        Bf[4] = (short)f2b(s1.x); Bf[5] = (short)f2b(s1.y);
        Bf[6] = (short)f2b(s1.z); Bf[7] = (short)f2b(s1.w);
        #pragma unroll
        for (int mt = 0; mt < 7; ++mt){
            short8 Af = *(const short8*)(tb + (size_t)(mt*16 + lr)*L_ + l);
            acc[mt] = __builtin_amdgcn_mfma_f32_16x16x32_bf16(Af, Bf, acc[mt], 0,0,0);
        }
    }
    int c = w*16 + lr;
    if (c < C_){
        float* vb = V + ((size_t)b*C_ + c)*F_;
        #pragma unroll
        for (int mt = 0; mt < 7; ++mt)
            #pragma unroll
            for (int r = 0; r < 4; ++r){
                int f = mt*16 + q*4 + r;
                if (f < F_) atomicAdd(vb + f, acc[mt][r]);
            }
    }
}

// ---------------- GCN ----------------
__global__ void gather_nodes_k(const int* __restrict__ nodes, const float* __restrict__ emb,
                               float* __restrict__ ne){
    int idx = blockIdx.x*256 + threadIdx.x;
    if (idx >= B_*NN_*D_) return;
    int d = idx & 255, n = (idx >> 8) & 511, b = idx >> 17;
    ne[idx] = emb[(size_t)nodes[b*NN_ + n]*D_ + d];
}
__global__ void deg_count_k(const int* __restrict__ edges, int* __restrict__ deg){
    int idx = blockIdx.x*256 + threadIdx.x;
    if (idx >= B_*EE_) return;
    int b = idx >> 13, e = idx & (EE_-1);
    int dst = edges[b*2*EE_ + EE_ + e];
    atomicAdd(&deg[b*NN_ + dst], 1);
}
__global__ void dinv_k(const int* __restrict__ deg, float* __restrict__ dinv){
    int i = blockIdx.x*256 + threadIdx.x;
    if (i < B_*NN_) dinv[i] = 1.0f / sqrtf((float)deg[i]);
}
__global__ void scan_csr_k(const int* __restrict__ deg, int* __restrict__ rp, int* __restrict__ cur){
    int b = blockIdx.x, t = threadIdx.x;    // 512 threads
    __shared__ int sh[NN_];
    int v = deg[b*NN_ + t];
    sh[t] = v; __syncthreads();
    for (int off = 1; off < NN_; off <<= 1){
        int x = (t >= off) ? sh[t-off] : 0;
        __syncthreads();
        sh[t] += x;
        __syncthreads();
    }
    int incl = sh[t], excl = incl - v;
    rp[b*513 + t] = excl;
    cur[b*NN_ + t] = excl;
    if (t == NN_-1) rp[b*513 + NN_] = incl;
}
__global__ void fill_csr_k(const int* __restrict__ edges, int* __restrict__ cur, int* __restrict__ adj){
    int e = blockIdx.x*256 + threadIdx.x, b = blockIdx.y;
    if (e >= ADJ_) return;
    int s, d;
    if (e < EE_){ s = edges[b*2*EE_ + e]; d = edges[b*2*EE_ + EE_ + e]; }
    else        { s = d = e - EE_; }
    int pos = atomicAdd(&cur[b*NN_ + d], 1);
    adj[b*ADJ_ + pos] = s;
}
__global__ __launch_bounds__(256) void gemm_nt_k(const float* __restrict__ A,
                                                 const float* __restrict__ W,
                                                 float* __restrict__ out){
    int b = blockIdx.z, n0 = blockIdx.x*64, i0 = blockIdx.y*64;
    __shared__ float aL[64][17], wL[64][17];
    int tid = threadIdx.x, tx = tid & 15, ty = tid >> 4;
    const float* Ab = A + (size_t)b*NN_*D_;
    float acc[4][4];
    #pragma unroll
    for (int r = 0; r < 4; ++r)
        #pragma unroll
        for (int i = 0; i < 4; ++i) acc[r][i] = 0.f;
    for (int j0 = 0; j0 < D_; j0 += 16){
        for (int idx = tid; idx < 1024; idx += 256){
            int r = idx >> 4, cc = idx & 15;
            aL[r][cc] = Ab[(size_t)(n0+r)*D_ + j0 + cc];
            wL[r][cc] = W[(size_t)(i0+r)*D_ + j0 + cc];
        }
        __syncthreads();
        #pragma unroll
        for (int kk = 0; kk < 16; ++kk){
            float av[4], wv[4];
            #pragma unroll
            for (int r = 0; r < 4; ++r) av[r] = aL[ty*4+r][kk];
            #pragma unroll
            for (int i = 0; i < 4; ++i) wv[i] = wL[tx*4+i][kk];
            #pragma unroll
            for (int r = 0; r < 4; ++r)
                #pragma unroll
                for (int i = 0; i < 4; ++i) acc[r][i] = fmaf(av[r], wv[i], acc[r][i]);
        }
        __syncthreads();
    }
    float* ob = out + (size_t)b*NN_*D_;
    #pragma unroll
    for (int r = 0; r < 4; ++r)
        #pragma unroll
        for (int i = 0; i < 4; ++i)
            ob[(size_t)(n0+ty*4+r)*D_ + i0+tx*4+i] = acc[r][i];
}
__global__ __launch_bounds__(256) void scatter_k(const float* __restrict__ xw,
                                                 const int* __restrict__ adj,
                                                 const int* __restrict__ rp,
                                                 const float* __restrict__ dinv,
                                                 const float* __restrict__ bias,
                                                 float* __restrict__ out,
                                                 int out_bs, int out_ld, int relu){
    int n = blockIdx.x, b = blockIdx.y, t = threadIdx.x;
    const int* rpb = rp + b*513;
    const int* adjb = adj + b*ADJ_;
    const float* xwb = xw + (size_t)b*NN_*D_;
    const float* dvb = dinv + b*NN_;
    int e0 = rpb[n], e1 = rpb[n+1];
    float acc = 0.f;
    for (int e = e0; e < e1; ++e){
        int s = adjb[e];
        acc = fmaf(xwb[(size_t)s*D_ + t], dvb[s], acc);
    }
    float v = fmaf(acc, dvb[n], bias[t]);
    if (relu) v = fmaxf(v, 0.f);
    out[(size_t)b*out_bs + (size_t)n*out_ld + t] = v;
}

// ---------------- concat V parts into out_cat cols [256,560) ----------------
__global__ void concat_v_k(const float* __restrict__ V, float* __restrict__ oc){
    int idx = blockIdx.x*256 + threadIdx.x;
    if (idx >= B_*C_*304) return;
    int p = idx % 304, c = (idx/304) % C_, b = idx/(304*C_);
    float v = 0.f;
    if      (p < 100) v = V[((size_t)(0*B_ + b)*C_ + c)*F_ + p];
    else if (p < 200) v = V[((size_t)(1*B_ + b)*C_ + c)*F_ + (p-100)];
    else if (p < 300) v = V[((size_t)(2*B_ + b)*C_ + c)*F_ + (p-200)];
    oc[((size_t)b*C_ + c)*OC_ + 256 + p] = v;
}

// ---------------- fused head ----------------
__global__ __launch_bounds__(128) void final_k(const float* __restrict__ oc,
                                               const float* __restrict__ w1t,
                                               const float* __restrict__ b1,
                                               const float* __restrict__ w2,
                                               const float* __restrict__ b2,
                                               float* __restrict__ y){
    int c = blockIdx.x, b = blockIdx.y, h = threadIdx.x;
    __shared__ float row[OC_];
    __shared__ float red[128];
    const float* src = oc + ((size_t)b*C_ + c)*OC_;
    for (int j = h; j < OC_; j += 128) row[j] = src[j];
    __syncthreads();
    float acc = b1[h];
    #pragma unroll 8
    for (int j = 0; j < OC_; ++j) acc = fmaf(row[j], w1t[j*128 + h], acc);
    float hid = fmaxf(acc, 0.f);
    red[h] = hid * w2[c*128 + h];
    __syncthreads();
    for (int o = 64; o > 0; o >>= 1){ if (h < o) red[h] += red[h+o]; __syncthreads(); }
    if (h == 0) y[b*C_ + c] = red[0] + b2[c];
}

// ===========================================================================
extern "C" void kernel_launch(void* const* d_in, const int* in_sizes, int n_in,
                              void* d_out, int out_size, void* d_ws, size_t ws_size,
                              hipStream_t stream){
    (void)in_sizes; (void)n_in; (void)out_size; (void)ws_size;
    const int*   x          = (const int*)d_in[0];
    const int*   nodes      = (const int*)d_in[2];
    const int*   edges      = (const int*)d_in[3];
    const float* word_emb   = (const float*)d_in[4];
    const float* entity_emb = (const float*)d_in[5];
    const float* convb[3]   = {(const float*)d_in[7], (const float*)d_in[10], (const float*)d_in[13]};
    const float* bn_gamma   = (const float*)d_in[15];
    const float* bn_beta    = (const float*)d_in[16];
    const float* gc1_w      = (const float*)d_in[19];
    const float* gc1_b      = (const float*)d_in[20];
    const float* gc2_w      = (const float*)d_in[21];
    const float* gc2_b      = (const float*)d_in[22];
    const float* fin1_w     = (const float*)d_in[23];
    const float* fin1_b     = (const float*)d_in[24];
    const float* fin2_w     = (const float*)d_in[25];
    const float* fin2_b     = (const float*)d_in[26];
    float* y = (float*)d_out;

    char* base = (char*)d_ws;
    size_t off = 0;
    auto alloc = [&](size_t elems, size_t esz) -> char* {
        char* p = base + off;
        off += ((elems*esz + 255) / 256) * 256;
        return p;
    };
    u16* hH  = (u16*)alloc((size_t)B_*LP_*D_, 2);
    u16* t0  = (u16*)alloc((size_t)B_*LP_*128, 2);
    u16* t1  = (u16*)alloc((size_t)B_*LP_*128, 2);
    u16* tT  = (u16*)alloc((size_t)B_*128*L_, 2);
    float* S    = (float*)alloc((size_t)B_*64*L_, 4);
    float* V    = (float*)alloc((size_t)3*B_*C_*F_, 4);
    float* ne   = (float*)alloc((size_t)B_*NN_*D_, 4);
    float* xw   = (float*)alloc((size_t)B_*NN_*D_, 4);
    float* g1   = (float*)alloc((size_t)B_*NN_*D_, 4);
    float* ocat = (float*)alloc((size_t)B_*C_*OC_, 4);
    u16* wfc1  = (u16*)alloc(3*WFC1_STRIDE, 2);
    u16* wfres = (u16*)alloc(6*WFRES_STRIDE, 2);
    u16* wfaw  = (u16*)alloc(3*WFAW_STRIDE, 2);
    u16* wfau  = (u16*)alloc(3*WFAU_STRIDE, 2);
    float* w1t   = (float*)alloc((size_t)OC_*128, 4);
    float* dinvp = (float*)alloc((size_t)B_*NN_, 4);
    int* deg = (int*)alloc((size_t)B_*NN_, 4);
    int* rpB = (int*)alloc((size_t)B_*513, 4);
    int* cur = (int*)alloc((size_t)B_*NN_, 4);
    int* adj = (int*)alloc((size_t)B_*ADJ_, 4);

    // ---- init & weight packing ----
    fill_f_k<<<CDIV(3*B_*C_*F_,256),256,0,stream>>>(V, 3*B_*C_*F_, 0.f);
    fill_i_k<<<CDIV(B_*NN_,256),256,0,stream>>>(deg, B_*NN_, 1);
    zero_pads1_k<<<CDIV(B_*16*128,256),256,0,stream>>>(t0);
    zero_pads1_k<<<CDIV(B_*16*128,256),256,0,stream>>>(t1);
    pack_conv1_k<<<dim3(CDIV(9*8*8*512,256),3),256,0,stream>>>(
        (const float*)d_in[6], (const float*)d_in[9], (const float*)d_in[12], wfc1);
    pack_res_k<<<dim3(CDIV(9*4*8*512,256),3,2),256,0,stream>>>(
        (const float*)d_in[8], (const float*)d_in[11], (const float*)d_in[14], wfres);
    pack_aw_k<<<dim3(CDIV(4*16*512,256),3),256,0,stream>>>((const float*)d_in[17], wfaw);
    pack_au_k<<<dim3(CDIV(8*4*512,256),3),256,0,stream>>>((const float*)d_in[18], wfau);

    // ---- embedding ----
    embed1_k<<<dim3(LP_/8, B_),256,0,stream>>>(x, word_emb, hH);

    // ---- GCN ----
    gather_nodes_k<<<CDIV(B_*NN_*D_,256),256,0,stream>>>(nodes, entity_emb, ne);
    deg_count_k<<<CDIV(B_*EE_,256),256,0,stream>>>(edges, deg);
    dinv_k<<<CDIV(B_*NN_,256),256,0,stream>>>(deg, dinvp);
    scan_csr_k<<<B_,NN_,0,stream>>>(deg, rpB, cur);
    fill_csr_k<<<dim3(CDIV(ADJ_,256),B_),256,0,stream>>>(edges, cur, adj);
    gemm_nt_k<<<dim3(NN_/64, D_/64, B_),256,0,stream>>>(ne, gc1_w, xw);
    scatter_k<<<dim3(NN_,B_),256,0,stream>>>(xw, adj, rpB, dinvp, gc1_b, g1, NN_*D_, D_, 1);
    gemm_nt_k<<<dim3(NN_/64, D_/64, B_),256,0,stream>>>(g1, gc2_w, xw);
    scatter_k<<<dim3(C_,B_),256,0,stream>>>(xw, adj, rpB, dinvp, gc2_b, ocat, C_*OC_, OC_, 0);

    // ---- encoder branches ----
    dim3 gc(64, B_), ga(32, B_);
    for (int br = 0; br < 3; ++br){
        const float* gam = bn_gamma + br*300;
        const float* bet = bn_beta + br*300;
        const u16* wc = wfc1 + (size_t)br*WFC1_STRIDE;
        const u16* wr1 = wfres + (size_t)(br*2+0)*WFRES_STRIDE;
        const u16* wr2 = wfres + (size_t)(br*2+1)*WFRES_STRIDE;
        if (br == 0){
            conv_mfma_k<3,0><<<gc,256,0,stream>>>(hH,256,8, wc, convb[br],gam,bet, t0, nullptr);
            conv_mfma_k<3,1><<<gc,256,0,stream>>>(t0,128,4, wr1, nullptr,gam+100,bet+100, t1, nullptr);
            conv_mfma_k<3,1><<<gc,256,0,stream>>>(t1,128,4, wr2, nullptr,gam+200,bet+200, t0, tT);
        } else if (br == 1){
            conv_mfma_k<5,0><<<gc,256,0,stream>>>(hH,256,8, wc, convb[br],gam,bet, t0, nullptr);
            conv_mfma_k<5,1><<<gc,256,0,stream>>>(t0,128,4, wr1, nullptr,gam+100,bet+100, t1, nullptr);
            conv_mfma_k<5,1><<<gc,256,0,stream>>>(t1,128,4, wr2, nullptr,gam+200,bet+200, t0, tT);
        } else {
            conv_mfma_k<9,0><<<gc,256,0,stream>>>(hH,256,8, wc, convb[br],gam,bet, t0, nullptr);
            conv_mfma_k<9,1><<<gc,256,0,stream>>>(t0,128,4, wr1, nullptr,gam+100,bet+100, t1, nullptr);
            conv_mfma_k<9,1><<<gc,256,0,stream>>>(t1,128,4, wr2, nullptr,gam+200,bet+200, t0, tT);
        }
        attn_k<<<ga,256,0,stream>>>(t0, wfaw + (size_t)br*WFAW_STRIDE,
                                    wfau + (size_t)br*WFAU_STRIDE, S);
        softmax_k<<<dim3(C_,B_),256,0,stream>>>(S);
        v_mfma_k<<<dim3(32, B_),256,0,stream>>>(tT, S, V + (size_t)br*B_*C_*F_);
    }

    // ---- head ----
    transpose_fin1_k<<<CDIV(OC_*128,256),256,0,stream>>>(fin1_w, w1t);
    concat_v_k<<<CDIV(B_*C_*304,256),256,0,stream>>>(V, ocat);
    final_k<<<dim3(C_,B_),128,0,stream>>>(ocat, w1t, fin1_b, fin2_w, fin2_b, y);
}

// Round 6
// 857.965 us; speedup vs baseline: 4.2712x; 1.2223x over previous
//
#include <hip/hip_runtime.h>

// ---------------------------------------------------------------------------
// Model_81990925681018 — Round 6: v_mfma writes per-L-chunk partials (plain
// coalesced stores, no device atomics — R5's 3.67M atomicAdds onto 80K addrs
// were the 81us bottleneck); reduce_v_k sums 32 chunks and writes straight
// into ocat (absorbs concat_v + V zero-init).
// ---------------------------------------------------------------------------

#define CDIV(a,b) (((a)+(b)-1)/(b))

#define B_    16
#define L_    4096
#define D_    256
#define LP_   4112      // L + 2*POFF
#define POFF  8
#define F_    100
#define A_    256
#define C_    50
#define NN_   512
#define EE_   8192
#define ADJ_  8704
#define OC_   560

#define WFC1_STRIDE ((size_t)9*8*8*512)   // per-branch conv1 frag stride (shorts)
#define WFRES_STRIDE ((size_t)9*4*8*512)  // per (branch,block) res frag stride
#define WFAW_STRIDE ((size_t)4*16*512)
#define WFAU_STRIDE ((size_t)8*4*512)

typedef unsigned short u16;
using short8  = __attribute__((ext_vector_type(8))) short;
using short4v = __attribute__((ext_vector_type(4))) short;
using f32x4   = __attribute__((ext_vector_type(4))) float;

__device__ __forceinline__ u16 f2b(float f){
    unsigned u = __float_as_uint(f);
    u += 0x7FFF + ((u >> 16) & 1);
    return (u16)(u >> 16);
}
__device__ __forceinline__ float b2f(u16 h){ return __uint_as_float(((unsigned)h) << 16); }

// ---------------- utility fills ----------------
__global__ void fill_i_k(int* p, int n, int v){
    int i = blockIdx.x*256 + threadIdx.x; if (i < n) p[i] = v;
}
// zero the 8 left + 8 right pad cols of a plane [b][LP_][128]
__global__ void zero_pads1_k(u16* p){
    int idx = blockIdx.x*256 + threadIdx.x;
    if (idx >= B_*16*128) return;
    int ch = idx & 127; int rest = idx >> 7;
    int pc = rest & 15; int b = rest >> 4;
    int col = (pc < 8) ? pc : (4096 + pc);
    p[((size_t)b*LP_ + col)*128 + ch] = 0;
}

// ---------------- embedding gather -> bf16 plane [b][col][256] -------------
__global__ __launch_bounds__(256) void embed1_k(const int* __restrict__ x,
                                                const float* __restrict__ emb,
                                                u16* __restrict__ hH){
    int b = blockIdx.y;
    int col = blockIdx.x*8 + (threadIdx.x >> 5);
    int cg  = (threadIdx.x & 31) * 8;
    size_t o = ((size_t)b*LP_ + col)*D_ + cg;
    int l = col - POFF;
    short8 h0;
    if (l < 0 || l >= L_){
        #pragma unroll
        for (int i = 0; i < 8; ++i) h0[i] = 0;
    } else {
        int tok = x[b*L_ + l];
        const float* s = emb + (size_t)tok*D_ + cg;
        #pragma unroll
        for (int i = 0; i < 8; ++i) h0[i] = (short)f2b(s[i]);
    }
    *(short8*)(hH + o) = h0;
}

// ---------------- weight -> MFMA A-fragment packer (single plane) ----------
__device__ __forceinline__ void pack_frag(const float* src, u16* dst,
                                          int M, int K, int kt, int nch, int MTtot, int idx){
    int i = idx & 7, lane = (idx >> 3) & 63, rest = idx >> 9;
    int mt = rest % MTtot, r2 = rest / MTtot;
    int cc = r2 % nch,  j = r2 / nch;
    int m  = mt*16 + (lane & 15);
    int ch = cc*32 + (lane >> 4)*8 + i;
    float v = (m < M && ch < K) ? src[((size_t)m*K + ch)*kt + j] : 0.f;
    dst[(size_t)rest*512 + lane*8 + i] = f2b(v);
}
__global__ void pack_conv1_k(const float* w3, const float* w5, const float* w9, u16* dst){
    int br = blockIdx.y;
    int k = (br == 0) ? 3 : (br == 1) ? 5 : 9;
    const float* s = (br == 0) ? w3 : (br == 1) ? w5 : w9;
    int idx = blockIdx.x*256 + threadIdx.x;
    if (idx < k*8*8*512) pack_frag(s, dst + (size_t)br*WFC1_STRIDE, F_, 256, k, 8, 8, idx);
}
__global__ void pack_res_k(const float* w3, const float* w5, const float* w9, u16* dst){
    int br = blockIdx.y, blk = blockIdx.z;
    int k = (br == 0) ? 3 : (br == 1) ? 5 : 9;
    const float* s = ((br == 0) ? w3 : (br == 1) ? w5 : w9) + (size_t)blk*F_*F_*k;
    int idx = blockIdx.x*256 + threadIdx.x;
    if (idx < k*4*8*512) pack_frag(s, dst + (size_t)(br*2 + blk)*WFRES_STRIDE, F_, F_, k, 4, 8, idx);
}
__global__ void pack_aw_k(const float* aw, u16* dst){
    int br = blockIdx.y;
    int idx = blockIdx.x*256 + threadIdx.x;
    if (idx < 4*16*512) pack_frag(aw + (size_t)br*A_*F_, dst + (size_t)br*WFAW_STRIDE, A_, F_, 1, 4, 16, idx);
}
__global__ void pack_au_k(const float* au, u16* dst){
    int br = blockIdx.y;
    int idx = blockIdx.x*256 + threadIdx.x;
    if (idx < 8*4*512) pack_frag(au + (size_t)br*C_*A_, dst + (size_t)br*WFAU_STRIDE, C_, A_, 1, 8, 4, idx);
}
// fin1_w[128][556] -> w1t[560][128] zero-padded
__global__ void transpose_fin1_k(const float* __restrict__ src, float* __restrict__ dst){
    int idx = blockIdx.x*256 + threadIdx.x;
    if (idx >= OC_*128) return;
    int h = idx & 127, j = idx >> 7;
    dst[idx] = (j < 556) ? src[h*556 + j] : 0.f;
}

// ---------------- MFMA shifted-GEMM conv, 64-col tile ----------------------
// Block 256 thr, waves 2x2 (wm: M-half of 128, wn: 32-col half).
// MODE 0: tanh(acc+bias)*s+beta ; MODE 1: tanh(acc*s+beta+resid)
// outT (optional): transposed plane [b][f][L_] for the V-GEMM's A-operand.
template<int KT, int MODE>
__global__ __launch_bounds__(256) void conv_mfma_k(
    const u16* __restrict__ in, int CHp_in, int nch,
    const u16* __restrict__ wf,
    const float* __restrict__ bias, const float* __restrict__ gamma,
    const float* __restrict__ beta,
    u16* __restrict__ out, u16* __restrict__ outT)
{
    __shared__ short sm[4352];   // staging 80*40=3200 ; epilogue pass 32*136=4352
    const int tid = threadIdx.x, lane = tid & 63;
    const int w = tid >> 6, wm = w >> 1, wn = w & 1;
    const int q = lane >> 4, lr = lane & 15;
    const int n0 = blockIdx.x * 64;
    const int b  = blockIdx.y;
    const u16* inb = in + (size_t)b*LP_*CHp_in;

    f32x4 acc[4][2];
    #pragma unroll
    for (int t = 0; t < 4; ++t)
        #pragma unroll
        for (int n = 0; n < 2; ++n) acc[t][n] = (f32x4){0.f,0.f,0.f,0.f};

    for (int cc = 0; cc < nch; ++cc){
        for (int idx = tid; idx < 320; idx += 256){
            int col = idx >> 2, qq = idx & 3;
            *(short8*)(sm + col*40 + qq*8) =
                *(const short8*)(inb + (size_t)(n0 + col)*CHp_in + cc*32 + qq*8);
        }
        __syncthreads();
        const u16* fpb = wf + (size_t)(cc*8 + wm*4)*512 + lane*8;
        short8 Ac[4];
        #pragma unroll
        for (int t = 0; t < 4; ++t) Ac[t] = *(const short8*)(fpb + (size_t)t*512);
        #pragma unroll
        for (int j = 0; j < KT; ++j){
            short8 An[4];
            if (j + 1 < KT){
                const u16* fn = fpb + (size_t)(j+1)*nch*8*512;
                #pragma unroll
                for (int t = 0; t < 4; ++t) An[t] = *(const short8*)(fn + (size_t)t*512);
            }
            int sc0 = 8 - (KT >> 1) + j + wn*32 + lr;
            short8 Bv[2];
            #pragma unroll
            for (int n = 0; n < 2; ++n)
                Bv[n] = *(const short8*)(sm + (sc0 + n*16)*40 + q*8);
            #pragma unroll
            for (int t = 0; t < 4; ++t)
                #pragma unroll
                for (int n = 0; n < 2; ++n)
                    acc[t][n] = __builtin_amdgcn_mfma_f32_16x16x32_bf16(Ac[t], Bv[n], acc[t][n], 0,0,0);
            if (j + 1 < KT){
                #pragma unroll
                for (int t = 0; t < 4; ++t) Ac[t] = An[t];
            }
        }
        __syncthreads();
    }

    // ---- epilogue: transpose to [col][128] plane via LDS, 2 passes of 32 cols
    const float BNS = 0.9999950000374997f; // 1/sqrt(1+1e-5)
    for (int p = 0; p < 2; ++p){
        if (wn == p){
            #pragma unroll
            for (int t = 0; t < 4; ++t){
                #pragma unroll
                for (int n = 0; n < 2; ++n){
                    int mbase = wm*64 + t*16 + q*4;
                    int cl = n*16 + lr;
                    int colg = n0 + p*32 + cl;
                    float rsum[4] = {0.f,0.f,0.f,0.f};
                    if (MODE == 1){
                        size_t ro = ((size_t)b*LP_ + POFF + colg)*CHp_in + mbase;
                        short4v rh = *(const short4v*)(in + ro);
                        #pragma unroll
                        for (int r = 0; r < 4; ++r) rsum[r] = b2f((u16)rh[r]);
                    }
                    short4v hv;
                    #pragma unroll
                    for (int r = 0; r < 4; ++r){
                        int mm = mbase + r;
                        float a = acc[t][n][r];
                        float v;
                        if (MODE == 0){
                            float bi=0.f, s=0.f, be=0.f;
                            if (mm < F_){ bi = bias[mm]; s = gamma[mm]*BNS; be = beta[mm]; }
                            v = tanhf(a + bi)*s + be;
                        } else {
                            float s=0.f, be=0.f;
                            if (mm < F_){ s = gamma[mm]*BNS; be = beta[mm]; }
                            v = tanhf(fmaf(a, s, be) + rsum[r]);
                        }
                        hv[r] = (short)f2b(v);
                    }
                    *(short4v*)(sm + cl*136 + mbase) = hv;
                }
            }
        }
        __syncthreads();
        for (int idx = tid; idx < 512; idx += 256){
            int col = idx >> 4, q8 = idx & 15;
            short8 vv = *(const short8*)(sm + col*136 + q8*8);
            *(short8*)(out + ((size_t)b*LP_ + POFF + n0 + p*32 + col)*128 + q8*8) = vv;
        }
        if (outT){
            // also emit transposed plane: [b][f][l], 128 f x 32 l per pass
            int f = tid & 127, half = tid >> 7;
            u16 vals[16];
            #pragma unroll
            for (int i = 0; i < 16; ++i) vals[i] = (u16)sm[(half*16 + i)*136 + f];
            short8 v0, v1;
            #pragma unroll
            for (int i = 0; i < 8; ++i){ v0[i] = (short)vals[i]; v1[i] = (short)vals[8+i]; }
            u16* dst = outT + ((size_t)b*128 + f)*L_ + n0 + p*32 + half*16;
            *(short8*)dst = v0;
            *(short8*)(dst + 8) = v1;
        }
        __syncthreads();
    }
}

// ---------------- fused attention: S = au . tanh(aw . t), Z in LDS ---------
// S padded to 64 rows per b; rows 50..63 are exact zeros (au pad).
__global__ __launch_bounds__(256) void attn_k(const u16* __restrict__ tpl,
                                              const u16* __restrict__ awf,
                                              const u16* __restrict__ auf,
                                              float* __restrict__ S){
    __shared__ short sm[17408];   // t-slab 128*136 ; reused as Z 64*264
    const int tid = threadIdx.x, lane = tid & 63;
    const int w = tid >> 6, wm = w >> 1, wn = w & 1;
    const int q = lane >> 4, lr = lane & 15;
    const int n0 = blockIdx.x * 128;
    const int b  = blockIdx.y;

    for (int idx = tid; idx < 2048; idx += 256){
        int col = idx >> 4, g = idx & 15;
        *(short8*)(sm + col*136 + g*8) =
            *(const short8*)(tpl + ((size_t)b*LP_ + POFF + n0 + col)*128 + g*8);
    }
    __syncthreads();

    f32x4 acc1[8][4];
    #pragma unroll
    for (int t = 0; t < 8; ++t)
        #pragma unroll
        for (int n = 0; n < 4; ++n) acc1[t][n] = (f32x4){0.f,0.f,0.f,0.f};
    for (int cc = 0; cc < 4; ++cc){
        short8 Af[8];
        const u16* fp = awf + (size_t)(cc*16 + wm*8)*512 + lane*8;
        #pragma unroll
        for (int t = 0; t < 8; ++t) Af[t] = *(const short8*)(fp + (size_t)t*512);
        short8 Bf[4];
        #pragma unroll
        for (int n = 0; n < 4; ++n)
            Bf[n] = *(const short8*)(sm + (wn*64 + n*16 + lr)*136 + cc*32 + q*8);
        #pragma unroll
        for (int t = 0; t < 8; ++t)
            #pragma unroll
            for (int n = 0; n < 4; ++n)
                acc1[t][n] = __builtin_amdgcn_mfma_f32_16x16x32_bf16(Af[t], Bf[n], acc1[t][n], 0,0,0);
    }
    __syncthreads();

    for (int p = 0; p < 2; ++p){
        if (wn == p){
            #pragma unroll
            for (int t = 0; t < 8; ++t){
                #pragma unroll
                for (int n = 0; n < 4; ++n){
                    int abase = wm*128 + t*16 + q*4;
                    int cl = n*16 + lr;
                    short4v zv;
                    #pragma unroll
                    for (int r = 0; r < 4; ++r) zv[r] = (short)f2b(tanhf(acc1[t][n][r]));
                    *(short4v*)(sm + cl*264 + abase) = zv;
                }
            }
        }
        __syncthreads();
        f32x4 acc2[4];
        #pragma unroll
        for (int t = 0; t < 4; ++t) acc2[t] = (f32x4){0.f,0.f,0.f,0.f};
        for (int cc = 0; cc < 8; ++cc){
            short8 Af2[4];
            const u16* fp2 = auf + (size_t)(cc*4)*512 + lane*8;
            #pragma unroll
            for (int t = 0; t < 4; ++t) Af2[t] = *(const short8*)(fp2 + (size_t)t*512);
            short8 Bf2 = *(const short8*)(sm + (w*16 + lr)*264 + cc*32 + q*8);
            #pragma unroll
            for (int t = 0; t < 4; ++t)
                acc2[t] = __builtin_amdgcn_mfma_f32_16x16x32_bf16(Af2[t], Bf2, acc2[t], 0,0,0);
        }
        #pragma unroll
        for (int t = 0; t < 4; ++t)
            #pragma unroll
            for (int r = 0; r < 4; ++r){
                int c = t*16 + q*4 + r;   // 0..63, padded S
                S[((size_t)b*64 + c)*L_ + n0 + p*64 + w*16 + lr] = acc2[t][r];
            }
        __syncthreads();
    }
}

// ---------------- softmax over L per (b,c) row, in place (padded S) --------
__global__ __launch_bounds__(256) void softmax_k(float* __restrict__ S){
    int c = blockIdx.x, b = blockIdx.y, t = threadIdx.x;
    float* p = S + ((size_t)b*64 + c)*L_;
    __shared__ float sh[256];
    float mx = -1e30f;
    for (int j = t; j < L_; j += 256) mx = fmaxf(mx, p[j]);
    sh[t] = mx; __syncthreads();
    for (int o = 128; o > 0; o >>= 1){ if (t < o) sh[t] = fmaxf(sh[t], sh[t+o]); __syncthreads(); }
    float m = sh[0]; __syncthreads();
    float sum = 0.f;
    for (int j = t; j < L_; j += 256){ float e = expf(p[j] - m); p[j] = e; sum += e; }
    sh[t] = sum; __syncthreads();
    for (int o = 128; o > 0; o >>= 1){ if (t < o) sh[t] += sh[t+o]; __syncthreads(); }
    float inv = 1.0f / sh[0];
    for (int j = t; j < L_; j += 256) p[j] *= inv;
}

// ---------------- V-GEMM: Vpart[b][c][cx][f] = sum_{l in chunk} tT*A -------
// MFMA, zero LDS, zero atomics: per-chunk partials stored with plain f32x4.
__global__ __launch_bounds__(256) void v_mfma_k(const u16* __restrict__ tT,
                                                const float* __restrict__ S,
                                                float* __restrict__ Vpart){
    int cx = blockIdx.x, b = blockIdx.y;
    int w = threadIdx.x >> 6, lane = threadIdx.x & 63;
    int q = lane >> 4, lr = lane & 15;
    int l0 = cx*128;
    f32x4 acc[7];
    #pragma unroll
    for (int mt = 0; mt < 7; ++mt) acc[mt] = (f32x4){0.f,0.f,0.f,0.f};
    const u16* tb = tT + (size_t)b*128*L_;
    const float* Sb = S + ((size_t)b*64 + w*16 + lr)*L_;
    #pragma unroll
    for (int kk = 0; kk < 4; ++kk){
        int l = l0 + kk*32 + q*8;
        float4 s0 = *(const float4*)(Sb + l);
        float4 s1 = *(const float4*)(Sb + l + 4);
        short8 Bf;
        Bf[0] = (short)f2b(s0.x); Bf[1] = (short)f2b(s0.y);
        Bf[2] = (short)f2b(s0.z); Bf[3] = (short)f2b(s0.w);
        Bf[4] = (short)f2b(s1.x); Bf[5] = (short)f2b(s1.y);
        Bf[6] = (short)f2b(s1.z); Bf[7] = (short)f2b(s1.w);
        #pragma unroll
        for (int mt = 0; mt < 7; ++mt){
            short8 Af = *(const short8*)(tb + (size_t)(mt*16 + lr)*L_ + l);
            acc[mt] = __builtin_amdgcn_mfma_f32_16x16x32_bf16(Af, Bf, acc[mt], 0,0,0);
        }
    }
    int c = w*16 + lr;
    if (c < C_){
        float* vp = Vpart + ((size_t)(b*64 + c)*32 + cx)*112;
        #pragma unroll
        for (int mt = 0; mt < 7; ++mt)
            *(f32x4*)(vp + mt*16 + q*4) = acc[mt];
    }
}

// ---------------- reduce Vpart over 32 chunks -> ocat cols [256+coloff,...) -
__global__ void reduce_v_k(const float* __restrict__ Vp, float* __restrict__ oc, int coloff){
    int idx = blockIdx.x*256 + threadIdx.x;
    if (idx >= B_*C_*F_) return;
    int f = idx % F_; int rest = idx / F_;
    int c = rest % C_; int b = rest / C_;
    const float* src = Vp + ((size_t)(b*64 + c)*32)*112 + f;
    float s = 0.f;
    #pragma unroll
    for (int cx = 0; cx < 32; ++cx) s += src[cx*112];
    oc[((size_t)b*C_ + c)*OC_ + 256 + coloff + f] = s;
}

// ---------------- GCN ----------------
__global__ void gather_nodes_k(const int* __restrict__ nodes, const float* __restrict__ emb,
                               float* __restrict__ ne){
    int idx = blockIdx.x*256 + threadIdx.x;
    if (idx >= B_*NN_*D_) return;
    int d = idx & 255, n = (idx >> 8) & 511, b = idx >> 17;
    ne[idx] = emb[(size_t)nodes[b*NN_ + n]*D_ + d];
}
__global__ void deg_count_k(const int* __restrict__ edges, int* __restrict__ deg){
    int idx = blockIdx.x*256 + threadIdx.x;
    if (idx >= B_*EE_) return;
    int b = idx >> 13, e = idx & (EE_-1);
    int dst = edges[b*2*EE_ + EE_ + e];
    atomicAdd(&deg[b*NN_ + dst], 1);
}
__global__ void dinv_k(const int* __restrict__ deg, float* __restrict__ dinv){
    int i = blockIdx.x*256 + threadIdx.x;
    if (i < B_*NN_) dinv[i] = 1.0f / sqrtf((float)deg[i]);
}
__global__ void scan_csr_k(const int* __restrict__ deg, int* __restrict__ rp, int* __restrict__ cur){
    int b = blockIdx.x, t = threadIdx.x;    // 512 threads
    __shared__ int sh[NN_];
    int v = deg[b*NN_ + t];
    sh[t] = v; __syncthreads();
    for (int off = 1; off < NN_; off <<= 1){
        int x = (t >= off) ? sh[t-off] : 0;
        __syncthreads();
        sh[t] += x;
        __syncthreads();
    }
    int incl = sh[t], excl = incl - v;
    rp[b*513 + t] = excl;
    cur[b*NN_ + t] = excl;
    if (t == NN_-1) rp[b*513 + NN_] = incl;
}
__global__ void fill_csr_k(const int* __restrict__ edges, int* __restrict__ cur, int* __restrict__ adj){
    int e = blockIdx.x*256 + threadIdx.x, b = blockIdx.y;
    if (e >= ADJ_) return;
    int s, d;
    if (e < EE_){ s = edges[b*2*EE_ + e]; d = edges[b*2*EE_ + EE_ + e]; }
    else        { s = d = e - EE_; }
    int pos = atomicAdd(&cur[b*NN_ + d], 1);
    adj[b*ADJ_ + pos] = s;
}
__global__ __launch_bounds__(256) void gemm_nt_k(const float* __restrict__ A,
                                                 const float* __restrict__ W,
                                                 float* __restrict__ out){
    int b = blockIdx.z, n0 = blockIdx.x*64, i0 = blockIdx.y*64;
    __shared__ float aL[64][17], wL[64][17];
    int tid = threadIdx.x, tx = tid & 15, ty = tid >> 4;
    const float* Ab = A + (size_t)b*NN_*D_;
    float acc[4][4];
    #pragma unroll
    for (int r = 0; r < 4; ++r)
        #pragma unroll
        for (int i = 0; i < 4; ++i) acc[r][i] = 0.f;
    for (int j0 = 0; j0 < D_; j0 += 16){
        for (int idx = tid; idx < 1024; idx += 256){
            int r = idx >> 4, cc = idx & 15;
            aL[r][cc] = Ab[(size_t)(n0+r)*D_ + j0 + cc];
            wL[r][cc] = W[(size_t)(i0+r)*D_ + j0 + cc];
        }
        __syncthreads();
        #pragma unroll
        for (int kk = 0; kk < 16; ++kk){
            float av[4], wv[4];
            #pragma unroll
            for (int r = 0; r < 4; ++r) av[r] = aL[ty*4+r][kk];
            #pragma unroll
            for (int i = 0; i < 4; ++i) wv[i] = wL[tx*4+i][kk];
            #pragma unroll
            for (int r = 0; r < 4; ++r)
                #pragma unroll
                for (int i = 0; i < 4; ++i) acc[r][i] = fmaf(av[r], wv[i], acc[r][i]);
        }
        __syncthreads();
    }
    float* ob = out + (size_t)b*NN_*D_;
    #pragma unroll
    for (int r = 0; r < 4; ++r)
        #pragma unroll
        for (int i = 0; i < 4; ++i)
            ob[(size_t)(n0+ty*4+r)*D_ + i0+tx*4+i] = acc[r][i];
}
__global__ __launch_bounds__(256) void scatter_k(const float* __restrict__ xw,
                                                 const int* __restrict__ adj,
                                                 const int* __restrict__ rp,
                                                 const float* __restrict__ dinv,
                                                 const float* __restrict__ bias,
                                                 float* __restrict__ out,
                                                 int out_bs, int out_ld, int relu){
    int n = blockIdx.x, b = blockIdx.y, t = threadIdx.x;
    const int* rpb = rp + b*513;
    const int* adjb = adj + b*ADJ_;
    const float* xwb = xw + (size_t)b*NN_*D_;
    const float* dvb = dinv + b*NN_;
    int e0 = rpb[n], e1 = rpb[n+1];
    float acc = 0.f;
    for (int e = e0; e < e1; ++e){
        int s = adjb[e];
        acc = fmaf(xwb[(size_t)s*D_ + t], dvb[s], acc);
    }
    float v = fmaf(acc, dvb[n], bias[t]);
    if (relu) v = fmaxf(v, 0.f);
    out[(size_t)b*out_bs + (size_t)n*out_ld + t] = v;
}

// ---------------- fused head ----------------
__global__ __launch_bounds__(128) void final_k(const float* __restrict__ oc,
                                               const float* __restrict__ w1t,
                                               const float* __restrict__ b1,
                                               const float* __restrict__ w2,
                                               const float* __restrict__ b2,
                                               float* __restrict__ y){
    int c = blockIdx.x, b = blockIdx.y, h = threadIdx.x;
    __shared__ float row[OC_];
    __shared__ float red[128];
    const float* src = oc + ((size_t)b*C_ + c)*OC_;
    for (int j = h; j < OC_; j += 128) row[j] = src[j];
    __syncthreads();
    float acc = b1[h];
    #pragma unroll 8
    for (int j = 0; j < OC_; ++j) acc = fmaf(row[j], w1t[j*128 + h], acc);
    float hid = fmaxf(acc, 0.f);
    red[h] = hid * w2[c*128 + h];
    __syncthreads();
    for (int o = 64; o > 0; o >>= 1){ if (h < o) red[h] += red[h+o]; __syncthreads(); }
    if (h == 0) y[b*C_ + c] = red[0] + b2[c];
}

// ===========================================================================
extern "C" void kernel_launch(void* const* d_in, const int* in_sizes, int n_in,
                              void* d_out, int out_size, void* d_ws, size_t ws_size,
                              hipStream_t stream){
    (void)in_sizes; (void)n_in; (void)out_size; (void)ws_size;
    const int*   x          = (const int*)d_in[0];
    const int*   nodes      = (const int*)d_in[2];
    const int*   edges      = (const int*)d_in[3];
    const float* word_emb   = (const float*)d_in[4];
    const float* entity_emb = (const float*)d_in[5];
    const float* convb[3]   = {(const float*)d_in[7], (const float*)d_in[10], (const float*)d_in[13]};
    const float* bn_gamma   = (const float*)d_in[15];
    const float* bn_beta    = (const float*)d_in[16];
    const float* gc1_w      = (const float*)d_in[19];
    const float* gc1_b      = (const float*)d_in[20];
    const float* gc2_w      = (const float*)d_in[21];
    const float* gc2_b      = (const float*)d_in[22];
    const float* fin1_w     = (const float*)d_in[23];
    const float* fin1_b     = (const float*)d_in[24];
    const float* fin2_w     = (const float*)d_in[25];
    const float* fin2_b     = (const float*)d_in[26];
    float* y = (float*)d_out;

    char* base = (char*)d_ws;
    size_t off = 0;
    auto alloc = [&](size_t elems, size_t esz) -> char* {
        char* p = base + off;
        off += ((elems*esz + 255) / 256) * 256;
        return p;
    };
    u16* hH  = (u16*)alloc((size_t)B_*LP_*D_, 2);
    u16* t0  = (u16*)alloc((size_t)B_*LP_*128, 2);
    u16* t1  = (u16*)alloc((size_t)B_*LP_*128, 2);
    u16* tT  = (u16*)alloc((size_t)B_*128*L_, 2);
    float* S     = (float*)alloc((size_t)B_*64*L_, 4);
    float* Vpart = (float*)alloc((size_t)B_*64*32*112, 4);
    float* ne   = (float*)alloc((size_t)B_*NN_*D_, 4);
    float* xw   = (float*)alloc((size_t)B_*NN_*D_, 4);
    float* g1   = (float*)alloc((size_t)B_*NN_*D_, 4);
    float* ocat = (float*)alloc((size_t)B_*C_*OC_, 4);
    u16* wfc1  = (u16*)alloc(3*WFC1_STRIDE, 2);
    u16* wfres = (u16*)alloc(6*WFRES_STRIDE, 2);
    u16* wfaw  = (u16*)alloc(3*WFAW_STRIDE, 2);
    u16* wfau  = (u16*)alloc(3*WFAU_STRIDE, 2);
    float* w1t   = (float*)alloc((size_t)OC_*128, 4);
    float* dinvp = (float*)alloc((size_t)B_*NN_, 4);
    int* deg = (int*)alloc((size_t)B_*NN_, 4);
    int* rpB = (int*)alloc((size_t)B_*513, 4);
    int* cur = (int*)alloc((size_t)B_*NN_, 4);
    int* adj = (int*)alloc((size_t)B_*ADJ_, 4);

    // ---- init & weight packing ----
    fill_i_k<<<CDIV(B_*NN_,256),256,0,stream>>>(deg, B_*NN_, 1);
    zero_pads1_k<<<CDIV(B_*16*128,256),256,0,stream>>>(t0);
    zero_pads1_k<<<CDIV(B_*16*128,256),256,0,stream>>>(t1);
    pack_conv1_k<<<dim3(CDIV(9*8*8*512,256),3),256,0,stream>>>(
        (const float*)d_in[6], (const float*)d_in[9], (const float*)d_in[12], wfc1);
    pack_res_k<<<dim3(CDIV(9*4*8*512,256),3,2),256,0,stream>>>(
        (const float*)d_in[8], (const float*)d_in[11], (const float*)d_in[14], wfres);
    pack_aw_k<<<dim3(CDIV(4*16*512,256),3),256,0,stream>>>((const float*)d_in[17], wfaw);
    pack_au_k<<<dim3(CDIV(8*4*512,256),3),256,0,stream>>>((const float*)d_in[18], wfau);

    // ---- embedding ----
    embed1_k<<<dim3(LP_/8, B_),256,0,stream>>>(x, word_emb, hH);

    // ---- GCN ----
    gather_nodes_k<<<CDIV(B_*NN_*D_,256),256,0,stream>>>(nodes, entity_emb, ne);
    deg_count_k<<<CDIV(B_*EE_,256),256,0,stream>>>(edges, deg);
    dinv_k<<<CDIV(B_*NN_,256),256,0,stream>>>(deg, dinvp);
    scan_csr_k<<<B_,NN_,0,stream>>>(deg, rpB, cur);
    fill_csr_k<<<dim3(CDIV(ADJ_,256),B_),256,0,stream>>>(edges, cur, adj);
    gemm_nt_k<<<dim3(NN_/64, D_/64, B_),256,0,stream>>>(ne, gc1_w, xw);
    scatter_k<<<dim3(NN_,B_),256,0,stream>>>(xw, adj, rpB, dinvp, gc1_b, g1, NN_*D_, D_, 1);
    gemm_nt_k<<<dim3(NN_/64, D_/64, B_),256,0,stream>>>(g1, gc2_w, xw);
    scatter_k<<<dim3(C_,B_),256,0,stream>>>(xw, adj, rpB, dinvp, gc2_b, ocat, C_*OC_, OC_, 0);

    // ---- encoder branches ----
    dim3 gc(64, B_), ga(32, B_);
    for (int br = 0; br < 3; ++br){
        const float* gam = bn_gamma + br*300;
        const float* bet = bn_beta + br*300;
        const u16* wc = wfc1 + (size_t)br*WFC1_STRIDE;
        const u16* wr1 = wfres + (size_t)(br*2+0)*WFRES_STRIDE;
        const u16* wr2 = wfres + (size_t)(br*2+1)*WFRES_STRIDE;
        if (br == 0){
            conv_mfma_k<3,0><<<gc,256,0,stream>>>(hH,256,8, wc, convb[br],gam,bet, t0, nullptr);
            conv_mfma_k<3,1><<<gc,256,0,stream>>>(t0,128,4, wr1, nullptr,gam+100,bet+100, t1, nullptr);
            conv_mfma_k<3,1><<<gc,256,0,stream>>>(t1,128,4, wr2, nullptr,gam+200,bet+200, t0, tT);
        } else if (br == 1){
            conv_mfma_k<5,0><<<gc,256,0,stream>>>(hH,256,8, wc, convb[br],gam,bet, t0, nullptr);
            conv_mfma_k<5,1><<<gc,256,0,stream>>>(t0,128,4, wr1, nullptr,gam+100,bet+100, t1, nullptr);
            conv_mfma_k<5,1><<<gc,256,0,stream>>>(t1,128,4, wr2, nullptr,gam+200,bet+200, t0, tT);
        } else {
            conv_mfma_k<9,0><<<gc,256,0,stream>>>(hH,256,8, wc, convb[br],gam,bet, t0, nullptr);
            conv_mfma_k<9,1><<<gc,256,0,stream>>>(t0,128,4, wr1, nullptr,gam+100,bet+100, t1, nullptr);
            conv_mfma_k<9,1><<<gc,256,0,stream>>>(t1,128,4, wr2, nullptr,gam+200,bet+200, t0, tT);
        }
        attn_k<<<ga,256,0,stream>>>(t0, wfaw + (size_t)br*WFAW_STRIDE,
                                    wfau + (size_t)br*WFAU_STRIDE, S);
        softmax_k<<<dim3(C_,B_),256,0,stream>>>(S);
        v_mfma_k<<<dim3(32, B_),256,0,stream>>>(tT, S, Vpart);
        reduce_v_k<<<CDIV(B_*C_*F_,256),256,0,stream>>>(Vpart, ocat, br*100);
    }

    // ---- head ----
    transpose_fin1_k<<<CDIV(OC_*128,256),256,0,stream>>>(fin1_w, w1t);
    final_k<<<dim3(C_,B_),128,0,stream>>>(ocat, w1t, fin1_b, fin2_w, fin2_b, y);
}

// Round 7
// 827.423 us; speedup vs baseline: 4.4288x; 1.0369x over previous
//
#include <hip/hip_runtime.h>

// ---------------------------------------------------------------------------
// Model_81990925681018 — Round 7: conv kernel restructured: 4-way m-split
// waves (no wn duplication -> half the A-frag L2 traffic) + all-chunks-up-front
// LDS staging (barriers 8->2 per block; conv1 in 2 passes of 4 chunks).
// ---------------------------------------------------------------------------

#define CDIV(a,b) (((a)+(b)-1)/(b))

#define B_    16
#define L_    4096
#define D_    256
#define LP_   4112      // L + 2*POFF
#define POFF  8
#define F_    100
#define A_    256
#define C_    50
#define NN_   512
#define EE_   8192
#define ADJ_  8704
#define OC_   560

#define WFC1_STRIDE ((size_t)9*8*8*512)   // per-branch conv1 frag stride (shorts)
#define WFRES_STRIDE ((size_t)9*4*8*512)  // per (branch,block) res frag stride
#define WFAW_STRIDE ((size_t)4*16*512)
#define WFAU_STRIDE ((size_t)8*4*512)

typedef unsigned short u16;
using short8  = __attribute__((ext_vector_type(8))) short;
using short4v = __attribute__((ext_vector_type(4))) short;
using f32x4   = __attribute__((ext_vector_type(4))) float;

__device__ __forceinline__ u16 f2b(float f){
    unsigned u = __float_as_uint(f);
    u += 0x7FFF + ((u >> 16) & 1);
    return (u16)(u >> 16);
}
__device__ __forceinline__ float b2f(u16 h){ return __uint_as_float(((unsigned)h) << 16); }

// ---------------- utility fills ----------------
__global__ void fill_i_k(int* p, int n, int v){
    int i = blockIdx.x*256 + threadIdx.x; if (i < n) p[i] = v;
}
// zero the 8 left + 8 right pad cols of a plane [b][LP_][128]
__global__ void zero_pads1_k(u16* p){
    int idx = blockIdx.x*256 + threadIdx.x;
    if (idx >= B_*16*128) return;
    int ch = idx & 127; int rest = idx >> 7;
    int pc = rest & 15; int b = rest >> 4;
    int col = (pc < 8) ? pc : (4096 + pc);
    p[((size_t)b*LP_ + col)*128 + ch] = 0;
}

// ---------------- embedding gather -> bf16 plane [b][col][256] -------------
__global__ __launch_bounds__(256) void embed1_k(const int* __restrict__ x,
                                                const float* __restrict__ emb,
                                                u16* __restrict__ hH){
    int b = blockIdx.y;
    int col = blockIdx.x*8 + (threadIdx.x >> 5);
    int cg  = (threadIdx.x & 31) * 8;
    size_t o = ((size_t)b*LP_ + col)*D_ + cg;
    int l = col - POFF;
    short8 h0;
    if (l < 0 || l >= L_){
        #pragma unroll
        for (int i = 0; i < 8; ++i) h0[i] = 0;
    } else {
        int tok = x[b*L_ + l];
        const float* s = emb + (size_t)tok*D_ + cg;
        #pragma unroll
        for (int i = 0; i < 8; ++i) h0[i] = (short)f2b(s[i]);
    }
    *(short8*)(hH + o) = h0;
}

// ---------------- weight -> MFMA A-fragment packer (single plane) ----------
__device__ __forceinline__ void pack_frag(const float* src, u16* dst,
                                          int M, int K, int kt, int nch, int MTtot, int idx){
    int i = idx & 7, lane = (idx >> 3) & 63, rest = idx >> 9;
    int mt = rest % MTtot, r2 = rest / MTtot;
    int cc = r2 % nch,  j = r2 / nch;
    int m  = mt*16 + (lane & 15);
    int ch = cc*32 + (lane >> 4)*8 + i;
    float v = (m < M && ch < K) ? src[((size_t)m*K + ch)*kt + j] : 0.f;
    dst[(size_t)rest*512 + lane*8 + i] = f2b(v);
}
__global__ void pack_conv1_k(const float* w3, const float* w5, const float* w9, u16* dst){
    int br = blockIdx.y;
    int k = (br == 0) ? 3 : (br == 1) ? 5 : 9;
    const float* s = (br == 0) ? w3 : (br == 1) ? w5 : w9;
    int idx = blockIdx.x*256 + threadIdx.x;
    if (idx < k*8*8*512) pack_frag(s, dst + (size_t)br*WFC1_STRIDE, F_, 256, k, 8, 8, idx);
}
__global__ void pack_res_k(const float* w3, const float* w5, const float* w9, u16* dst){
    int br = blockIdx.y, blk = blockIdx.z;
    int k = (br == 0) ? 3 : (br == 1) ? 5 : 9;
    const float* s = ((br == 0) ? w3 : (br == 1) ? w5 : w9) + (size_t)blk*F_*F_*k;
    int idx = blockIdx.x*256 + threadIdx.x;
    if (idx < k*4*8*512) pack_frag(s, dst + (size_t)(br*2 + blk)*WFRES_STRIDE, F_, F_, k, 4, 8, idx);
}
__global__ void pack_aw_k(const float* aw, u16* dst){
    int br = blockIdx.y;
    int idx = blockIdx.x*256 + threadIdx.x;
    if (idx < 4*16*512) pack_frag(aw + (size_t)br*A_*F_, dst + (size_t)br*WFAW_STRIDE, A_, F_, 1, 4, 16, idx);
}
__global__ void pack_au_k(const float* au, u16* dst){
    int br = blockIdx.y;
    int idx = blockIdx.x*256 + threadIdx.x;
    if (idx < 8*4*512) pack_frag(au + (size_t)br*C_*A_, dst + (size_t)br*WFAU_STRIDE, C_, A_, 1, 8, 4, idx);
}
// fin1_w[128][556] -> w1t[560][128] zero-padded
__global__ void transpose_fin1_k(const float* __restrict__ src, float* __restrict__ dst){
    int idx = blockIdx.x*256 + threadIdx.x;
    if (idx >= OC_*128) return;
    int h = idx & 127, j = idx >> 7;
    dst[idx] = (j < 556) ? src[h*556 + j] : 0.f;
}

// ---------------- MFMA shifted-GEMM conv, 64-col tile ----------------------
// Block 256 thr, 4 waves each owning a 32-row m-quarter x all 64 cols.
// Staging: all 4 chunks (res) or 2 passes of 4 (conv1) up-front -> 2 (4)
// barriers per block instead of 8 (16).
// MODE 0: tanh(acc+bias)*s+beta ; MODE 1: tanh(acc*s+beta+resid)
// outT (optional): transposed plane [b][f][L_] for the V-GEMM's A-operand.
template<int KT, int MODE, int NCH>
__global__ __launch_bounds__(256) void conv_mfma_k(
    const u16* __restrict__ in, int CHp_in,
    const u16* __restrict__ wf,
    const float* __restrict__ bias, const float* __restrict__ gamma,
    const float* __restrict__ beta,
    u16* __restrict__ out, u16* __restrict__ outT)
{
    __shared__ short sm[12800];  // staging 4 chunks x 80x40 ; epilogue 32x136
    const int tid = threadIdx.x, lane = tid & 63;
    const int w = tid >> 6;               // wave id = m-quarter
    const int q = lane >> 4, lr = lane & 15;
    const int n0 = blockIdx.x * 64;
    const int b  = blockIdx.y;
    const u16* inb = in + (size_t)b*LP_*CHp_in;

    f32x4 acc[2][4];
    #pragma unroll
    for (int t = 0; t < 2; ++t)
        #pragma unroll
        for (int n = 0; n < 4; ++n) acc[t][n] = (f32x4){0.f,0.f,0.f,0.f};

    constexpr int NPASS = NCH / 4;
    for (int pass = 0; pass < NPASS; ++pass){
        // ---- stage 4 chunks: 80 cols x 32 ch each ----
        for (int idx = tid; idx < 1280; idx += 256){
            int cc = idx >> 8;            // idx/320 would be wrong; use 5 even loads:
            cc = idx / 320;
            int e = idx - cc*320;
            int col = e >> 2, qq = e & 3;
            *(short8*)(sm + cc*3200 + col*40 + qq*8) =
                *(const short8*)(inb + (size_t)(n0 + col)*CHp_in + (pass*4 + cc)*32 + qq*8);
        }
        __syncthreads();
        // ---- compute: flattened (j, cc) loop, cc fastest; A prefetch depth 1
        auto fragPtr = [&](int it)->const u16*{
            int j = it >> 2, cc = it & 3;
            int rest = (j*NCH + pass*4 + cc)*8 + w*2;
            return wf + (size_t)rest*512 + lane*8;
        };
        short8 Ac0 = *(const short8*)(fragPtr(0));
        short8 Ac1 = *(const short8*)(fragPtr(0) + 512);
        #pragma unroll
        for (int it = 0; it < KT*4; ++it){
            short8 An0, An1;
            if (it + 1 < KT*4){
                const u16* fn = fragPtr(it+1);
                An0 = *(const short8*)(fn);
                An1 = *(const short8*)(fn + 512);
            }
            int j = it >> 2, cc = it & 3;
            int sc0 = 8 - (KT >> 1) + j + lr;
            short8 Bv[4];
            #pragma unroll
            for (int n = 0; n < 4; ++n)
                Bv[n] = *(const short8*)(sm + cc*3200 + (sc0 + n*16)*40 + q*8);
            #pragma unroll
            for (int n = 0; n < 4; ++n){
                acc[0][n] = __builtin_amdgcn_mfma_f32_16x16x32_bf16(Ac0, Bv[n], acc[0][n], 0,0,0);
                acc[1][n] = __builtin_amdgcn_mfma_f32_16x16x32_bf16(Ac1, Bv[n], acc[1][n], 0,0,0);
            }
            if (it + 1 < KT*4){ Ac0 = An0; Ac1 = An1; }
        }
        __syncthreads();
    }

    // ---- epilogue: transpose to [col][128] plane via LDS, 2 passes of 32 cols
    const float BNS = 0.9999950000374997f; // 1/sqrt(1+1e-5)
    for (int p = 0; p < 2; ++p){
        #pragma unroll
        for (int t = 0; t < 2; ++t){
            #pragma unroll
            for (int u = 0; u < 2; ++u){
                int n = p*2 + u;
                int mbase = w*32 + t*16 + q*4;
                int cl = u*16 + lr;
                int colg = n0 + n*16 + lr;
                float rsum[4] = {0.f,0.f,0.f,0.f};
                if (MODE == 1){
                    size_t ro = ((size_t)b*LP_ + POFF + colg)*CHp_in + mbase;
                    short4v rh = *(const short4v*)(in + ro);
                    #pragma unroll
                    for (int r = 0; r < 4; ++r) rsum[r] = b2f((u16)rh[r]);
                }
                short4v hv;
                #pragma unroll
                for (int r = 0; r < 4; ++r){
                    int mm = mbase + r;
                    float a = acc[t][n][r];
                    float v;
                    if (MODE == 0){
                        float bi=0.f, s=0.f, be=0.f;
                        if (mm < F_){ bi = bias[mm]; s = gamma[mm]*BNS; be = beta[mm]; }
                        v = tanhf(a + bi)*s + be;
                    } else {
                        float s=0.f, be=0.f;
                        if (mm < F_){ s = gamma[mm]*BNS; be = beta[mm]; }
                        v = tanhf(fmaf(a, s, be) + rsum[r]);
                    }
                    hv[r] = (short)f2b(v);
                }
                *(short4v*)(sm + cl*136 + mbase) = hv;
            }
        }
        __syncthreads();
        for (int idx = tid; idx < 512; idx += 256){
            int col = idx >> 4, q8 = idx & 15;
            short8 vv = *(const short8*)(sm + col*136 + q8*8);
            *(short8*)(out + ((size_t)b*LP_ + POFF + n0 + p*32 + col)*128 + q8*8) = vv;
        }
        if (outT){
            int f = tid & 127, half = tid >> 7;
            u16 vals[16];
            #pragma unroll
            for (int i = 0; i < 16; ++i) vals[i] = (u16)sm[(half*16 + i)*136 + f];
            short8 v0, v1;
            #pragma unroll
            for (int i = 0; i < 8; ++i){ v0[i] = (short)vals[i]; v1[i] = (short)vals[8+i]; }
            u16* dst = outT + ((size_t)b*128 + f)*L_ + n0 + p*32 + half*16;
            *(short8*)dst = v0;
            *(short8*)(dst + 8) = v1;
        }
        __syncthreads();
    }
}

// ---------------- fused attention: S = au . tanh(aw . t), Z in LDS ---------
// S padded to 64 rows per b; rows 50..63 are exact zeros (au pad).
__global__ __launch_bounds__(256) void attn_k(const u16* __restrict__ tpl,
                                              const u16* __restrict__ awf,
                                              const u16* __restrict__ auf,
                                              float* __restrict__ S){
    __shared__ short sm[17408];   // t-slab 128*136 ; reused as Z 64*264
    const int tid = threadIdx.x, lane = tid & 63;
    const int w = tid >> 6, wm = w >> 1, wn = w & 1;
    const int q = lane >> 4, lr = lane & 15;
    const int n0 = blockIdx.x * 128;
    const int b  = blockIdx.y;

    for (int idx = tid; idx < 2048; idx += 256){
        int col = idx >> 4, g = idx & 15;
        *(short8*)(sm + col*136 + g*8) =
            *(const short8*)(tpl + ((size_t)b*LP_ + POFF + n0 + col)*128 + g*8);
    }
    __syncthreads();

    f32x4 acc1[8][4];
    #pragma unroll
    for (int t = 0; t < 8; ++t)
        #pragma unroll
        for (int n = 0; n < 4; ++n) acc1[t][n] = (f32x4){0.f,0.f,0.f,0.f};
    for (int cc = 0; cc < 4; ++cc){
        short8 Af[8];
        const u16* fp = awf + (size_t)(cc*16 + wm*8)*512 + lane*8;
        #pragma unroll
        for (int t = 0; t < 8; ++t) Af[t] = *(const short8*)(fp + (size_t)t*512);
        short8 Bf[4];
        #pragma unroll
        for (int n = 0; n < 4; ++n)
            Bf[n] = *(const short8*)(sm + (wn*64 + n*16 + lr)*136 + cc*32 + q*8);
        #pragma unroll
        for (int t = 0; t < 8; ++t)
            #pragma unroll
            for (int n = 0; n < 4; ++n)
                acc1[t][n] = __builtin_amdgcn_mfma_f32_16x16x32_bf16(Af[t], Bf[n], acc1[t][n], 0,0,0);
    }
    __syncthreads();

    for (int p = 0; p < 2; ++p){
        if (wn == p){
            #pragma unroll
            for (int t = 0; t < 8; ++t){
                #pragma unroll
                for (int n = 0; n < 4; ++n){
                    int abase = wm*128 + t*16 + q*4;
                    int cl = n*16 + lr;
                    short4v zv;
                    #pragma unroll
                    for (int r = 0; r < 4; ++r) zv[r] = (short)f2b(tanhf(acc1[t][n][r]));
                    *(short4v*)(sm + cl*264 + abase) = zv;
                }
            }
        }
        __syncthreads();
        f32x4 acc2[4];
        #pragma unroll
        for (int t = 0; t < 4; ++t) acc2[t] = (f32x4){0.f,0.f,0.f,0.f};
        for (int cc = 0; cc < 8; ++cc){
            short8 Af2[4];
            const u16* fp2 = auf + (size_t)(cc*4)*512 + lane*8;
            #pragma unroll
            for (int t = 0; t < 4; ++t) Af2[t] = *(const short8*)(fp2 + (size_t)t*512);
            short8 Bf2 = *(const short8*)(sm + (w*16 + lr)*264 + cc*32 + q*8);
            #pragma unroll
            for (int t = 0; t < 4; ++t)
                acc2[t] = __builtin_amdgcn_mfma_f32_16x16x32_bf16(Af2[t], Bf2, acc2[t], 0,0,0);
        }
        #pragma unroll
        for (int t = 0; t < 4; ++t)
            #pragma unroll
            for (int r = 0; r < 4; ++r){
                int c = t*16 + q*4 + r;   // 0..63, padded S
                S[((size_t)b*64 + c)*L_ + n0 + p*64 + w*16 + lr] = acc2[t][r];
            }
        __syncthreads();
    }
}

// ---------------- softmax over L per (b,c) row, in place (padded S) --------
__global__ __launch_bounds__(256) void softmax_k(float* __restrict__ S){
    int c = blockIdx.x, b = blockIdx.y, t = threadIdx.x;
    float* p = S + ((size_t)b*64 + c)*L_;
    __shared__ float sh[256];
    float mx = -1e30f;
    for (int j = t; j < L_; j += 256) mx = fmaxf(mx, p[j]);
    sh[t] = mx; __syncthreads();
    for (int o = 128; o > 0; o >>= 1){ if (t < o) sh[t] = fmaxf(sh[t], sh[t+o]); __syncthreads(); }
    float m = sh[0]; __syncthreads();
    float sum = 0.f;
    for (int j = t; j < L_; j += 256){ float e = expf(p[j] - m); p[j] = e; sum += e; }
    sh[t] = sum; __syncthreads();
    for (int o = 128; o > 0; o >>= 1){ if (t < o) sh[t] += sh[t+o]; __syncthreads(); }
    float inv = 1.0f / sh[0];
    for (int j = t; j < L_; j += 256) p[j] *= inv;
}

// ---------------- V-GEMM: Vpart[b][c][cx][f] = sum_{l in chunk} tT*A -------
__global__ __launch_bounds__(256) void v_mfma_k(const u16* __restrict__ tT,
                                                const float* __restrict__ S,
                                                float* __restrict__ Vpart){
    int cx = blockIdx.x, b = blockIdx.y;
    int w = threadIdx.x >> 6, lane = threadIdx.x & 63;
    int q = lane >> 4, lr = lane & 15;
    int l0 = cx*128;
    f32x4 acc[7];
    #pragma unroll
    for (int mt = 0; mt < 7; ++mt) acc[mt] = (f32x4){0.f,0.f,0.f,0.f};
    const u16* tb = tT + (size_t)b*128*L_;
    const float* Sb = S + ((size_t)b*64 + w*16 + lr)*L_;
    #pragma unroll
    for (int kk = 0; kk < 4; ++kk){
        int l = l0 + kk*32 + q*8;
        float4 s0 = *(const float4*)(Sb + l);
        float4 s1 = *(const float4*)(Sb + l + 4);
        short8 Bf;
        Bf[0] = (short)f2b(s0.x); Bf[1] = (short)f2b(s0.y);
        Bf[2] = (short)f2b(s0.z); Bf[3] = (short)f2b(s0.w);
        Bf[4] = (short)f2b(s1.x); Bf[5] = (short)f2b(s1.y);
        Bf[6] = (short)f2b(s1.z); Bf[7] = (short)f2b(s1.w);
        #pragma unroll
        for (int mt = 0; mt < 7; ++mt){
            short8 Af = *(const short8*)(tb + (size_t)(mt*16 + lr)*L_ + l);
            acc[mt] = __builtin_amdgcn_mfma_f32_16x16x32_bf16(Af, Bf, acc[mt], 0,0,0);
        }
    }
    int c = w*16 + lr;
    if (c < C_){
        float* vp = Vpart + ((size_t)(b*64 + c)*32 + cx)*112;
        #pragma unroll
        for (int mt = 0; mt < 7; ++mt)
            *(f32x4*)(vp + mt*16 + q*4) = acc[mt];
    }
}

// ---------------- reduce Vpart over 32 chunks -> ocat cols [256+coloff,...) -
__global__ void reduce_v_k(const float* __restrict__ Vp, float* __restrict__ oc, int coloff){
    int idx = blockIdx.x*256 + threadIdx.x;
    if (idx >= B_*C_*F_) return;
    int f = idx % F_; int rest = idx / F_;
    int c = rest % C_; int b = rest / C_;
    const float* src = Vp + ((size_t)(b*64 + c)*32)*112 + f;
    float s = 0.f;
    #pragma unroll
    for (int cx = 0; cx < 32; ++cx) s += src[cx*112];
    oc[((size_t)b*C_ + c)*OC_ + 256 + coloff + f] = s;
}

// ---------------- GCN ----------------
__global__ void gather_nodes_k(const int* __restrict__ nodes, const float* __restrict__ emb,
                               float* __restrict__ ne){
    int idx = blockIdx.x*256 + threadIdx.x;
    if (idx >= B_*NN_*D_) return;
    int d = idx & 255, n = (idx >> 8) & 511, b = idx >> 17;
    ne[idx] = emb[(size_t)nodes[b*NN_ + n]*D_ + d];
}
__global__ void deg_count_k(const int* __restrict__ edges, int* __restrict__ deg){
    int idx = blockIdx.x*256 + threadIdx.x;
    if (idx >= B_*EE_) return;
    int b = idx >> 13, e = idx & (EE_-1);
    int dst = edges[b*2*EE_ + EE_ + e];
    atomicAdd(&deg[b*NN_ + dst], 1);
}
__global__ void dinv_k(const int* __restrict__ deg, float* __restrict__ dinv){
    int i = blockIdx.x*256 + threadIdx.x;
    if (i < B_*NN_) dinv[i] = 1.0f / sqrtf((float)deg[i]);
}
__global__ void scan_csr_k(const int* __restrict__ deg, int* __restrict__ rp, int* __restrict__ cur){
    int b = blockIdx.x, t = threadIdx.x;    // 512 threads
    __shared__ int sh[NN_];
    int v = deg[b*NN_ + t];
    sh[t] = v; __syncthreads();
    for (int off = 1; off < NN_; off <<= 1){
        int x = (t >= off) ? sh[t-off] : 0;
        __syncthreads();
        sh[t] += x;
        __syncthreads();
    }
    int incl = sh[t], excl = incl - v;
    rp[b*513 + t] = excl;
    cur[b*NN_ + t] = excl;
    if (t == NN_-1) rp[b*513 + NN_] = incl;
}
__global__ void fill_csr_k(const int* __restrict__ edges, int* __restrict__ cur, int* __restrict__ adj){
    int e = blockIdx.x*256 + threadIdx.x, b = blockIdx.y;
    if (e >= ADJ_) return;
    int s, d;
    if (e < EE_){ s = edges[b*2*EE_ + e]; d = edges[b*2*EE_ + EE_ + e]; }
    else        { s = d = e - EE_; }
    int pos = atomicAdd(&cur[b*NN_ + d], 1);
    adj[b*ADJ_ + pos] = s;
}
__global__ __launch_bounds__(256) void gemm_nt_k(const float* __restrict__ A,
                                                 const float* __restrict__ W,
                                                 float* __restrict__ out){
    int b = blockIdx.z, n0 = blockIdx.x*64, i0 = blockIdx.y*64;
    __shared__ float aL[64][17], wL[64][17];
    int tid = threadIdx.x, tx = tid & 15, ty = tid >> 4;
    const float* Ab = A + (size_t)b*NN_*D_;
    float acc[4][4];
    #pragma unroll
    for (int r = 0; r < 4; ++r)
        #pragma unroll
        for (int i = 0; i < 4; ++i) acc[r][i] = 0.f;
    for (int j0 = 0; j0 < D_; j0 += 16){
        for (int idx = tid; idx < 1024; idx += 256){
            int r = idx >> 4, cc = idx & 15;
            aL[r][cc] = Ab[(size_t)(n0+r)*D_ + j0 + cc];
            wL[r][cc] = W[(size_t)(i0+r)*D_ + j0 + cc];
        }
        __syncthreads();
        #pragma unroll
        for (int kk = 0; kk < 16; ++kk){
            float av[4], wv[4];
            #pragma unroll
            for (int r = 0; r < 4; ++r) av[r] = aL[ty*4+r][kk];
            #pragma unroll
            for (int i = 0; i < 4; ++i) wv[i] = wL[tx*4+i][kk];
            #pragma unroll
            for (int r = 0; r < 4; ++r)
                #pragma unroll
                for (int i = 0; i < 4; ++i) acc[r][i] = fmaf(av[r], wv[i], acc[r][i]);
        }
        __syncthreads();
    }
    float* ob = out + (size_t)b*NN_*D_;
    #pragma unroll
    for (int r = 0; r < 4; ++r)
        #pragma unroll
        for (int i = 0; i < 4; ++i)
            ob[(size_t)(n0+ty*4+r)*D_ + i0+tx*4+i] = acc[r][i];
}
__global__ __launch_bounds__(256) void scatter_k(const float* __restrict__ xw,
                                                 const int* __restrict__ adj,
                                                 const int* __restrict__ rp,
                                                 const float* __restrict__ dinv,
                                                 const float* __restrict__ bias,
                                                 float* __restrict__ out,
                                                 int out_bs, int out_ld, int relu){
    int n = blockIdx.x, b = blockIdx.y, t = threadIdx.x;
    const int* rpb = rp + b*513;
    const int* adjb = adj + b*ADJ_;
    const float* xwb = xw + (size_t)b*NN_*D_;
    const float* dvb = dinv + b*NN_;
    int e0 = rpb[n], e1 = rpb[n+1];
    float acc = 0.f;
    for (int e = e0; e < e1; ++e){
        int s = adjb[e];
        acc = fmaf(xwb[(size_t)s*D_ + t], dvb[s], acc);
    }
    float v = fmaf(acc, dvb[n], bias[t]);
    if (relu) v = fmaxf(v, 0.f);
    out[(size_t)b*out_bs + (size_t)n*out_ld + t] = v;
}

// ---------------- fused head ----------------
__global__ __launch_bounds__(128) void final_k(const float* __restrict__ oc,
                                               const float* __restrict__ w1t,
                                               const float* __restrict__ b1,
                                               const float* __restrict__ w2,
                                               const float* __restrict__ b2,
                                               float* __restrict__ y){
    int c = blockIdx.x, b = blockIdx.y, h = threadIdx.x;
    __shared__ float row[OC_];
    __shared__ float red[128];
    const float* src = oc + ((size_t)b*C_ + c)*OC_;
    for (int j = h; j < OC_; j += 128) row[j] = src[j];
    __syncthreads();
    float acc = b1[h];
    #pragma unroll 8
    for (int j = 0; j < OC_; ++j) acc = fmaf(row[j], w1t[j*128 + h], acc);
    float hid = fmaxf(acc, 0.f);
    red[h] = hid * w2[c*128 + h];
    __syncthreads();
    for (int o = 64; o > 0; o >>= 1){ if (h < o) red[h] += red[h+o]; __syncthreads(); }
    if (h == 0) y[b*C_ + c] = red[0] + b2[c];
}

// ===========================================================================
extern "C" void kernel_launch(void* const* d_in, const int* in_sizes, int n_in,
                              void* d_out, int out_size, void* d_ws, size_t ws_size,
                              hipStream_t stream){
    (void)in_sizes; (void)n_in; (void)out_size; (void)ws_size;
    const int*   x          = (const int*)d_in[0];
    const int*   nodes      = (const int*)d_in[2];
    const int*   edges      = (const int*)d_in[3];
    const float* word_emb   = (const float*)d_in[4];
    const float* entity_emb = (const float*)d_in[5];
    const float* convb[3]   = {(const float*)d_in[7], (const float*)d_in[10], (const float*)d_in[13]};
    const float* bn_gamma   = (const float*)d_in[15];
    const float* bn_beta    = (const float*)d_in[16];
    const float* gc1_w      = (const float*)d_in[19];
    const float* gc1_b      = (const float*)d_in[20];
    const float* gc2_w      = (const float*)d_in[21];
    const float* gc2_b      = (const float*)d_in[22];
    const float* fin1_w     = (const float*)d_in[23];
    const float* fin1_b     = (const float*)d_in[24];
    const float* fin2_w     = (const float*)d_in[25];
    const float* fin2_b     = (const float*)d_in[26];
    float* y = (float*)d_out;

    char* base = (char*)d_ws;
    size_t off = 0;
    auto alloc = [&](size_t elems, size_t esz) -> char* {
        char* p = base + off;
        off += ((elems*esz + 255) / 256) * 256;
        return p;
    };
    u16* hH  = (u16*)alloc((size_t)B_*LP_*D_, 2);
    u16* t0  = (u16*)alloc((size_t)B_*LP_*128, 2);
    u16* t1  = (u16*)alloc((size_t)B_*LP_*128, 2);
    u16* tT  = (u16*)alloc((size_t)B_*128*L_, 2);
    float* S     = (float*)alloc((size_t)B_*64*L_, 4);
    float* Vpart = (float*)alloc((size_t)B_*64*32*112, 4);
    float* ne   = (float*)alloc((size_t)B_*NN_*D_, 4);
    float* xw   = (float*)alloc((size_t)B_*NN_*D_, 4);
    float* g1   = (float*)alloc((size_t)B_*NN_*D_, 4);
    float* ocat = (float*)alloc((size_t)B_*C_*OC_, 4);
    u16* wfc1  = (u16*)alloc(3*WFC1_STRIDE, 2);
    u16* wfres = (u16*)alloc(6*WFRES_STRIDE, 2);
    u16* wfaw  = (u16*)alloc(3*WFAW_STRIDE, 2);
    u16* wfau  = (u16*)alloc(3*WFAU_STRIDE, 2);
    float* w1t   = (float*)alloc((size_t)OC_*128, 4);
    float* dinvp = (float*)alloc((size_t)B_*NN_, 4);
    int* deg = (int*)alloc((size_t)B_*NN_, 4);
    int* rpB = (int*)alloc((size_t)B_*513, 4);
    int* cur = (int*)alloc((size_t)B_*NN_, 4);
    int* adj = (int*)alloc((size_t)B_*ADJ_, 4);

    // ---- init & weight packing ----
    fill_i_k<<<CDIV(B_*NN_,256),256,0,stream>>>(deg, B_*NN_, 1);
    zero_pads1_k<<<CDIV(B_*16*128,256),256,0,stream>>>(t0);
    zero_pads1_k<<<CDIV(B_*16*128,256),256,0,stream>>>(t1);
    pack_conv1_k<<<dim3(CDIV(9*8*8*512,256),3),256,0,stream>>>(
        (const float*)d_in[6], (const float*)d_in[9], (const float*)d_in[12], wfc1);
    pack_res_k<<<dim3(CDIV(9*4*8*512,256),3,2),256,0,stream>>>(
        (const float*)d_in[8], (const float*)d_in[11], (const float*)d_in[14], wfres);
    pack_aw_k<<<dim3(CDIV(4*16*512,256),3),256,0,stream>>>((const float*)d_in[17], wfaw);
    pack_au_k<<<dim3(CDIV(8*4*512,256),3),256,0,stream>>>((const float*)d_in[18], wfau);

    // ---- embedding ----
    embed1_k<<<dim3(LP_/8, B_),256,0,stream>>>(x, word_emb, hH);

    // ---- GCN ----
    gather_nodes_k<<<CDIV(B_*NN_*D_,256),256,0,stream>>>(nodes, entity_emb, ne);
    deg_count_k<<<CDIV(B_*EE_,256),256,0,stream>>>(edges, deg);
    dinv_k<<<CDIV(B_*NN_,256),256,0,stream>>>(deg, dinvp);
    scan_csr_k<<<B_,NN_,0,stream>>>(deg, rpB, cur);
    fill_csr_k<<<dim3(CDIV(ADJ_,256),B_),256,0,stream>>>(edges, cur, adj);
    gemm_nt_k<<<dim3(NN_/64, D_/64, B_),256,0,stream>>>(ne, gc1_w, xw);
    scatter_k<<<dim3(NN_,B_),256,0,stream>>>(xw, adj, rpB, dinvp, gc1_b, g1, NN_*D_, D_, 1);
    gemm_nt_k<<<dim3(NN_/64, D_/64, B_),256,0,stream>>>(g1, gc2_w, xw);
    scatter_k<<<dim3(C_,B_),256,0,stream>>>(xw, adj, rpB, dinvp, gc2_b, ocat, C_*OC_, OC_, 0);

    // ---- encoder branches ----
    dim3 gc(64, B_), ga(32, B_);
    for (int br = 0; br < 3; ++br){
        const float* gam = bn_gamma + br*300;
        const float* bet = bn_beta + br*300;
        const u16* wc = wfc1 + (size_t)br*WFC1_STRIDE;
        const u16* wr1 = wfres + (size_t)(br*2+0)*WFRES_STRIDE;
        const u16* wr2 = wfres + (size_t)(br*2+1)*WFRES_STRIDE;
        if (br == 0){
            conv_mfma_k<3,0,8><<<gc,256,0,stream>>>(hH,256, wc, convb[br],gam,bet, t0, nullptr);
            conv_mfma_k<3,1,4><<<gc,256,0,stream>>>(t0,128, wr1, nullptr,gam+100,bet+100, t1, nullptr);
            conv_mfma_k<3,1,4><<<gc,256,0,stream>>>(t1,128, wr2, nullptr,gam+200,bet+200, t0, tT);
        } else if (br == 1){
            conv_mfma_k<5,0,8><<<gc,256,0,stream>>>(hH,256, wc, convb[br],gam,bet, t0, nullptr);
            conv_mfma_k<5,1,4><<<gc,256,0,stream>>>(t0,128, wr1, nullptr,gam+100,bet+100, t1, nullptr);
            conv_mfma_k<5,1,4><<<gc,256,0,stream>>>(t1,128, wr2, nullptr,gam+200,bet+200, t0, tT);
        } else {
            conv_mfma_k<9,0,8><<<gc,256,0,stream>>>(hH,256, wc, convb[br],gam,bet, t0, nullptr);
            conv_mfma_k<9,1,4><<<gc,256,0,stream>>>(t0,128, wr1, nullptr,gam+100,bet+100, t1, nullptr);
            conv_mfma_k<9,1,4><<<gc,256,0,stream>>>(t1,128, wr2, nullptr,gam+200,bet+200, t0, tT);
        }
        attn_k<<<ga,256,0,stream>>>(t0, wfaw + (size_t)br*WFAW_STRIDE,
                                    wfau + (size_t)br*WFAU_STRIDE, S);
        softmax_k<<<dim3(C_,B_),256,0,stream>>>(S);
        v_mfma_k<<<dim3(32, B_),256,0,stream>>>(tT, S, Vpart);
        reduce_v_k<<<CDIV(B_*C_*F_,256),256,0,stream>>>(Vpart, ocat, br*100);
    }

    // ---- head ----
    transpose_fin1_k<<<CDIV(OC_*128,256),256,0,stream>>>(fin1_w, w1t);
    final_k<<<dim3(C_,B_),128,0,stream>>>(ocat, w1t, fin1_b, fin2_w, fin2_b, y);
}

// Round 9
// 708.402 us; speedup vs baseline: 5.1729x; 1.1680x over previous
//
#include <hip/hip_runtime.h>

// ---------------------------------------------------------------------------
// Model_81990925681018 — Round 9: R8 branch-fused dispatches + workspace diet.
// R8 crashed: ~311 MB d_ws use exceeded capacity (largest known-good 247 MB).
// Fixes: S stored bf16 (25MB), Vpart 16 chunks (22MB), hH aliased inside t1
// region, Vpart aliased onto GCN scratch. Total ~208 MB.
// ---------------------------------------------------------------------------

#define CDIV(a,b) (((a)+(b)-1)/(b))

#define B_    16
#define L_    4096
#define D_    256
#define LP_   4112      // L + 2*POFF
#define POFF  8
#define F_    100
#define A_    256
#define C_    50
#define NN_   512
#define EE_   8192
#define ADJ_  8704
#define OC_   560

#define PLANE ((size_t)B_*LP_*128)     // one branch t-plane (shorts)
#define TTS   ((size_t)B_*128*L_)      // one branch tT plane (shorts)
#define SST   ((size_t)B_*64*L_)       // one branch S (bf16 elems)
#define VPS   ((size_t)B_*64*16*112)   // one branch Vpart (floats), 16 chunks

#define WFC1_STRIDE ((size_t)9*8*8*512)   // per-branch conv1 frag stride (shorts)
#define WFRES_STRIDE ((size_t)9*4*8*512)  // per (branch,block) res frag stride
#define WFAW_STRIDE ((size_t)4*16*512)
#define WFAU_STRIDE ((size_t)8*4*512)

typedef unsigned short u16;
using short8  = __attribute__((ext_vector_type(8))) short;
using short4v = __attribute__((ext_vector_type(4))) short;
using f32x4   = __attribute__((ext_vector_type(4))) float;

__device__ __forceinline__ u16 f2b(float f){
    unsigned u = __float_as_uint(f);
    u += 0x7FFF + ((u >> 16) & 1);
    return (u16)(u >> 16);
}
__device__ __forceinline__ float b2f(u16 h){ return __uint_as_float(((unsigned)h) << 16); }

// ---------------- utility fills ----------------
__global__ void fill_i_k(int* p, int n, int v){
    int i = blockIdx.x*256 + threadIdx.x; if (i < n) p[i] = v;
}
// zero pad cols of 3 consecutive [b][LP_][128] planes
__global__ void zero_pads3_k(u16* p){
    int idx = blockIdx.x*256 + threadIdx.x;
    if (idx >= 3*B_*16*128) return;
    int ch = idx & 127; int rest = idx >> 7;
    int pc = rest & 15; rest >>= 4;
    int b = rest & 15;  int br = rest >> 4;
    int col = (pc < 8) ? pc : (4096 + pc);
    p[(size_t)br*PLANE + ((size_t)b*LP_ + col)*128 + ch] = 0;
}

// ---------------- embedding gather -> bf16 plane [b][col][256] -------------
__global__ __launch_bounds__(256) void embed1_k(const int* __restrict__ x,
                                                const float* __restrict__ emb,
                                                u16* __restrict__ hH){
    int b = blockIdx.y;
    int col = blockIdx.x*8 + (threadIdx.x >> 5);
    int cg  = (threadIdx.x & 31) * 8;
    size_t o = ((size_t)b*LP_ + col)*D_ + cg;
    int l = col - POFF;
    short8 h0;
    if (l < 0 || l >= L_){
        #pragma unroll
        for (int i = 0; i < 8; ++i) h0[i] = 0;
    } else {
        int tok = x[b*L_ + l];
        const float* s = emb + (size_t)tok*D_ + cg;
        #pragma unroll
        for (int i = 0; i < 8; ++i) h0[i] = (short)f2b(s[i]);
    }
    *(short8*)(hH + o) = h0;
}

// ---------------- weight -> MFMA A-fragment packer (single plane) ----------
__device__ __forceinline__ void pack_frag(const float* src, u16* dst,
                                          int M, int K, int kt, int nch, int MTtot, int idx){
    int i = idx & 7, lane = (idx >> 3) & 63, rest = idx >> 9;
    int mt = rest % MTtot, r2 = rest / MTtot;
    int cc = r2 % nch,  j = r2 / nch;
    int m  = mt*16 + (lane & 15);
    int ch = cc*32 + (lane >> 4)*8 + i;
    float v = (m < M && ch < K) ? src[((size_t)m*K + ch)*kt + j] : 0.f;
    dst[(size_t)rest*512 + lane*8 + i] = f2b(v);
}
__global__ void pack_conv1_k(const float* w3, const float* w5, const float* w9, u16* dst){
    int br = blockIdx.y;
    int k = (br == 0) ? 3 : (br == 1) ? 5 : 9;
    const float* s = (br == 0) ? w3 : (br == 1) ? w5 : w9;
    int idx = blockIdx.x*256 + threadIdx.x;
    if (idx < k*8*8*512) pack_frag(s, dst + (size_t)br*WFC1_STRIDE, F_, 256, k, 8, 8, idx);
}
__global__ void pack_res_k(const float* w3, const float* w5, const float* w9, u16* dst){
    int br = blockIdx.y, blk = blockIdx.z;
    int k = (br == 0) ? 3 : (br == 1) ? 5 : 9;
    const float* s = ((br == 0) ? w3 : (br == 1) ? w5 : w9) + (size_t)blk*F_*F_*k;
    int idx = blockIdx.x*256 + threadIdx.x;
    if (idx < k*4*8*512) pack_frag(s, dst + (size_t)(br*2 + blk)*WFRES_STRIDE, F_, F_, k, 4, 8, idx);
}
__global__ void pack_aw_k(const float* aw, u16* dst){
    int br = blockIdx.y;
    int idx = blockIdx.x*256 + threadIdx.x;
    if (idx < 4*16*512) pack_frag(aw + (size_t)br*A_*F_, dst + (size_t)br*WFAW_STRIDE, A_, F_, 1, 4, 16, idx);
}
__global__ void pack_au_k(const float* au, u16* dst){
    int br = blockIdx.y;
    int idx = blockIdx.x*256 + threadIdx.x;
    if (idx < 8*4*512) pack_frag(au + (size_t)br*C_*A_, dst + (size_t)br*WFAU_STRIDE, C_, A_, 1, 8, 4, idx);
}
// fin1_w[128][556] -> w1t[560][128] zero-padded
__global__ void transpose_fin1_k(const float* __restrict__ src, float* __restrict__ dst){
    int idx = blockIdx.x*256 + threadIdx.x;
    if (idx >= OC_*128) return;
    int h = idx & 127, j = idx >> 7;
    dst[idx] = (j < 556) ? src[h*556 + j] : 0.f;
}

// ---------------- MFMA shifted-GEMM conv, 64-col tile, branch-fused --------
// grid (64, B, 3). Runtime kt per branch (3/5/9). 4 waves = 4 m-quarters.
// MODE 0: tanh(acc+bias)*s+beta ; MODE 1: tanh(acc*s+beta+resid)
template<int MODE, int NCH>
__global__ __launch_bounds__(256) void conv_mfma_k(
    const u16* __restrict__ in_base, int CHp_in, long in_bs,
    const u16* __restrict__ wf_base, long wf_bs,
    const float* __restrict__ bias0, const float* __restrict__ bias1,
    const float* __restrict__ bias2,
    const float* __restrict__ gamma_base, const float* __restrict__ beta_base, int layeroff,
    u16* __restrict__ out_base, u16* __restrict__ outT_base)
{
    __shared__ short sm[12800];  // staging 4 chunks x 80x40 ; epilogue 32x136
    const int tid = threadIdx.x, lane = tid & 63;
    const int w = tid >> 6;
    const int q = lane >> 4, lr = lane & 15;
    const int n0 = blockIdx.x * 64;
    const int b  = blockIdx.y;
    const int br = blockIdx.z;
    const int kt = (br == 0) ? 3 : (br == 1) ? 5 : 9;
    const u16* in = in_base + (size_t)br*in_bs;
    const u16* wf = wf_base + (size_t)br*wf_bs;
    const float* bias = (MODE == 0) ? ((br == 0) ? bias0 : (br == 1) ? bias1 : bias2) : nullptr;
    const float* gamma = gamma_base + br*300 + layeroff;
    const float* beta  = beta_base  + br*300 + layeroff;
    u16* out  = out_base + (size_t)br*PLANE;
    u16* outT = outT_base ? (outT_base + (size_t)br*TTS) : nullptr;
    const u16* inb = in + (size_t)b*LP_*CHp_in;

    f32x4 acc[2][4];
    #pragma unroll
    for (int t = 0; t < 2; ++t)
        #pragma unroll
        for (int n = 0; n < 4; ++n) acc[t][n] = (f32x4){0.f,0.f,0.f,0.f};

    constexpr int NPASS = NCH / 4;
    for (int pass = 0; pass < NPASS; ++pass){
        for (int idx = tid; idx < 1280; idx += 256){
            int cc = idx / 320;
            int e = idx - cc*320;
            int col = e >> 2, qq = e & 3;
            *(short8*)(sm + cc*3200 + col*40 + qq*8) =
                *(const short8*)(inb + (size_t)(n0 + col)*CHp_in + (pass*4 + cc)*32 + qq*8);
        }
        __syncthreads();
        auto fragPtr = [&](int it)->const u16*{
            int j = it >> 2, cc = it & 3;
            int rest = (j*NCH + pass*4 + cc)*8 + w*2;
            return wf + (size_t)rest*512 + lane*8;
        };
        const int kt4 = kt*4;
        short8 Ac0 = *(const short8*)(fragPtr(0));
        short8 Ac1 = *(const short8*)(fragPtr(0) + 512);
        for (int it = 0; it < kt4; ++it){
            short8 An0, An1;
            if (it + 1 < kt4){
                const u16* fn = fragPtr(it+1);
                An0 = *(const short8*)(fn);
                An1 = *(const short8*)(fn + 512);
            }
            int j = it >> 2, cc = it & 3;
            int sc0 = 8 - (kt >> 1) + j + lr;
            short8 Bv[4];
            #pragma unroll
            for (int n = 0; n < 4; ++n)
                Bv[n] = *(const short8*)(sm + cc*3200 + (sc0 + n*16)*40 + q*8);
            #pragma unroll
            for (int n = 0; n < 4; ++n){
                acc[0][n] = __builtin_amdgcn_mfma_f32_16x16x32_bf16(Ac0, Bv[n], acc[0][n], 0,0,0);
                acc[1][n] = __builtin_amdgcn_mfma_f32_16x16x32_bf16(Ac1, Bv[n], acc[1][n], 0,0,0);
            }
            if (it + 1 < kt4){ Ac0 = An0; Ac1 = An1; }
        }
        __syncthreads();
    }

    // ---- epilogue: transpose to [col][128] plane via LDS, 2 passes of 32 cols
    const float BNS = 0.9999950000374997f; // 1/sqrt(1+1e-5)
    for (int p = 0; p < 2; ++p){
        #pragma unroll
        for (int t = 0; t < 2; ++t){
            #pragma unroll
            for (int u = 0; u < 2; ++u){
                int n = p*2 + u;
                int mbase = w*32 + t*16 + q*4;
                int cl = u*16 + lr;
                int colg = n0 + n*16 + lr;
                float rsum[4] = {0.f,0.f,0.f,0.f};
                if (MODE == 1){
                    size_t ro = ((size_t)b*LP_ + POFF + colg)*CHp_in + mbase;
                    short4v rh = *(const short4v*)(in + ro);
                    #pragma unroll
                    for (int r = 0; r < 4; ++r) rsum[r] = b2f((u16)rh[r]);
                }
                short4v hv;
                #pragma unroll
                for (int r = 0; r < 4; ++r){
                    int mm = mbase + r;
                    float a = acc[t][n][r];
                    float v;
                    if (MODE == 0){
                        float bi=0.f, s=0.f, be=0.f;
                        if (mm < F_){ bi = bias[mm]; s = gamma[mm]*BNS; be = beta[mm]; }
                        v = tanhf(a + bi)*s + be;
                    } else {
                        float s=0.f, be=0.f;
                        if (mm < F_){ s = gamma[mm]*BNS; be = beta[mm]; }
                        v = tanhf(fmaf(a, s, be) + rsum[r]);
                    }
                    hv[r] = (short)f2b(v);
                }
                *(short4v*)(sm + cl*136 + mbase) = hv;
            }
        }
        __syncthreads();
        for (int idx = tid; idx < 512; idx += 256){
            int col = idx >> 4, q8 = idx & 15;
            short8 vv = *(const short8*)(sm + col*136 + q8*8);
            *(short8*)(out + ((size_t)b*LP_ + POFF + n0 + p*32 + col)*128 + q8*8) = vv;
        }
        if (outT){
            int f = tid & 127, half = tid >> 7;
            u16 vals[16];
            #pragma unroll
            for (int i = 0; i < 16; ++i) vals[i] = (u16)sm[(half*16 + i)*136 + f];
            short8 v0, v1;
            #pragma unroll
            for (int i = 0; i < 8; ++i){ v0[i] = (short)vals[i]; v1[i] = (short)vals[8+i]; }
            u16* dst = outT + ((size_t)b*128 + f)*L_ + n0 + p*32 + half*16;
            *(short8*)dst = v0;
            *(short8*)(dst + 8) = v1;
        }
        __syncthreads();
    }
}

// ---------------- fused attention (branch-fused): S = au.tanh(aw.t) --------
// S stored bf16, 64 rows/b (rows 50..63 exact zeros from au padding).
__global__ __launch_bounds__(256) void attn_k(const u16* __restrict__ t_base,
                                              const u16* __restrict__ awf_base,
                                              const u16* __restrict__ auf_base,
                                              u16* __restrict__ S_base){
    __shared__ short sm[17408];   // t-slab 128*136 ; reused as Z 64*264
    const int tid = threadIdx.x, lane = tid & 63;
    const int w = tid >> 6, wm = w >> 1, wn = w & 1;
    const int q = lane >> 4, lr = lane & 15;
    const int n0 = blockIdx.x * 128;
    const int b  = blockIdx.y;
    const int br = blockIdx.z;
    const u16* tpl = t_base + (size_t)br*PLANE;
    const u16* awf = awf_base + (size_t)br*WFAW_STRIDE;
    const u16* auf = auf_base + (size_t)br*WFAU_STRIDE;
    u16* S = S_base + (size_t)br*SST;

    for (int idx = tid; idx < 2048; idx += 256){
        int col = idx >> 4, g = idx & 15;
        *(short8*)(sm + col*136 + g*8) =
            *(const short8*)(tpl + ((size_t)b*LP_ + POFF + n0 + col)*128 + g*8);
    }
    __syncthreads();

    f32x4 acc1[8][4];
    #pragma unroll
    for (int t = 0; t < 8; ++t)
        #pragma unroll
        for (int n = 0; n < 4; ++n) acc1[t][n] = (f32x4){0.f,0.f,0.f,0.f};
    for (int cc = 0; cc < 4; ++cc){
        short8 Af[8];
        const u16* fp = awf + (size_t)(cc*16 + wm*8)*512 + lane*8;
        #pragma unroll
        for (int t = 0; t < 8; ++t) Af[t] = *(const short8*)(fp + (size_t)t*512);
        short8 Bf[4];
        #pragma unroll
        for (int n = 0; n < 4; ++n)
            Bf[n] = *(const short8*)(sm + (wn*64 + n*16 + lr)*136 + cc*32 + q*8);
        #pragma unroll
        for (int t = 0; t < 8; ++t)
            #pragma unroll
            for (int n = 0; n < 4; ++n)
                acc1[t][n] = __builtin_amdgcn_mfma_f32_16x16x32_bf16(Af[t], Bf[n], acc1[t][n], 0,0,0);
    }
    __syncthreads();

    for (int p = 0; p < 2; ++p){
        if (wn == p){
            #pragma unroll
            for (int t = 0; t < 8; ++t){
                #pragma unroll
                for (int n = 0; n < 4; ++n){
                    int abase = wm*128 + t*16 + q*4;
                    int cl = n*16 + lr;
                    short4v zv;
                    #pragma unroll
                    for (int r = 0; r < 4; ++r) zv[r] = (short)f2b(tanhf(acc1[t][n][r]));
                    *(short4v*)(sm + cl*264 + abase) = zv;
                }
            }
        }
        __syncthreads();
        f32x4 acc2[4];
        #pragma unroll
        for (int t = 0; t < 4; ++t) acc2[t] = (f32x4){0.f,0.f,0.f,0.f};
        for (int cc = 0; cc < 8; ++cc){
            short8 Af2[4];
            const u16* fp2 = auf + (size_t)(cc*4)*512 + lane*8;
            #pragma unroll
            for (int t = 0; t < 4; ++t) Af2[t] = *(const short8*)(fp2 + (size_t)t*512);
            short8 Bf2 = *(const short8*)(sm + (w*16 + lr)*264 + cc*32 + q*8);
            #pragma unroll
            for (int t = 0; t < 4; ++t)
                acc2[t] = __builtin_amdgcn_mfma_f32_16x16x32_bf16(Af2[t], Bf2, acc2[t], 0,0,0);
        }
        #pragma unroll
        for (int t = 0; t < 4; ++t)
            #pragma unroll
            for (int r = 0; r < 4; ++r){
                int c = t*16 + q*4 + r;   // 0..63, padded S
                S[((size_t)b*64 + c)*L_ + n0 + p*64 + w*16 + lr] = f2b(acc2[t][r]);
            }
        __syncthreads();
    }
}

// ---------------- softmax over L per (br,b,c) bf16 row, in place -----------
__global__ __launch_bounds__(256) void softmax_k(u16* __restrict__ S){
    int c = blockIdx.x, b = blockIdx.y, br = blockIdx.z, t = threadIdx.x;
    u16* p = S + (size_t)br*SST + ((size_t)b*64 + c)*L_;
    __shared__ float sh[256];
    float mx = -1e30f;
    for (int j = t; j < L_; j += 256) mx = fmaxf(mx, b2f(p[j]));
    sh[t] = mx; __syncthreads();
    for (int o = 128; o > 0; o >>= 1){ if (t < o) sh[t] = fmaxf(sh[t], sh[t+o]); __syncthreads(); }
    float m = sh[0]; __syncthreads();
    float sum = 0.f;
    for (int j = t; j < L_; j += 256){ float e = expf(b2f(p[j]) - m); p[j] = f2b(e); sum += e; }
    sh[t] = sum; __syncthreads();
    for (int o = 128; o > 0; o >>= 1){ if (t < o) sh[t] += sh[t+o]; __syncthreads(); }
    float inv = 1.0f / sh[0];
    for (int j = t; j < L_; j += 256) p[j] = f2b(b2f(p[j]) * inv);
}

// ---------------- V-GEMM (branch-fused): 16 chunks of 256 cols -------------
__global__ __launch_bounds__(256) void v_mfma_k(const u16* __restrict__ tT_base,
                                                const u16* __restrict__ S_base,
                                                float* __restrict__ Vp_base){
    int cx = blockIdx.x, b = blockIdx.y, br = blockIdx.z;
    int w = threadIdx.x >> 6, lane = threadIdx.x & 63;
    int q = lane >> 4, lr = lane & 15;
    int l0 = cx*256;
    f32x4 acc[7];
    #pragma unroll
    for (int mt = 0; mt < 7; ++mt) acc[mt] = (f32x4){0.f,0.f,0.f,0.f};
    const u16* tb = tT_base + (size_t)br*TTS + (size_t)b*128*L_;
    const u16* Sb = S_base + (size_t)br*SST + ((size_t)b*64 + w*16 + lr)*L_;
    #pragma unroll
    for (int kk = 0; kk < 8; ++kk){
        int l = l0 + kk*32 + q*8;
        short8 Bf = *(const short8*)(Sb + l);
        #pragma unroll
        for (int mt = 0; mt < 7; ++mt){
            short8 Af = *(const short8*)(tb + (size_t)(mt*16 + lr)*L_ + l);
            acc[mt] = __builtin_amdgcn_mfma_f32_16x16x32_bf16(Af, Bf, acc[mt], 0,0,0);
        }
    }
    int c = w*16 + lr;
    if (c < C_){
        float* vp = Vp_base + (size_t)br*VPS + ((size_t)(b*64 + c)*16 + cx)*112;
        #pragma unroll
        for (int mt = 0; mt < 7; ++mt)
            *(f32x4*)(vp + mt*16 + q*4) = acc[mt];
    }
}

// ---------------- reduce Vpart (all branches) -> ocat ----------------------
__global__ void reduce_v_k(const float* __restrict__ Vp, float* __restrict__ oc){
    int idx = blockIdx.x*256 + threadIdx.x;
    if (idx >= 3*B_*C_*F_) return;
    int f = idx % F_; int rest = idx / F_;
    int c = rest % C_; rest /= C_;
    int b = rest % B_; int br = rest / B_;
    const float* src = Vp + (size_t)br*VPS + ((size_t)(b*64 + c)*16)*112 + f;
    float s = 0.f;
    #pragma unroll
    for (int cx = 0; cx < 16; ++cx) s += src[cx*112];
    oc[((size_t)b*C_ + c)*OC_ + 256 + br*100 + f] = s;
}

// ---------------- GCN ----------------
__global__ void gather_nodes_k(const int* __restrict__ nodes, const float* __restrict__ emb,
                               float* __restrict__ ne){
    int idx = blockIdx.x*256 + threadIdx.x;
    if (idx >= B_*NN_*D_) return;
    int d = idx & 255, n = (idx >> 8) & 511, b = idx >> 17;
    ne[idx] = emb[(size_t)nodes[b*NN_ + n]*D_ + d];
}
__global__ void deg_count_k(const int* __restrict__ edges, int* __restrict__ deg){
    int idx = blockIdx.x*256 + threadIdx.x;
    if (idx >= B_*EE_) return;
    int b = idx >> 13, e = idx & (EE_-1);
    int dst = edges[b*2*EE_ + EE_ + e];
    atomicAdd(&deg[b*NN_ + dst], 1);
}
__global__ void dinv_k(const int* __restrict__ deg, float* __restrict__ dinv){
    int i = blockIdx.x*256 + threadIdx.x;
    if (i < B_*NN_) dinv[i] = 1.0f / sqrtf((float)deg[i]);
}
__global__ void scan_csr_k(const int* __restrict__ deg, int* __restrict__ rp, int* __restrict__ cur){
    int b = blockIdx.x, t = threadIdx.x;    // 512 threads
    __shared__ int sh[NN_];
    int v = deg[b*NN_ + t];
    sh[t] = v; __syncthreads();
    for (int off = 1; off < NN_; off <<= 1){
        int x = (t >= off) ? sh[t-off] : 0;
        __syncthreads();
        sh[t] += x;
        __syncthreads();
    }
    int incl = sh[t], excl = incl - v;
    rp[b*513 + t] = excl;
    cur[b*NN_ + t] = excl;
    if (t == NN_-1) rp[b*513 + NN_] = incl;
}
__global__ void fill_csr_k(const int* __restrict__ edges, int* __restrict__ cur, int* __restrict__ adj){
    int e = blockIdx.x*256 + threadIdx.x, b = blockIdx.y;
    if (e >= ADJ_) return;
    int s, d;
    if (e < EE_){ s = edges[b*2*EE_ + e]; d = edges[b*2*EE_ + EE_ + e]; }
    else        { s = d = e - EE_; }
    int pos = atomicAdd(&cur[b*NN_ + d], 1);
    adj[b*ADJ_ + pos] = s;
}
__global__ __launch_bounds__(256) void gemm_nt_k(const float* __restrict__ A,
                                                 const float* __restrict__ W,
                                                 float* __restrict__ out){
    int b = blockIdx.z, n0 = blockIdx.x*64, i0 = blockIdx.y*64;
    __shared__ float aL[64][17], wL[64][17];
    int tid = threadIdx.x, tx = tid & 15, ty = tid >> 4;
    const float* Ab = A + (size_t)b*NN_*D_;
    float acc[4][4];
    #pragma unroll
    for (int r = 0; r < 4; ++r)
        #pragma unroll
        for (int i = 0; i < 4; ++i) acc[r][i] = 0.f;
    for (int j0 = 0; j0 < D_; j0 += 16){
        for (int idx = tid; idx < 1024; idx += 256){
            int r = idx >> 4, cc = idx & 15;
            aL[r][cc] = Ab[(size_t)(n0+r)*D_ + j0 + cc];
            wL[r][cc] = W[(size_t)(i0+r)*D_ + j0 + cc];
        }
        __syncthreads();
        #pragma unroll
        for (int kk = 0; kk < 16; ++kk){
            float av[4], wv[4];
            #pragma unroll
            for (int r = 0; r < 4; ++r) av[r] = aL[ty*4+r][kk];
            #pragma unroll
            for (int i = 0; i < 4; ++i) wv[i] = wL[tx*4+i][kk];
            #pragma unroll
            for (int r = 0; r < 4; ++r)
                #pragma unroll
                for (int i = 0; i < 4; ++i) acc[r][i] = fmaf(av[r], wv[i], acc[r][i]);
        }
        __syncthreads();
    }
    float* ob = out + (size_t)b*NN_*D_;
    #pragma unroll
    for (int r = 0; r < 4; ++r)
        #pragma unroll
        for (int i = 0; i < 4; ++i)
            ob[(size_t)(n0+ty*4+r)*D_ + i0+tx*4+i] = acc[r][i];
}
__global__ __launch_bounds__(256) void scatter_k(const float* __restrict__ xw,
                                                 const int* __restrict__ adj,
                                                 const int* __restrict__ rp,
                                                 const float* __restrict__ dinv,
                                                 const float* __restrict__ bias,
                                                 float* __restrict__ out,
                                                 int out_bs, int out_ld, int relu){
    int n = blockIdx.x, b = blockIdx.y, t = threadIdx.x;
    const int* rpb = rp + b*513;
    const int* adjb = adj + b*ADJ_;
    const float* xwb = xw + (size_t)b*NN_*D_;
    const float* dvb = dinv + b*NN_;
    int e0 = rpb[n], e1 = rpb[n+1];
    float acc = 0.f;
    for (int e = e0; e < e1; ++e){
        int s = adjb[e];
        acc = fmaf(xwb[(size_t)s*D_ + t], dvb[s], acc);
    }
    float v = fmaf(acc, dvb[n], bias[t]);
    if (relu) v = fmaxf(v, 0.f);
    out[(size_t)b*out_bs + (size_t)n*out_ld + t] = v;
}

// ---------------- fused head ----------------
__global__ __launch_bounds__(128) void final_k(const float* __restrict__ oc,
                                               const float* __restrict__ w1t,
                                               const float* __restrict__ b1,
                                               const float* __restrict__ w2,
                                               const float* __restrict__ b2,
                                               float* __restrict__ y){
    int c = blockIdx.x, b = blockIdx.y, h = threadIdx.x;
    __shared__ float row[OC_];
    __shared__ float red[128];
    const float* src = oc + ((size_t)b*C_ + c)*OC_;
    for (int j = h; j < OC_; j += 128) row[j] = src[j];
    __syncthreads();
    float acc = b1[h];
    #pragma unroll 8
    for (int j = 0; j < OC_; ++j) acc = fmaf(row[j], w1t[j*128 + h], acc);
    float hid = fmaxf(acc, 0.f);
    red[h] = hid * w2[c*128 + h];
    __syncthreads();
    for (int o = 64; o > 0; o >>= 1){ if (h < o) red[h] += red[h+o]; __syncthreads(); }
    if (h == 0) y[b*C_ + c] = red[0] + b2[c];
}

// ===========================================================================
extern "C" void kernel_launch(void* const* d_in, const int* in_sizes, int n_in,
                              void* d_out, int out_size, void* d_ws, size_t ws_size,
                              hipStream_t stream){
    (void)in_sizes; (void)n_in; (void)out_size; (void)ws_size;
    const int*   x          = (const int*)d_in[0];
    const int*   nodes      = (const int*)d_in[2];
    const int*   edges      = (const int*)d_in[3];
    const float* word_emb   = (const float*)d_in[4];
    const float* entity_emb = (const float*)d_in[5];
    const float* bn_gamma   = (const float*)d_in[15];
    const float* bn_beta    = (const float*)d_in[16];
    const float* gc1_w      = (const float*)d_in[19];
    const float* gc1_b      = (const float*)d_in[20];
    const float* gc2_w      = (const float*)d_in[21];
    const float* gc2_b      = (const float*)d_in[22];
    const float* fin1_w     = (const float*)d_in[23];
    const float* fin1_b     = (const float*)d_in[24];
    const float* fin2_w     = (const float*)d_in[25];
    const float* fin2_b     = (const float*)d_in[26];
    float* y = (float*)d_out;

    // ---- workspace layout (~208 MB; R8's 311 MB crashed) ----
    char* base = (char*)d_ws;
    size_t off = 0;
    auto alloc = [&](size_t bytes) -> char* {
        char* p = base + off;
        off += ((bytes + 255) / 256) * 256;
        return p;
    };
    u16* t0 = (u16*)alloc(3*PLANE*2);
    u16* t1 = (u16*)alloc(3*PLANE*2);
    u16* hH = t1;                          // alias: hH (2*PLANE) dead after conv1
    u16* tT = (u16*)alloc(3*TTS*2);
    u16* S  = (u16*)alloc(3*SST*2);        // bf16
    // GCN scratch region, later reused as Vpart (22.0 MB <= 25.2 MB)
    char* G = alloc((size_t)3*B_*NN_*D_*4);
    float* ne = (float*)G;
    float* xw = ne + (size_t)B_*NN_*D_;
    float* g1 = xw + (size_t)B_*NN_*D_;
    float* Vpart = (float*)G;
    float* ocat = (float*)alloc((size_t)B_*C_*OC_*4);
    u16* wfc1  = (u16*)alloc(3*WFC1_STRIDE*2);
    u16* wfres = (u16*)alloc(6*WFRES_STRIDE*2);
    u16* wfaw  = (u16*)alloc(3*WFAW_STRIDE*2);
    u16* wfau  = (u16*)alloc(3*WFAU_STRIDE*2);
    float* w1t   = (float*)alloc((size_t)OC_*128*4);
    float* dinvp = (float*)alloc((size_t)B_*NN_*4);
    int* deg = (int*)alloc((size_t)B_*NN_*4);
    int* rpB = (int*)alloc((size_t)B_*513*4);
    int* cur = (int*)alloc((size_t)B_*NN_*4);
    int* adj = (int*)alloc((size_t)B_*ADJ_*4);

    // ---- init & weight packing ----
    fill_i_k<<<CDIV(B_*NN_,256),256,0,stream>>>(deg, B_*NN_, 1);
    zero_pads3_k<<<CDIV(3*B_*16*128,256),256,0,stream>>>(t0);
    pack_conv1_k<<<dim3(CDIV(9*8*8*512,256),3),256,0,stream>>>(
        (const float*)d_in[6], (const float*)d_in[9], (const float*)d_in[12], wfc1);
    pack_res_k<<<dim3(CDIV(9*4*8*512,256),3,2),256,0,stream>>>(
        (const float*)d_in[8], (const float*)d_in[11], (const float*)d_in[14], wfres);
    pack_aw_k<<<dim3(CDIV(4*16*512,256),3),256,0,stream>>>((const float*)d_in[17], wfaw);
    pack_au_k<<<dim3(CDIV(8*4*512,256),3),256,0,stream>>>((const float*)d_in[18], wfau);

    // ---- embedding (hH lives in the t1 region; t1 pads zeroed after conv1) --
    embed1_k<<<dim3(LP_/8, B_),256,0,stream>>>(x, word_emb, hH);

    // ---- GCN (scratch region G; freed for Vpart afterwards) ----
    gather_nodes_k<<<CDIV(B_*NN_*D_,256),256,0,stream>>>(nodes, entity_emb, ne);
    deg_count_k<<<CDIV(B_*EE_,256),256,0,stream>>>(edges, deg);
    dinv_k<<<CDIV(B_*NN_,256),256,0,stream>>>(deg, dinvp);
    scan_csr_k<<<B_,NN_,0,stream>>>(deg, rpB, cur);
    fill_csr_k<<<dim3(CDIV(ADJ_,256),B_),256,0,stream>>>(edges, cur, adj);
    gemm_nt_k<<<dim3(NN_/64, D_/64, B_),256,0,stream>>>(ne, gc1_w, xw);
    scatter_k<<<dim3(NN_,B_),256,0,stream>>>(xw, adj, rpB, dinvp, gc1_b, g1, NN_*D_, D_, 1);
    gemm_nt_k<<<dim3(NN_/64, D_/64, B_),256,0,stream>>>(g1, gc2_w, xw);
    scatter_k<<<dim3(C_,B_),256,0,stream>>>(xw, adj, rpB, dinvp, gc2_b, ocat, C_*OC_, OC_, 0);

    // ---- encoder: branch-fused dispatches ----
    dim3 gc(64, B_, 3), ga(32, B_, 3);
    // conv1 (all branches): hH -> t0[br]
    conv_mfma_k<0,8><<<gc,256,0,stream>>>(hH, 256, 0,
        wfc1, (long)WFC1_STRIDE,
        (const float*)d_in[7], (const float*)d_in[10], (const float*)d_in[13],
        bn_gamma, bn_beta, 0, t0, nullptr);
    // hH dead; prepare t1 pads (same memory region)
    zero_pads3_k<<<CDIV(3*B_*16*128,256),256,0,stream>>>(t1);
    // res1 (all branches): t0[br] -> t1[br]
    conv_mfma_k<1,4><<<gc,256,0,stream>>>(t0, 128, (long)PLANE,
        wfres, (long)(2*WFRES_STRIDE),
        nullptr, nullptr, nullptr,
        bn_gamma, bn_beta, 100, t1, nullptr);
    // res2 (all branches): t1[br] -> t0[br] + tT[br]
    conv_mfma_k<1,4><<<gc,256,0,stream>>>(t1, 128, (long)PLANE,
        wfres + WFRES_STRIDE, (long)(2*WFRES_STRIDE),
        nullptr, nullptr, nullptr,
        bn_gamma, bn_beta, 200, t0, tT);
    // attention + softmax + V for all branches
    attn_k<<<ga,256,0,stream>>>(t0, wfaw, wfau, S);
    softmax_k<<<dim3(C_,B_,3),256,0,stream>>>(S);
    v_mfma_k<<<dim3(16,B_,3),256,0,stream>>>(tT, S, Vpart);
    reduce_v_k<<<CDIV(3*B_*C_*F_,256),256,0,stream>>>(Vpart, ocat);

    // ---- head ----
    transpose_fin1_k<<<CDIV(OC_*128,256),256,0,stream>>>(fin1_w, w1t);
    final_k<<<dim3(C_,B_),128,0,stream>>>(ocat, w1t, fin1_b, fin2_w, fin2_b, y);
}

// Round 10
// 687.722 us; speedup vs baseline: 5.3285x; 1.0301x over previous
//
#include <hip/hip_runtime.h>

// ---------------------------------------------------------------------------
// Model_81990925681018 — Round 10: compile-time-KT conv paths inside the
// branch-fused kernel. R9's runtime kt loop was VALU-bound (VALUBusy 50% >
// MfmaUtil 31%): unrollable KT*4 loop lets the compiler fold all 4 B-LDS
// addresses per iteration into ds_read immediate offsets (zero VALU) and
// strength-reduce A-prefetch addressing.
// ---------------------------------------------------------------------------

#define CDIV(a,b) (((a)+(b)-1)/(b))

#define B_    16
#define L_    4096
#define D_    256
#define LP_   4112      // L + 2*POFF
#define POFF  8
#define F_    100
#define A_    256
#define C_    50
#define NN_   512
#define EE_   8192
#define ADJ_  8704
#define OC_   560

#define PLANE ((size_t)B_*LP_*128)     // one branch t-plane (shorts)
#define TTS   ((size_t)B_*128*L_)      // one branch tT plane (shorts)
#define SST   ((size_t)B_*64*L_)       // one branch S (bf16 elems)
#define VPS   ((size_t)B_*64*16*112)   // one branch Vpart (floats), 16 chunks

#define WFC1_STRIDE ((size_t)9*8*8*512)   // per-branch conv1 frag stride (shorts)
#define WFRES_STRIDE ((size_t)9*4*8*512)  // per (branch,block) res frag stride
#define WFAW_STRIDE ((size_t)4*16*512)
#define WFAU_STRIDE ((size_t)8*4*512)

typedef unsigned short u16;
using short8  = __attribute__((ext_vector_type(8))) short;
using short4v = __attribute__((ext_vector_type(4))) short;
using f32x4   = __attribute__((ext_vector_type(4))) float;

__device__ __forceinline__ u16 f2b(float f){
    unsigned u = __float_as_uint(f);
    u += 0x7FFF + ((u >> 16) & 1);
    return (u16)(u >> 16);
}
__device__ __forceinline__ float b2f(u16 h){ return __uint_as_float(((unsigned)h) << 16); }

// ---------------- utility fills ----------------
__global__ void fill_i_k(int* p, int n, int v){
    int i = blockIdx.x*256 + threadIdx.x; if (i < n) p[i] = v;
}
// zero pad cols of 3 consecutive [b][LP_][128] planes
__global__ void zero_pads3_k(u16* p){
    int idx = blockIdx.x*256 + threadIdx.x;
    if (idx >= 3*B_*16*128) return;
    int ch = idx & 127; int rest = idx >> 7;
    int pc = rest & 15; rest >>= 4;
    int b = rest & 15;  int br = rest >> 4;
    int col = (pc < 8) ? pc : (4096 + pc);
    p[(size_t)br*PLANE + ((size_t)b*LP_ + col)*128 + ch] = 0;
}

// ---------------- embedding gather -> bf16 plane [b][col][256] -------------
__global__ __launch_bounds__(256) void embed1_k(const int* __restrict__ x,
                                                const float* __restrict__ emb,
                                                u16* __restrict__ hH){
    int b = blockIdx.y;
    int col = blockIdx.x*8 + (threadIdx.x >> 5);
    int cg  = (threadIdx.x & 31) * 8;
    size_t o = ((size_t)b*LP_ + col)*D_ + cg;
    int l = col - POFF;
    short8 h0;
    if (l < 0 || l >= L_){
        #pragma unroll
        for (int i = 0; i < 8; ++i) h0[i] = 0;
    } else {
        int tok = x[b*L_ + l];
        const float* s = emb + (size_t)tok*D_ + cg;
        #pragma unroll
        for (int i = 0; i < 8; ++i) h0[i] = (short)f2b(s[i]);
    }
    *(short8*)(hH + o) = h0;
}

// ---------------- weight -> MFMA A-fragment packer (single plane) ----------
__device__ __forceinline__ void pack_frag(const float* src, u16* dst,
                                          int M, int K, int kt, int nch, int MTtot, int idx){
    int i = idx & 7, lane = (idx >> 3) & 63, rest = idx >> 9;
    int mt = rest % MTtot, r2 = rest / MTtot;
    int cc = r2 % nch,  j = r2 / nch;
    int m  = mt*16 + (lane & 15);
    int ch = cc*32 + (lane >> 4)*8 + i;
    float v = (m < M && ch < K) ? src[((size_t)m*K + ch)*kt + j] : 0.f;
    dst[(size_t)rest*512 + lane*8 + i] = f2b(v);
}
__global__ void pack_conv1_k(const float* w3, const float* w5, const float* w9, u16* dst){
    int br = blockIdx.y;
    int k = (br == 0) ? 3 : (br == 1) ? 5 : 9;
    const float* s = (br == 0) ? w3 : (br == 1) ? w5 : w9;
    int idx = blockIdx.x*256 + threadIdx.x;
    if (idx < k*8*8*512) pack_frag(s, dst + (size_t)br*WFC1_STRIDE, F_, 256, k, 8, 8, idx);
}
__global__ void pack_res_k(const float* w3, const float* w5, const float* w9, u16* dst){
    int br = blockIdx.y, blk = blockIdx.z;
    int k = (br == 0) ? 3 : (br == 1) ? 5 : 9;
    const float* s = ((br == 0) ? w3 : (br == 1) ? w5 : w9) + (size_t)blk*F_*F_*k;
    int idx = blockIdx.x*256 + threadIdx.x;
    if (idx < k*4*8*512) pack_frag(s, dst + (size_t)(br*2 + blk)*WFRES_STRIDE, F_, F_, k, 4, 8, idx);
}
__global__ void pack_aw_k(const float* aw, u16* dst){
    int br = blockIdx.y;
    int idx = blockIdx.x*256 + threadIdx.x;
    if (idx < 4*16*512) pack_frag(aw + (size_t)br*A_*F_, dst + (size_t)br*WFAW_STRIDE, A_, F_, 1, 4, 16, idx);
}
__global__ void pack_au_k(const float* au, u16* dst){
    int br = blockIdx.y;
    int idx = blockIdx.x*256 + threadIdx.x;
    if (idx < 8*4*512) pack_frag(au + (size_t)br*C_*A_, dst + (size_t)br*WFAU_STRIDE, C_, A_, 1, 8, 4, idx);
}
// fin1_w[128][556] -> w1t[560][128] zero-padded
__global__ void transpose_fin1_k(const float* __restrict__ src, float* __restrict__ dst){
    int idx = blockIdx.x*256 + threadIdx.x;
    if (idx >= OC_*128) return;
    int h = idx & 127, j = idx >> 7;
    dst[idx] = (j < 556) ? src[h*556 + j] : 0.f;
}

// ---------------- conv main loop, compile-time KT (fully unrolled) ---------
template<int KT, int NCH>
__device__ __forceinline__ void conv_loop(
    const u16* __restrict__ inb, int CHp_in,
    const u16* __restrict__ wf,
    short* sm, int n0, int tid, int w, int lane, int q, int lr,
    f32x4 (&acc)[2][4])
{
    constexpr int NPASS = NCH / 4;
    for (int pass = 0; pass < NPASS; ++pass){
        // ---- stage 4 chunks: 80 cols x 32 ch each ----
        #pragma unroll
        for (int s5 = 0; s5 < 5; ++s5){
            int idx = s5*256 + tid;
            int cc = idx / 320;
            int e = idx - cc*320;
            int col = e >> 2, qq = e & 3;
            *(short8*)(sm + cc*3200 + col*40 + qq*8) =
                *(const short8*)(inb + (size_t)(n0 + col)*CHp_in + (pass*4 + cc)*32 + qq*8);
        }
        __syncthreads();
        // wbase: frag for (j=0, cc=pass*4, this wave/lane)
        const u16* wbase = wf + ((size_t)(pass*4)*8 + w*2)*512 + lane*8;
        // bbase: LDS B base for (j=0, n=0, this lane) — all per-it offsets are
        // compile-time constants -> ds_read immediate offsets, zero VALU.
        const short* bbase = sm + (8 - (KT >> 1) + lr)*40 + q*8;
        short8 Ac0 = *(const short8*)(wbase);
        short8 Ac1 = *(const short8*)(wbase + 512);
        #pragma unroll
        for (int it = 0; it < KT*4; ++it){
            const int j = it >> 2, cc = it & 3;
            short8 An0, An1;
            if (it + 1 < KT*4){
                const int jn = (it+1) >> 2, ccn = (it+1) & 3;
                const u16* fn = wbase + (size_t)(jn*NCH + ccn)*8*512;
                An0 = *(const short8*)(fn);
                An1 = *(const short8*)(fn + 512);
            }
            short8 Bv[4];
            #pragma unroll
            for (int n = 0; n < 4; ++n)
                Bv[n] = *(const short8*)(bbase + cc*3200 + (j + n*16)*40);
            #pragma unroll
            for (int n = 0; n < 4; ++n){
                acc[0][n] = __builtin_amdgcn_mfma_f32_16x16x32_bf16(Ac0, Bv[n], acc[0][n], 0,0,0);
                acc[1][n] = __builtin_amdgcn_mfma_f32_16x16x32_bf16(Ac1, Bv[n], acc[1][n], 0,0,0);
            }
            if (it + 1 < KT*4){ Ac0 = An0; Ac1 = An1; }
        }
        __syncthreads();
    }
}

// ---------------- MFMA shifted-GEMM conv, 64-col tile, branch-fused --------
// grid (64, B, 3). Per-block (wave-uniform) dispatch to compile-time KT path.
// MODE 0: tanh(acc+bias)*s+beta ; MODE 1: tanh(acc*s+beta+resid)
template<int MODE, int NCH>
__global__ __launch_bounds__(256) void conv_mfma_k(
    const u16* __restrict__ in_base, int CHp_in, long in_bs,
    const u16* __restrict__ wf_base, long wf_bs,
    const float* __restrict__ bias0, const float* __restrict__ bias1,
    const float* __restrict__ bias2,
    const float* __restrict__ gamma_base, const float* __restrict__ beta_base, int layeroff,
    u16* __restrict__ out_base, u16* __restrict__ outT_base)
{
    __shared__ short sm[12800];  // staging 4 chunks x 80x40 ; epilogue 32x136
    const int tid = threadIdx.x, lane = tid & 63;
    const int w = tid >> 6;
    const int q = lane >> 4, lr = lane & 15;
    const int n0 = blockIdx.x * 64;
    const int b  = blockIdx.y;
    const int br = blockIdx.z;
    const u16* in = in_base + (size_t)br*in_bs;
    const u16* wf = wf_base + (size_t)br*wf_bs;
    const float* bias = (MODE == 0) ? ((br == 0) ? bias0 : (br == 1) ? bias1 : bias2) : nullptr;
    const float* gamma = gamma_base + br*300 + layeroff;
    const float* beta  = beta_base  + br*300 + layeroff;
    u16* out  = out_base + (size_t)br*PLANE;
    u16* outT = outT_base ? (outT_base + (size_t)br*TTS) : nullptr;
    const u16* inb = in + (size_t)b*LP_*CHp_in;

    f32x4 acc[2][4];
    #pragma unroll
    for (int t = 0; t < 2; ++t)
        #pragma unroll
        for (int n = 0; n < 4; ++n) acc[t][n] = (f32x4){0.f,0.f,0.f,0.f};

    if (br == 0)      conv_loop<3,NCH>(inb, CHp_in, wf, sm, n0, tid, w, lane, q, lr, acc);
    else if (br == 1) conv_loop<5,NCH>(inb, CHp_in, wf, sm, n0, tid, w, lane, q, lr, acc);
    else              conv_loop<9,NCH>(inb, CHp_in, wf, sm, n0, tid, w, lane, q, lr, acc);

    // ---- epilogue: transpose to [col][128] plane via LDS, 2 passes of 32 cols
    const float BNS = 0.9999950000374997f; // 1/sqrt(1+1e-5)
    for (int p = 0; p < 2; ++p){
        #pragma unroll
        for (int t = 0; t < 2; ++t){
            #pragma unroll
            for (int u = 0; u < 2; ++u){
                int n = p*2 + u;
                int mbase = w*32 + t*16 + q*4;
                int cl = u*16 + lr;
                int colg = n0 + n*16 + lr;
                float rsum[4] = {0.f,0.f,0.f,0.f};
                if (MODE == 1){
                    size_t ro = ((size_t)b*LP_ + POFF + colg)*CHp_in + mbase;
                    short4v rh = *(const short4v*)(in + ro);
                    #pragma unroll
                    for (int r = 0; r < 4; ++r) rsum[r] = b2f((u16)rh[r]);
                }
                short4v hv;
                #pragma unroll
                for (int r = 0; r < 4; ++r){
                    int mm = mbase + r;
                    float a = acc[t][n][r];
                    float v;
                    if (MODE == 0){
                        float bi=0.f, s=0.f, be=0.f;
                        if (mm < F_){ bi = bias[mm]; s = gamma[mm]*BNS; be = beta[mm]; }
                        v = tanhf(a + bi)*s + be;
                    } else {
                        float s=0.f, be=0.f;
                        if (mm < F_){ s = gamma[mm]*BNS; be = beta[mm]; }
                        v = tanhf(fmaf(a, s, be) + rsum[r]);
                    }
                    hv[r] = (short)f2b(v);
                }
                *(short4v*)(sm + cl*136 + mbase) = hv;
            }
        }
        __syncthreads();
        for (int idx = tid; idx < 512; idx += 256){
            int col = idx >> 4, q8 = idx & 15;
            short8 vv = *(const short8*)(sm + col*136 + q8*8);
            *(short8*)(out + ((size_t)b*LP_ + POFF + n0 + p*32 + col)*128 + q8*8) = vv;
        }
        if (outT){
            int f = tid & 127, half = tid >> 7;
            u16 vals[16];
            #pragma unroll
            for (int i = 0; i < 16; ++i) vals[i] = (u16)sm[(half*16 + i)*136 + f];
            short8 v0, v1;
            #pragma unroll
            for (int i = 0; i < 8; ++i){ v0[i] = (short)vals[i]; v1[i] = (short)vals[8+i]; }
            u16* dst = outT + ((size_t)b*128 + f)*L_ + n0 + p*32 + half*16;
            *(short8*)dst = v0;
            *(short8*)(dst + 8) = v1;
        }
        __syncthreads();
    }
}

// ---------------- fused attention (branch-fused): S = au.tanh(aw.t) --------
// S stored bf16, 64 rows/b (rows 50..63 exact zeros from au padding).
__global__ __launch_bounds__(256) void attn_k(const u16* __restrict__ t_base,
                                              const u16* __restrict__ awf_base,
                                              const u16* __restrict__ auf_base,
                                              u16* __restrict__ S_base){
    __shared__ short sm[17408];   // t-slab 128*136 ; reused as Z 64*264
    const int tid = threadIdx.x, lane = tid & 63;
    const int w = tid >> 6, wm = w >> 1, wn = w & 1;
    const int q = lane >> 4, lr = lane & 15;
    const int n0 = blockIdx.x * 128;
    const int b  = blockIdx.y;
    const int br = blockIdx.z;
    const u16* tpl = t_base + (size_t)br*PLANE;
    const u16* awf = awf_base + (size_t)br*WFAW_STRIDE;
    const u16* auf = auf_base + (size_t)br*WFAU_STRIDE;
    u16* S = S_base + (size_t)br*SST;

    for (int idx = tid; idx < 2048; idx += 256){
        int col = idx >> 4, g = idx & 15;
        *(short8*)(sm + col*136 + g*8) =
            *(const short8*)(tpl + ((size_t)b*LP_ + POFF + n0 + col)*128 + g*8);
    }
    __syncthreads();

    f32x4 acc1[8][4];
    #pragma unroll
    for (int t = 0; t < 8; ++t)
        #pragma unroll
        for (int n = 0; n < 4; ++n) acc1[t][n] = (f32x4){0.f,0.f,0.f,0.f};
    for (int cc = 0; cc < 4; ++cc){
        short8 Af[8];
        const u16* fp = awf + (size_t)(cc*16 + wm*8)*512 + lane*8;
        #pragma unroll
        for (int t = 0; t < 8; ++t) Af[t] = *(const short8*)(fp + (size_t)t*512);
        short8 Bf[4];
        #pragma unroll
        for (int n = 0; n < 4; ++n)
            Bf[n] = *(const short8*)(sm + (wn*64 + n*16 + lr)*136 + cc*32 + q*8);
        #pragma unroll
        for (int t = 0; t < 8; ++t)
            #pragma unroll
            for (int n = 0; n < 4; ++n)
                acc1[t][n] = __builtin_amdgcn_mfma_f32_16x16x32_bf16(Af[t], Bf[n], acc1[t][n], 0,0,0);
    }
    __syncthreads();

    for (int p = 0; p < 2; ++p){
        if (wn == p){
            #pragma unroll
            for (int t = 0; t < 8; ++t){
                #pragma unroll
                for (int n = 0; n < 4; ++n){
                    int abase = wm*128 + t*16 + q*4;
                    int cl = n*16 + lr;
                    short4v zv;
                    #pragma unroll
                    for (int r = 0; r < 4; ++r) zv[r] = (short)f2b(tanhf(acc1[t][n][r]));
                    *(short4v*)(sm + cl*264 + abase) = zv;
                }
            }
        }
        __syncthreads();
        f32x4 acc2[4];
        #pragma unroll
        for (int t = 0; t < 4; ++t) acc2[t] = (f32x4){0.f,0.f,0.f,0.f};
        for (int cc = 0; cc < 8; ++cc){
            short8 Af2[4];
            const u16* fp2 = auf + (size_t)(cc*4)*512 + lane*8;
            #pragma unroll
            for (int t = 0; t < 4; ++t) Af2[t] = *(const short8*)(fp2 + (size_t)t*512);
            short8 Bf2 = *(const short8*)(sm + (w*16 + lr)*264 + cc*32 + q*8);
            #pragma unroll
            for (int t = 0; t < 4; ++t)
                acc2[t] = __builtin_amdgcn_mfma_f32_16x16x32_bf16(Af2[t], Bf2, acc2[t], 0,0,0);
        }
        #pragma unroll
        for (int t = 0; t < 4; ++t)
            #pragma unroll
            for (int r = 0; r < 4; ++r){
                int c = t*16 + q*4 + r;   // 0..63, padded S
                S[((size_t)b*64 + c)*L_ + n0 + p*64 + w*16 + lr] = f2b(acc2[t][r]);
            }
        __syncthreads();
    }
}

// ---------------- softmax over L per (br,b,c) bf16 row, in place -----------
__global__ __launch_bounds__(256) void softmax_k(u16* __restrict__ S){
    int c = blockIdx.x, b = blockIdx.y, br = blockIdx.z, t = threadIdx.x;
    u16* p = S + (size_t)br*SST + ((size_t)b*64 + c)*L_;
    __shared__ float sh[256];
    float mx = -1e30f;
    for (int j = t; j < L_; j += 256) mx = fmaxf(mx, b2f(p[j]));
    sh[t] = mx; __syncthreads();
    for (int o = 128; o > 0; o >>= 1){ if (t < o) sh[t] = fmaxf(sh[t], sh[t+o]); __syncthreads(); }
    float m = sh[0]; __syncthreads();
    float sum = 0.f;
    for (int j = t; j < L_; j += 256){ float e = expf(b2f(p[j]) - m); p[j] = f2b(e); sum += e; }
    sh[t] = sum; __syncthreads();
    for (int o = 128; o > 0; o >>= 1){ if (t < o) sh[t] += sh[t+o]; __syncthreads(); }
    float inv = 1.0f / sh[0];
    for (int j = t; j < L_; j += 256) p[j] = f2b(b2f(p[j]) * inv);
}

// ---------------- V-GEMM (branch-fused): 16 chunks of 256 cols -------------
__global__ __launch_bounds__(256) void v_mfma_k(const u16* __restrict__ tT_base,
                                                const u16* __restrict__ S_base,
                                                float* __restrict__ Vp_base){
    int cx = blockIdx.x, b = blockIdx.y, br = blockIdx.z;
    int w = threadIdx.x >> 6, lane = threadIdx.x & 63;
    int q = lane >> 4, lr = lane & 15;
    int l0 = cx*256;
    f32x4 acc[7];
    #pragma unroll
    for (int mt = 0; mt < 7; ++mt) acc[mt] = (f32x4){0.f,0.f,0.f,0.f};
    const u16* tb = tT_base + (size_t)br*TTS + (size_t)b*128*L_;
    const u16* Sb = S_base + (size_t)br*SST + ((size_t)b*64 + w*16 + lr)*L_;
    #pragma unroll
    for (int kk = 0; kk < 8; ++kk){
        int l = l0 + kk*32 + q*8;
        short8 Bf = *(const short8*)(Sb + l);
        #pragma unroll
        for (int mt = 0; mt < 7; ++mt){
            short8 Af = *(const short8*)(tb + (size_t)(mt*16 + lr)*L_ + l);
            acc[mt] = __builtin_amdgcn_mfma_f32_16x16x32_bf16(Af, Bf, acc[mt], 0,0,0);
        }
    }
    int c = w*16 + lr;
    if (c < C_){
        float* vp = Vp_base + (size_t)br*VPS + ((size_t)(b*64 + c)*16 + cx)*112;
        #pragma unroll
        for (int mt = 0; mt < 7; ++mt)
            *(f32x4*)(vp + mt*16 + q*4) = acc[mt];
    }
}

// ---------------- reduce Vpart (all branches) -> ocat ----------------------
__global__ void reduce_v_k(const float* __restrict__ Vp, float* __restrict__ oc){
    int idx = blockIdx.x*256 + threadIdx.x;
    if (idx >= 3*B_*C_*F_) return;
    int f = idx % F_; int rest = idx / F_;
    int c = rest % C_; rest /= C_;
    int b = rest % B_; int br = rest / B_;
    const float* src = Vp + (size_t)br*VPS + ((size_t)(b*64 + c)*16)*112 + f;
    float s = 0.f;
    #pragma unroll
    for (int cx = 0; cx < 16; ++cx) s += src[cx*112];
    oc[((size_t)b*C_ + c)*OC_ + 256 + br*100 + f] = s;
}

// ---------------- GCN ----------------
__global__ void gather_nodes_k(const int* __restrict__ nodes, const float* __restrict__ emb,
                               float* __restrict__ ne){
    int idx = blockIdx.x*256 + threadIdx.x;
    if (idx >= B_*NN_*D_) return;
    int d = idx & 255, n = (idx >> 8) & 511, b = idx >> 17;
    ne[idx] = emb[(size_t)nodes[b*NN_ + n]*D_ + d];
}
__global__ void deg_count_k(const int* __restrict__ edges, int* __restrict__ deg){
    int idx = blockIdx.x*256 + threadIdx.x;
    if (idx >= B_*EE_) return;
    int b = idx >> 13, e = idx & (EE_-1);
    int dst = edges[b*2*EE_ + EE_ + e];
    atomicAdd(&deg[b*NN_ + dst], 1);
}
__global__ void dinv_k(const int* __restrict__ deg, float* __restrict__ dinv){
    int i = blockIdx.x*256 + threadIdx.x;
    if (i < B_*NN_) dinv[i] = 1.0f / sqrtf((float)deg[i]);
}
__global__ void scan_csr_k(const int* __restrict__ deg, int* __restrict__ rp, int* __restrict__ cur){
    int b = blockIdx.x, t = threadIdx.x;    // 512 threads
    __shared__ int sh[NN_];
    int v = deg[b*NN_ + t];
    sh[t] = v; __syncthreads();
    for (int off = 1; off < NN_; off <<= 1){
        int x = (t >= off) ? sh[t-off] : 0;
        __syncthreads();
        sh[t] += x;
        __syncthreads();
    }
    int incl = sh[t], excl = incl - v;
    rp[b*513 + t] = excl;
    cur[b*NN_ + t] = excl;
    if (t == NN_-1) rp[b*513 + NN_] = incl;
}
__global__ void fill_csr_k(const int* __restrict__ edges, int* __restrict__ cur, int* __restrict__ adj){
    int e = blockIdx.x*256 + threadIdx.x, b = blockIdx.y;
    if (e >= ADJ_) return;
    int s, d;
    if (e < EE_){ s = edges[b*2*EE_ + e]; d = edges[b*2*EE_ + EE_ + e]; }
    else        { s = d = e - EE_; }
    int pos = atomicAdd(&cur[b*NN_ + d], 1);
    adj[b*ADJ_ + pos] = s;
}
__global__ __launch_bounds__(256) void gemm_nt_k(const float* __restrict__ A,
                                                 const float* __restrict__ W,
                                                 float* __restrict__ out){
    int b = blockIdx.z, n0 = blockIdx.x*64, i0 = blockIdx.y*64;
    __shared__ float aL[64][17], wL[64][17];
    int tid = threadIdx.x, tx = tid & 15, ty = tid >> 4;
    const float* Ab = A + (size_t)b*NN_*D_;
    float acc[4][4];
    #pragma unroll
    for (int r = 0; r < 4; ++r)
        #pragma unroll
        for (int i = 0; i < 4; ++i) acc[r][i] = 0.f;
    for (int j0 = 0; j0 < D_; j0 += 16){
        for (int idx = tid; idx < 1024; idx += 256){
            int r = idx >> 4, cc = idx & 15;
            aL[r][cc] = Ab[(size_t)(n0+r)*D_ + j0 + cc];
            wL[r][cc] = W[(size_t)(i0+r)*D_ + j0 + cc];
        }
        __syncthreads();
        #pragma unroll
        for (int kk = 0; kk < 16; ++kk){
            float av[4], wv[4];
            #pragma unroll
            for (int r = 0; r < 4; ++r) av[r] = aL[ty*4+r][kk];
            #pragma unroll
            for (int i = 0; i < 4; ++i) wv[i] = wL[tx*4+i][kk];
            #pragma unroll
            for (int r = 0; r < 4; ++r)
                #pragma unroll
                for (int i = 0; i < 4; ++i) acc[r][i] = fmaf(av[r], wv[i], acc[r][i]);
        }
        __syncthreads();
    }
    float* ob = out + (size_t)b*NN_*D_;
    #pragma unroll
    for (int r = 0; r < 4; ++r)
        #pragma unroll
        for (int i = 0; i < 4; ++i)
            ob[(size_t)(n0+ty*4+r)*D_ + i0+tx*4+i] = acc[r][i];
}
__global__ __launch_bounds__(256) void scatter_k(const float* __restrict__ xw,
                                                 const int* __restrict__ adj,
                                                 const int* __restrict__ rp,
                                                 const float* __restrict__ dinv,
                                                 const float* __restrict__ bias,
                                                 float* __restrict__ out,
                                                 int out_bs, int out_ld, int relu){
    int n = blockIdx.x, b = blockIdx.y, t = threadIdx.x;
    const int* rpb = rp + b*513;
    const int* adjb = adj + b*ADJ_;
    const float* xwb = xw + (size_t)b*NN_*D_;
    const float* dvb = dinv + b*NN_;
    int e0 = rpb[n], e1 = rpb[n+1];
    float acc = 0.f;
    for (int e = e0; e < e1; ++e){
        int s = adjb[e];
        acc = fmaf(xwb[(size_t)s*D_ + t], dvb[s], acc);
    }
    float v = fmaf(acc, dvb[n], bias[t]);
    if (relu) v = fmaxf(v, 0.f);
    out[(size_t)b*out_bs + (size_t)n*out_ld + t] = v;
}

// ---------------- fused head ----------------
__global__ __launch_bounds__(128) void final_k(const float* __restrict__ oc,
                                               const float* __restrict__ w1t,
                                               const float* __restrict__ b1,
                                               const float* __restrict__ w2,
                                               const float* __restrict__ b2,
                                               float* __restrict__ y){
    int c = blockIdx.x, b = blockIdx.y, h = threadIdx.x;
    __shared__ float row[OC_];
    __shared__ float red[128];
    const float* src = oc + ((size_t)b*C_ + c)*OC_;
    for (int j = h; j < OC_; j += 128) row[j] = src[j];
    __syncthreads();
    float acc = b1[h];
    #pragma unroll 8
    for (int j = 0; j < OC_; ++j) acc = fmaf(row[j], w1t[j*128 + h], acc);
    float hid = fmaxf(acc, 0.f);
    red[h] = hid * w2[c*128 + h];
    __syncthreads();
    for (int o = 64; o > 0; o >>= 1){ if (h < o) red[h] += red[h+o]; __syncthreads(); }
    if (h == 0) y[b*C_ + c] = red[0] + b2[c];
}

// ===========================================================================
extern "C" void kernel_launch(void* const* d_in, const int* in_sizes, int n_in,
                              void* d_out, int out_size, void* d_ws, size_t ws_size,
                              hipStream_t stream){
    (void)in_sizes; (void)n_in; (void)out_size; (void)ws_size;
    const int*   x          = (const int*)d_in[0];
    const int*   nodes      = (const int*)d_in[2];
    const int*   edges      = (const int*)d_in[3];
    const float* word_emb   = (const float*)d_in[4];
    const float* entity_emb = (const float*)d_in[5];
    const float* bn_gamma   = (const float*)d_in[15];
    const float* bn_beta    = (const float*)d_in[16];
    const float* gc1_w      = (const float*)d_in[19];
    const float* gc1_b      = (const float*)d_in[20];
    const float* gc2_w      = (const float*)d_in[21];
    const float* gc2_b      = (const float*)d_in[22];
    const float* fin1_w     = (const float*)d_in[23];
    const float* fin1_b     = (const float*)d_in[24];
    const float* fin2_w     = (const float*)d_in[25];
    const float* fin2_b     = (const float*)d_in[26];
    float* y = (float*)d_out;

    // ---- workspace layout (~208 MB) ----
    char* base = (char*)d_ws;
    size_t off = 0;
    auto alloc = [&](size_t bytes) -> char* {
        char* p = base + off;
        off += ((bytes + 255) / 256) * 256;
        return p;
    };
    u16* t0 = (u16*)alloc(3*PLANE*2);
    u16* t1 = (u16*)alloc(3*PLANE*2);
    u16* hH = t1;                          // alias: hH (2*PLANE) dead after conv1
    u16* tT = (u16*)alloc(3*TTS*2);
    u16* S  = (u16*)alloc(3*SST*2);        // bf16
    // GCN scratch region, later reused as Vpart (22.0 MB <= 25.2 MB)
    char* G = alloc((size_t)3*B_*NN_*D_*4);
    float* ne = (float*)G;
    float* xw = ne + (size_t)B_*NN_*D_;
    float* g1 = xw + (size_t)B_*NN_*D_;
    float* Vpart = (float*)G;
    float* ocat = (float*)alloc((size_t)B_*C_*OC_*4);
    u16* wfc1  = (u16*)alloc(3*WFC1_STRIDE*2);
    u16* wfres = (u16*)alloc(6*WFRES_STRIDE*2);
    u16* wfaw  = (u16*)alloc(3*WFAW_STRIDE*2);
    u16* wfau  = (u16*)alloc(3*WFAU_STRIDE*2);
    float* w1t   = (float*)alloc((size_t)OC_*128*4);
    float* dinvp = (float*)alloc((size_t)B_*NN_*4);
    int* deg = (int*)alloc((size_t)B_*NN_*4);
    int* rpB = (int*)alloc((size_t)B_*513*4);
    int* cur = (int*)alloc((size_t)B_*NN_*4);
    int* adj = (int*)alloc((size_t)B_*ADJ_*4);

    // ---- init & weight packing ----
    fill_i_k<<<CDIV(B_*NN_,256),256,0,stream>>>(deg, B_*NN_, 1);
    zero_pads3_k<<<CDIV(3*B_*16*128,256),256,0,stream>>>(t0);
    pack_conv1_k<<<dim3(CDIV(9*8*8*512,256),3),256,0,stream>>>(
        (const float*)d_in[6], (const float*)d_in[9], (const float*)d_in[12], wfc1);
    pack_res_k<<<dim3(CDIV(9*4*8*512,256),3,2),256,0,stream>>>(
        (const float*)d_in[8], (const float*)d_in[11], (const float*)d_in[14], wfres);
    pack_aw_k<<<dim3(CDIV(4*16*512,256),3),256,0,stream>>>((const float*)d_in[17], wfaw);
    pack_au_k<<<dim3(CDIV(8*4*512,256),3),256,0,stream>>>((const float*)d_in[18], wfau);

    // ---- embedding (hH lives in the t1 region; t1 pads zeroed after conv1) --
    embed1_k<<<dim3(LP_/8, B_),256,0,stream>>>(x, word_emb, hH);

    // ---- GCN (scratch region G; freed for Vpart afterwards) ----
    gather_nodes_k<<<CDIV(B_*NN_*D_,256),256,0,stream>>>(nodes, entity_emb, ne);
    deg_count_k<<<CDIV(B_*EE_,256),256,0,stream>>>(edges, deg);
    dinv_k<<<CDIV(B_*NN_,256),256,0,stream>>>(deg, dinvp);
    scan_csr_k<<<B_,NN_,0,stream>>>(deg, rpB, cur);
    fill_csr_k<<<dim3(CDIV(ADJ_,256),B_),256,0,stream>>>(edges, cur, adj);
    gemm_nt_k<<<dim3(NN_/64, D_/64, B_),256,0,stream>>>(ne, gc1_w, xw);
    scatter_k<<<dim3(NN_,B_),256,0,stream>>>(xw, adj, rpB, dinvp, gc1_b, g1, NN_*D_, D_, 1);
    gemm_nt_k<<<dim3(NN_/64, D_/64, B_),256,0,stream>>>(g1, gc2_w, xw);
    scatter_k<<<dim3(C_,B_),256,0,stream>>>(xw, adj, rpB, dinvp, gc2_b, ocat, C_*OC_, OC_, 0);

    // ---- encoder: branch-fused dispatches ----
    dim3 gc(64, B_, 3), ga(32, B_, 3);
    // conv1 (all branches): hH -> t0[br]
    conv_mfma_k<0,8><<<gc,256,0,stream>>>(hH, 256, 0,
        wfc1, (long)WFC1_STRIDE,
        (const float*)d_in[7], (const float*)d_in[10], (const float*)d_in[13],
        bn_gamma, bn_beta, 0, t0, nullptr);
    // hH dead; prepare t1 pads (same memory region)
    zero_pads3_k<<<CDIV(3*B_*16*128,256),256,0,stream>>>(t1);
    // res1 (all branches): t0[br] -> t1[br]
    conv_mfma_k<1,4><<<gc,256,0,stream>>>(t0, 128, (long)PLANE,
        wfres, (long)(2*WFRES_STRIDE),
        nullptr, nullptr, nullptr,
        bn_gamma, bn_beta, 100, t1, nullptr);
    // res2 (all branches): t1[br] -> t0[br] + tT[br]
    conv_mfma_k<1,4><<<gc,256,0,stream>>>(t1, 128, (long)PLANE,
        wfres + WFRES_STRIDE, (long)(2*WFRES_STRIDE),
        nullptr, nullptr, nullptr,
        bn_gamma, bn_beta, 200, t0, tT);
    // attention + softmax + V for all branches
    attn_k<<<ga,256,0,stream>>>(t0, wfaw, wfau, S);
    softmax_k<<<dim3(C_,B_,3),256,0,stream>>>(S);
    v_mfma_k<<<dim3(16,B_,3),256,0,stream>>>(tT, S, Vpart);
    reduce_v_k<<<CDIV(3*B_*C_*F_,256),256,0,stream>>>(Vpart, ocat);

    // ---- head ----
    transpose_fin1_k<<<CDIV(OC_*128,256),256,0,stream>>>(fin1_w, w1t);
    final_k<<<dim3(C_,B_),128,0,stream>>>(ocat, w1t, fin1_b, fin2_w, fin2_b, y);
}